// Round 2
// baseline (1707.553 us; speedup 1.0000x reference)
//
#include <hip/hip_runtime.h>
#include <hip/hip_bf16.h>
#include <math.h>

// Problem constants (fixed by setup_inputs: B=8, H=W=56)
#define BB 8
#define HH 56
#define WW 56
#define LL (HH*WW)          // 3136
#define DMODEL 384
#define DINNER 768
#define NH 12
#define HD 64
#define DS 64
#define CDIM (DINNER + 2*DS)    // 896
#define NPROJ (2*DINNER + 2*DS + NH) // 1676
#define MTOT (BB*LL)        // 25088
#define LN_EPS 1e-5f

typedef __hip_bfloat16 bf16;
__device__ __forceinline__ float b2f(bf16 v) { return __bfloat162float(v); }
__device__ __forceinline__ bf16 f2b(float v) { return __float2bfloat16(v); }

// ---------------- GEMM1: zxbcdt = x @ in_proj_w^T, split outputs ----------------
// M=25088, N=1676, K=384. Tile 128x64, block 256 threads, each thread 8x4.
// fp32 math, bf16 stores for z / xBC; fp32 store for dt (small).
__global__ __launch_bounds__(256) void k_gemm1(
    const float* __restrict__ x, const float* __restrict__ w,
    const float* __restrict__ dt_bias,
    bf16* __restrict__ zbuf, bf16* __restrict__ xbcbuf, float* __restrict__ dtbuf)
{
    __shared__ float As[16][128 + 1];
    __shared__ float Bs[16][64 + 1];
    const int m0 = blockIdx.y * 128;
    const int n0 = blockIdx.x * 64;
    const int tid = threadIdx.x;
    const int tx = tid & 15;   // n-dir
    const int ty = tid >> 4;   // m-dir
    float acc[8][4];
#pragma unroll
    for (int i = 0; i < 8; ++i)
#pragma unroll
        for (int j = 0; j < 4; ++j) acc[i][j] = 0.f;

    for (int k0 = 0; k0 < DMODEL; k0 += 16) {
#pragma unroll
        for (int idx = tid; idx < 128 * 16; idx += 256) {
            int m = idx >> 4, k = idx & 15;
            As[k][m] = x[(size_t)(m0 + m) * DMODEL + k0 + k];
        }
#pragma unroll
        for (int idx = tid; idx < 64 * 16; idx += 256) {
            int n = idx >> 4, k = idx & 15;
            int gn = n0 + n;
            Bs[k][n] = (gn < NPROJ) ? w[(size_t)gn * DMODEL + k0 + k] : 0.f;
        }
        __syncthreads();
#pragma unroll
        for (int k = 0; k < 16; ++k) {
            float a[8], bv[4];
#pragma unroll
            for (int i = 0; i < 8; ++i) a[i] = As[k][ty * 8 + i];
#pragma unroll
            for (int j = 0; j < 4; ++j) bv[j] = Bs[k][tx * 4 + j];
#pragma unroll
            for (int i = 0; i < 8; ++i)
#pragma unroll
                for (int j = 0; j < 4; ++j) acc[i][j] += a[i] * bv[j];
        }
        __syncthreads();
    }
#pragma unroll
    for (int i = 0; i < 8; ++i) {
        int m = m0 + ty * 8 + i;  // MTOT divisible by 128 -> always valid
#pragma unroll
        for (int j = 0; j < 4; ++j) {
            int n = n0 + tx * 4 + j;
            if (n >= NPROJ) continue;
            float v = acc[i][j];
            if (n < DINNER) {
                zbuf[(size_t)m * DINNER + n] = f2b(v);
            } else if (n < DINNER + CDIM) {
                xbcbuf[(size_t)m * CDIM + (n - DINNER)] = f2b(v);
            } else {
                int h = n - (DINNER + CDIM);
                float t = v + dt_bias[h];
                float sp = (t > 20.f) ? t : log1pf(expf(t));
                dtbuf[(size_t)m * NH + h] = sp;
            }
        }
    }
}

// ---------------- depthwise 3x3 conv (SAME, cross-correlation) + bias + SiLU ----
__global__ __launch_bounds__(896) void k_conv(
    const bf16* __restrict__ xbc, const float* __restrict__ cw,
    const float* __restrict__ cb, bf16* __restrict__ out)
{
    const int bij = blockIdx.x;
    const int c = threadIdx.x;            // 0..895
    const int b = bij / (HH * WW);
    const int ij = bij % (HH * WW);
    const int i = ij / WW, j = ij % WW;
    float acc = cb[c];
#pragma unroll
    for (int ky = 0; ky < 3; ++ky) {
        int ii = i + ky - 1;
        if (ii < 0 || ii >= HH) continue;
#pragma unroll
        for (int kx = 0; kx < 3; ++kx) {
            int jj = j + kx - 1;
            if (jj < 0 || jj >= WW) continue;
            acc += cw[c * 9 + ky * 3 + kx] * b2f(xbc[((size_t)b * LL + ii * WW + jj) * CDIM + c]);
        }
    }
    float s = acc / (1.f + expf(-acc));   // silu
    out[((size_t)b * LL + ij) * CDIM + c] = f2b(s);
}

// ---------------- fused dx = dt*A*x_in, then 3x3 count-normalized avg pool ------
// out layout: dxp[b][h][l][d]  (bf16, overlaid on d_out)
__global__ __launch_bounds__(768) void k_dxpool(
    const bf16* __restrict__ xbc_conv, const float* __restrict__ dtbuf,
    const float* __restrict__ A_log, bf16* __restrict__ dxp)
{
    const int bl = blockIdx.x;
    const int tid = threadIdx.x;          // 0..767 = h*64+d
    const int b = bl / LL;
    const int l = bl % LL;
    const int i = l / WW, j = l % WW;
    const int h = tid >> 6;
    const int d = tid & 63;
    const float Ahd = -expf(A_log[tid]);
    float sum = 0.f;
    int cnt = 0;
#pragma unroll
    for (int dy = -1; dy <= 1; ++dy) {
        int ii = i + dy;
        if (ii < 0 || ii >= HH) continue;
#pragma unroll
        for (int dxx = -1; dxx <= 1; ++dxx) {
            int jj = j + dxx;
            if (jj < 0 || jj >= WW) continue;
            int ll = ii * WW + jj;
            ++cnt;
            float dtv = dtbuf[((size_t)b * LL + ll) * NH + h];
            float xv = b2f(xbc_conv[((size_t)b * LL + ll) * CDIM + tid]);
            sum += dtv * xv;
        }
    }
    float v = Ahd * sum / (float)cnt;
    dxp[(((size_t)b * NH + h) * LL + l) * HD + d] = f2b(v);
}

// ---------------- h_state[b,h,s,d] = sum_l Bm[b,l,s]*dxp[b,h,l,d]  (split-K) ----
#define SPLITK 8
__global__ __launch_bounds__(256) void k_hstate(
    const bf16* __restrict__ xbc_conv, const bf16* __restrict__ dxp,
    float* __restrict__ hstate)
{
    const int bh = blockIdx.x;            // 0..95
    const int b = bh / NH, h = bh % NH;
    const int lc = blockIdx.y;
    const int l_beg = lc * (LL / SPLITK);
    const int l_end = l_beg + (LL / SPLITK);   // 392, divisible by 8
    __shared__ float Bsh[8][64];
    __shared__ float Dsh[8][64 + 1];
    const int tid = threadIdx.x;
    const int tx = tid & 15;   // d-dir
    const int ty = tid >> 4;   // s-dir
    float acc[4][4];
#pragma unroll
    for (int i = 0; i < 4; ++i)
#pragma unroll
        for (int j = 0; j < 4; ++j) acc[i][j] = 0.f;

    for (int l0 = l_beg; l0 < l_end; l0 += 8) {
#pragma unroll
        for (int idx = tid; idx < 8 * 64; idx += 256) {
            int li = idx >> 6, q = idx & 63;
            Bsh[li][q] = b2f(xbc_conv[((size_t)b * LL + l0 + li) * CDIM + DINNER + q]);
            Dsh[li][q] = b2f(dxp[(((size_t)b * NH + h) * LL + l0 + li) * HD + q]);
        }
        __syncthreads();
#pragma unroll
        for (int li = 0; li < 8; ++li) {
            float a[4], c[4];
#pragma unroll
            for (int i = 0; i < 4; ++i) a[i] = Bsh[li][ty * 4 + i];
#pragma unroll
            for (int j = 0; j < 4; ++j) c[j] = Dsh[li][tx * 4 + j];
#pragma unroll
            for (int i = 0; i < 4; ++i)
#pragma unroll
                for (int j = 0; j < 4; ++j) acc[i][j] += a[i] * c[j];
        }
        __syncthreads();
    }
#pragma unroll
    for (int i = 0; i < 4; ++i)
#pragma unroll
        for (int j = 0; j < 4; ++j) {
            int s = ty * 4 + i, dd = tx * 4 + j;
            atomicAdd(&hstate[((size_t)bh * DS + s) * HD + dd], acc[i][j]);
        }
}

// ---------------- Ch + y: y[b,l,h*64+d] = sum_s Cm[b,l,s]*h[b,h,s,d] + xs*D[h] --
__global__ __launch_bounds__(256) void k_chy(
    const bf16* __restrict__ xbc_conv, const float* __restrict__ hstate,
    const float* __restrict__ Dp, bf16* __restrict__ ybuf)
{
    const int bh = blockIdx.x;
    const int b = bh / NH, h = bh % NH;
    const int l0 = blockIdx.y * 64;
    __shared__ float Hs[64][64];   // [s][d]
    const int tid = threadIdx.x;
    for (int idx = tid; idx < 4096; idx += 256)
        Hs[idx >> 6][idx & 63] = hstate[(size_t)bh * 4096 + idx];
    __syncthreads();
    const float Dh = Dp[h];
    const int d = tid & 63;
    const int lbase = tid >> 6;    // 0..3
#pragma unroll
    for (int r = 0; r < 16; ++r) {
        int ll = lbase + r * 4;
        int l = l0 + ll;
        const bf16* cm = &xbc_conv[((size_t)b * LL + l) * CDIM + DINNER + DS];
        float acc = 0.f;
#pragma unroll
        for (int s = 0; s < 64; ++s) acc += b2f(cm[s]) * Hs[s][d];
        float xv = b2f(xbc_conv[((size_t)b * LL + l) * CDIM + h * HD + d]);
        ybuf[((size_t)b * LL + l) * DINNER + h * HD + d] = f2b(acc + xv * Dh);
    }
}

// ---------------- g = y*silu(z); LayerNorm(768) -> gn ---------------------------
__global__ __launch_bounds__(256) void k_gln(
    const bf16* __restrict__ ybuf, const bf16* __restrict__ zbuf,
    const float* __restrict__ nw, const float* __restrict__ nb,
    bf16* __restrict__ gnbuf)
{
    const int bl = blockIdx.x;
    const int tid = threadIdx.x;   // 256
    __shared__ float s_sum[4], s_sq[4];
    float g[3];
    float sum = 0.f, sumsq = 0.f;
#pragma unroll
    for (int r = 0; r < 3; ++r) {
        int c = tid + r * 256;
        float yv = b2f(ybuf[(size_t)bl * DINNER + c]);
        float zv = b2f(zbuf[(size_t)bl * DINNER + c]);
        float gv = yv * (zv / (1.f + expf(-zv)));
        g[r] = gv;
        sum += gv;
        sumsq += gv * gv;
    }
#pragma unroll
    for (int off = 32; off > 0; off >>= 1) {
        sum += __shfl_down(sum, off, 64);
        sumsq += __shfl_down(sumsq, off, 64);
    }
    const int wave = tid >> 6, lane = tid & 63;
    if (lane == 0) { s_sum[wave] = sum; s_sq[wave] = sumsq; }
    __syncthreads();
    if (tid == 0) {
        float a = 0.f, b2 = 0.f;
#pragma unroll
        for (int w2 = 0; w2 < 4; ++w2) { a += s_sum[w2]; b2 += s_sq[w2]; }
        float mu = a / (float)DINNER;
        float var = b2 / (float)DINNER - mu * mu;
        s_sum[0] = mu;
        s_sq[0] = rsqrtf(var + LN_EPS);
    }
    __syncthreads();
    const float mu = s_sum[0], rstd = s_sq[0];
#pragma unroll
    for (int r = 0; r < 3; ++r) {
        int c = tid + r * 256;
        gnbuf[(size_t)bl * DINNER + c] = f2b((g[r] - mu) * rstd * nw[c] + nb[c]);
    }
}

// ---------------- GEMM2: out = gn @ out_proj_w^T  (M=25088,N=384,K=768) ---------
__global__ __launch_bounds__(256) void k_gemm2(
    const bf16* __restrict__ gn, const float* __restrict__ w,
    float* __restrict__ out)
{
    __shared__ float As[16][128 + 1];
    __shared__ float Bs[16][64 + 1];
    const int m0 = blockIdx.y * 128;
    const int n0 = blockIdx.x * 64;
    const int tid = threadIdx.x;
    const int tx = tid & 15;
    const int ty = tid >> 4;
    float acc[8][4];
#pragma unroll
    for (int i = 0; i < 8; ++i)
#pragma unroll
        for (int j = 0; j < 4; ++j) acc[i][j] = 0.f;

    for (int k0 = 0; k0 < DINNER; k0 += 16) {
#pragma unroll
        for (int idx = tid; idx < 128 * 16; idx += 256) {
            int m = idx >> 4, k = idx & 15;
            As[k][m] = b2f(gn[(size_t)(m0 + m) * DINNER + k0 + k]);
        }
#pragma unroll
        for (int idx = tid; idx < 64 * 16; idx += 256) {
            int n = idx >> 4, k = idx & 15;
            Bs[k][n] = w[(size_t)(n0 + n) * DINNER + k0 + k];
        }
        __syncthreads();
#pragma unroll
        for (int k = 0; k < 16; ++k) {
            float a[8], bv[4];
#pragma unroll
            for (int i = 0; i < 8; ++i) a[i] = As[k][ty * 8 + i];
#pragma unroll
            for (int j = 0; j < 4; ++j) bv[j] = Bs[k][tx * 4 + j];
#pragma unroll
            for (int i = 0; i < 8; ++i)
#pragma unroll
                for (int j = 0; j < 4; ++j) acc[i][j] += a[i] * bv[j];
        }
        __syncthreads();
    }
#pragma unroll
    for (int i = 0; i < 8; ++i) {
        int m = m0 + ty * 8 + i;
#pragma unroll
        for (int j = 0; j < 4; ++j) {
            int n = n0 + tx * 4 + j;   // N=384 divisible by 64 -> always valid
            out[(size_t)m * DMODEL + n] = acc[i][j];
        }
    }
}

extern "C" void kernel_launch(void* const* d_in, const int* in_sizes, int n_in,
                              void* d_out, int out_size, void* d_ws, size_t ws_size,
                              hipStream_t stream)
{
    const float* x         = (const float*)d_in[0];
    const float* in_proj_w = (const float*)d_in[1];
    const float* conv_w    = (const float*)d_in[2];
    const float* conv_b    = (const float*)d_in[3];
    const float* dt_bias   = (const float*)d_in[4];
    const float* A_log     = (const float*)d_in[5];
    const float* Dp        = (const float*)d_in[6];
    const float* norm_w    = (const float*)d_in[7];
    const float* norm_b    = (const float*)d_in[8];
    const float* out_proj_w= (const float*)d_in[9];
    // d_in[10]=H, d_in[11]=W fixed at 56 (hard-coded)

    // workspace layout (bytes), total ~131 MB:
    //   dtbuf   fp32  MTOT*NH          =  1,204,224 B
    //   hstate  fp32  BB*NH*DS*HD      =  1,572,864 B
    //   zbuf    bf16  MTOT*DINNER      = 38,535,168 B
    //   xbcraw  bf16  MTOT*CDIM        = 44,957,696 B
    //   xbcconv bf16  MTOT*CDIM        = 44,957,696 B
    char* wsb = (char*)d_ws;
    float* dtbuf   = (float*)wsb;                               // 1,204,224 B
    float* hstate  = (float*)(wsb + 1204224);                   // 1,572,864 B
    bf16*  zbuf    = (bf16*) (wsb + 1204224 + 1572864);         // 38,535,168 B
    bf16*  xbcraw  = (bf16*) (wsb + 1204224 + 1572864 + 38535168);
    bf16*  xbcconv = (bf16*) (wsb + 1204224 + 1572864 + 38535168 + 44957696);
    // dxp / ybuf (bf16, MTOT*DINNER = 38,535,168 B) overlaid on d_out
    // (out_size*4 = 38,535,168 B — exact fit; consumed before final GEMM write)
    bf16*  dxp     = (bf16*)d_out;
    bf16*  ybuf    = (bf16*)d_out;     // reuse: dxp consumed by k_hstate
    bf16*  gnbuf   = xbcraw;           // reuse: raw xBC dead after k_conv

    hipMemsetAsync(hstate, 0, (size_t)BB * NH * DS * HD * sizeof(float), stream);

    k_gemm1<<<dim3((NPROJ + 63) / 64, MTOT / 128), 256, 0, stream>>>(
        x, in_proj_w, dt_bias, zbuf, xbcraw, dtbuf);
    k_conv<<<BB * LL, CDIM, 0, stream>>>(xbcraw, conv_w, conv_b, xbcconv);
    k_dxpool<<<BB * LL, DINNER, 0, stream>>>(xbcconv, dtbuf, A_log, dxp);
    k_hstate<<<dim3(BB * NH, SPLITK), 256, 0, stream>>>(xbcconv, dxp, hstate);
    k_chy<<<dim3(BB * NH, LL / 64), 256, 0, stream>>>(xbcconv, hstate, Dp, ybuf);
    k_gln<<<BB * LL, 256, 0, stream>>>(ybuf, zbuf, norm_w, norm_b, gnbuf);
    k_gemm2<<<dim3(DMODEL / 64, MTOT / 128), 256, 0, stream>>>(gnbuf, out_proj_w, (float*)d_out);
}

// Round 4
// 1039.556 us; speedup vs baseline: 1.6426x; 1.6426x over previous
//
#include <hip/hip_runtime.h>
#include <hip/hip_bf16.h>
#include <math.h>

// Problem constants (fixed by setup_inputs: B=8, H=W=56)
#define BB 8
#define HH 56
#define WW 56
#define LL (HH*WW)          // 3136
#define DMODEL 384
#define DINNER 768
#define NH 12
#define HD 64
#define DS 64
#define CDIM (DINNER + 2*DS)    // 896
#define NPROJ (2*DINNER + 2*DS + NH) // 1676
#define NPAD 1792           // NPROJ padded to multiple of 128
#define MTOT (BB*LL)        // 25088
#define LN_EPS 1e-5f

typedef __hip_bfloat16 bf16;
typedef __attribute__((ext_vector_type(8))) __bf16 bf16x8;
typedef __attribute__((ext_vector_type(4))) float f32x4;

__device__ __forceinline__ float b2f(bf16 v) { return __bfloat162float(v); }
__device__ __forceinline__ bf16 f2b(float v) { return __float2bfloat16(v); }
__device__ __forceinline__ ushort f2bu(float v) {
    union { bf16 h; ushort u; } cv; cv.h = __float2bfloat16(v); return cv.u;
}
__device__ __forceinline__ float u2f(ushort u) {
    union { ushort u; bf16 h; } cv; cv.u = u; return __bfloat162float(cv.h);
}

// ---------------- cast kernels: fp32 -> bf16 hi + bf16 lo residual --------------
__global__ __launch_bounds__(256) void k_cast_x(
    const float4* __restrict__ in, ushort4* __restrict__ hi, ushort4* __restrict__ lo)
{
    int i = blockIdx.x * 256 + threadIdx.x;    // grid sized exactly
    float4 v = in[i];
    ushort4 h, l;
    h.x = f2bu(v.x); h.y = f2bu(v.y); h.z = f2bu(v.z); h.w = f2bu(v.w);
    l.x = f2bu(v.x - u2f(h.x)); l.y = f2bu(v.y - u2f(h.y));
    l.z = f2bu(v.z - u2f(h.z)); l.w = f2bu(v.w - u2f(h.w));
    hi[i] = h; lo[i] = l;
}

// w1 hi/lo [n][k], n<NPAD: zero-padded rows beyond NPROJ
__global__ __launch_bounds__(256) void k_cast_w1(
    const float* __restrict__ w, ushort4* __restrict__ hi, ushort4* __restrict__ lo)
{
    int i = blockIdx.x * 256 + threadIdx.x;   // over NPAD*384/4 = 172032
    int n = i / (DMODEL / 4);
    int k = (i % (DMODEL / 4)) * 4;
    ushort4 h = {0,0,0,0}, l = {0,0,0,0};
    if (n < NPROJ) {
        float4 v = *(const float4*)(w + (size_t)n * DMODEL + k);
        h.x = f2bu(v.x); h.y = f2bu(v.y); h.z = f2bu(v.z); h.w = f2bu(v.w);
        l.x = f2bu(v.x - u2f(h.x)); l.y = f2bu(v.y - u2f(h.y));
        l.z = f2bu(v.z - u2f(h.z)); l.w = f2bu(v.w - u2f(h.w));
    }
    hi[i] = h; lo[i] = l;
}

__global__ __launch_bounds__(256) void k_cast_w2(
    const float4* __restrict__ in, ushort4* __restrict__ hi, ushort4* __restrict__ lo)
{
    int i = blockIdx.x * 256 + threadIdx.x;   // over 384*768/4 = 73728
    float4 v = in[i];
    ushort4 h, l;
    h.x = f2bu(v.x); h.y = f2bu(v.y); h.z = f2bu(v.z); h.w = f2bu(v.w);
    l.x = f2bu(v.x - u2f(h.x)); l.y = f2bu(v.y - u2f(h.y));
    l.z = f2bu(v.z - u2f(h.z)); l.w = f2bu(v.w - u2f(h.w));
    hi[i] = h; lo[i] = l;
}

// ---------------- GEMM1 (MFMA, split-bf16): zxbcdt = x @ in_proj_w^T ------------
// M=25088, N=1792(pad), K=384. NT layout, 128x128 tile, BK=32, 4 waves 2x2.
// A and B both split hi/lo; acc += aH*bH + aL*bH + aH*bL  (fp32-grade inputs).
#define LDSW 40
__global__ __launch_bounds__(256) void k_gemm1_mfma(
    const ushort* __restrict__ xh, const ushort* __restrict__ xl,
    const ushort* __restrict__ wh, const ushort* __restrict__ wl,
    const float* __restrict__ dt_bias,
    ushort* __restrict__ zbuf, ushort* __restrict__ xbcbuf, float* __restrict__ dtbuf)
{
    __shared__ ushort AsH[128 * LDSW];
    __shared__ ushort AsL[128 * LDSW];
    __shared__ ushort BsH[128 * LDSW];
    __shared__ ushort BsL[128 * LDSW];
    const int m0 = blockIdx.y * 128;
    const int n0 = blockIdx.x * 128;
    const int tid = threadIdx.x;
    const int wid = tid >> 6;
    const int lane = tid & 63;
    const int r = lane & 15;
    const int quad = lane >> 4;
    const int wm = (wid >> 1) * 64;
    const int wn = (wid & 1) * 64;
    const int srow = tid >> 2;        // 0..63
    const int scol = (tid & 3) * 8;   // 0,8,16,24

    f32x4 acc[4][4];
#pragma unroll
    for (int i = 0; i < 4; ++i)
#pragma unroll
        for (int j = 0; j < 4; ++j) acc[i][j] = (f32x4){0.f, 0.f, 0.f, 0.f};

    for (int k0 = 0; k0 < DMODEL; k0 += 32) {
        size_t aoff0 = (size_t)(m0 + srow)      * DMODEL + k0 + scol;
        size_t aoff1 = (size_t)(m0 + srow + 64) * DMODEL + k0 + scol;
        size_t boff0 = (size_t)(n0 + srow)      * DMODEL + k0 + scol;
        size_t boff1 = (size_t)(n0 + srow + 64) * DMODEL + k0 + scol;
        int4 ah0 = *(const int4*)(xh + aoff0);
        int4 ah1 = *(const int4*)(xh + aoff1);
        int4 al0 = *(const int4*)(xl + aoff0);
        int4 al1 = *(const int4*)(xl + aoff1);
        int4 bh0 = *(const int4*)(wh + boff0);
        int4 bh1 = *(const int4*)(wh + boff1);
        int4 bl0 = *(const int4*)(wl + boff0);
        int4 bl1 = *(const int4*)(wl + boff1);
        __syncthreads();
        *(int4*)(AsH + srow * LDSW + scol)        = ah0;
        *(int4*)(AsH + (srow + 64) * LDSW + scol) = ah1;
        *(int4*)(AsL + srow * LDSW + scol)        = al0;
        *(int4*)(AsL + (srow + 64) * LDSW + scol) = al1;
        *(int4*)(BsH + srow * LDSW + scol)        = bh0;
        *(int4*)(BsH + (srow + 64) * LDSW + scol) = bh1;
        *(int4*)(BsL + srow * LDSW + scol)        = bl0;
        *(int4*)(BsL + (srow + 64) * LDSW + scol) = bl1;
        __syncthreads();
        bf16x8 afH[4], afL[4], bfH[4], bfL[4];
#pragma unroll
        for (int t = 0; t < 4; ++t) {
            afH[t] = *(const bf16x8*)(AsH + (wm + t * 16 + r) * LDSW + quad * 8);
            afL[t] = *(const bf16x8*)(AsL + (wm + t * 16 + r) * LDSW + quad * 8);
            bfH[t] = *(const bf16x8*)(BsH + (wn + t * 16 + r) * LDSW + quad * 8);
            bfL[t] = *(const bf16x8*)(BsL + (wn + t * 16 + r) * LDSW + quad * 8);
        }
#pragma unroll
        for (int i = 0; i < 4; ++i)
#pragma unroll
            for (int j = 0; j < 4; ++j) {
                acc[i][j] = __builtin_amdgcn_mfma_f32_16x16x32_bf16(afH[i], bfH[j], acc[i][j], 0, 0, 0);
                acc[i][j] = __builtin_amdgcn_mfma_f32_16x16x32_bf16(afL[i], bfH[j], acc[i][j], 0, 0, 0);
                acc[i][j] = __builtin_amdgcn_mfma_f32_16x16x32_bf16(afH[i], bfL[j], acc[i][j], 0, 0, 0);
            }
    }
    // epilogue: D row = quad*4+v (m), col = r (n); split by n
#pragma unroll
    for (int i = 0; i < 4; ++i) {
#pragma unroll
        for (int j = 0; j < 4; ++j) {
            int n = n0 + wn + j * 16 + r;
            if (n >= NPROJ) continue;
#pragma unroll
            for (int v = 0; v < 4; ++v) {
                int m = m0 + wm + i * 16 + quad * 4 + v;
                float val = acc[i][j][v];
                if (n < DINNER) {
                    zbuf[(size_t)m * DINNER + n] = f2bu(val);
                } else if (n < DINNER + CDIM) {
                    xbcbuf[(size_t)m * CDIM + (n - DINNER)] = f2bu(val);
                } else {
                    int h = n - (DINNER + CDIM);
                    float t = val + dt_bias[h];
                    float sp = (t > 20.f) ? t : log1pf(expf(t));
                    dtbuf[(size_t)m * NH + h] = sp;
                }
            }
        }
    }
}

// ---------------- GEMM2 (MFMA): out = gn @ (w2_hi+w2_lo)^T  (M=25088,N=384,K=768)
__global__ __launch_bounds__(256) void k_gemm2_mfma(
    const ushort* __restrict__ gn, const ushort* __restrict__ wh,
    const ushort* __restrict__ wl, float* __restrict__ out)
{
    __shared__ ushort As[128 * LDSW];
    __shared__ ushort BsH[128 * LDSW];
    __shared__ ushort BsL[128 * LDSW];
    const int m0 = blockIdx.y * 128;
    const int n0 = blockIdx.x * 128;
    const int tid = threadIdx.x;
    const int wid = tid >> 6;
    const int lane = tid & 63;
    const int r = lane & 15;
    const int quad = lane >> 4;
    const int wm = (wid >> 1) * 64;
    const int wn = (wid & 1) * 64;
    const int srow = tid >> 2;
    const int scol = (tid & 3) * 8;

    f32x4 acc[4][4];
#pragma unroll
    for (int i = 0; i < 4; ++i)
#pragma unroll
        for (int j = 0; j < 4; ++j) acc[i][j] = (f32x4){0.f, 0.f, 0.f, 0.f};

    for (int k0 = 0; k0 < DINNER; k0 += 32) {
        size_t aoff0 = (size_t)(m0 + srow)      * DINNER + k0 + scol;
        size_t aoff1 = (size_t)(m0 + srow + 64) * DINNER + k0 + scol;
        size_t boff0 = (size_t)(n0 + srow)      * DINNER + k0 + scol;
        size_t boff1 = (size_t)(n0 + srow + 64) * DINNER + k0 + scol;
        int4 a0  = *(const int4*)(gn + aoff0);
        int4 a1  = *(const int4*)(gn + aoff1);
        int4 bh0 = *(const int4*)(wh + boff0);
        int4 bh1 = *(const int4*)(wh + boff1);
        int4 bl0 = *(const int4*)(wl + boff0);
        int4 bl1 = *(const int4*)(wl + boff1);
        __syncthreads();
        *(int4*)(As + srow * LDSW + scol)         = a0;
        *(int4*)(As + (srow + 64) * LDSW + scol)  = a1;
        *(int4*)(BsH + srow * LDSW + scol)        = bh0;
        *(int4*)(BsH + (srow + 64) * LDSW + scol) = bh1;
        *(int4*)(BsL + srow * LDSW + scol)        = bl0;
        *(int4*)(BsL + (srow + 64) * LDSW + scol) = bl1;
        __syncthreads();
        bf16x8 af[4], bfH[4], bfL[4];
#pragma unroll
        for (int t = 0; t < 4; ++t) {
            af[t]  = *(const bf16x8*)(As + (wm + t * 16 + r) * LDSW + quad * 8);
            bfH[t] = *(const bf16x8*)(BsH + (wn + t * 16 + r) * LDSW + quad * 8);
            bfL[t] = *(const bf16x8*)(BsL + (wn + t * 16 + r) * LDSW + quad * 8);
        }
#pragma unroll
        for (int i = 0; i < 4; ++i)
#pragma unroll
            for (int j = 0; j < 4; ++j) {
                acc[i][j] = __builtin_amdgcn_mfma_f32_16x16x32_bf16(af[i], bfH[j], acc[i][j], 0, 0, 0);
                acc[i][j] = __builtin_amdgcn_mfma_f32_16x16x32_bf16(af[i], bfL[j], acc[i][j], 0, 0, 0);
            }
    }
#pragma unroll
    for (int i = 0; i < 4; ++i) {
#pragma unroll
        for (int j = 0; j < 4; ++j) {
            int n = n0 + wn + j * 16 + r;
#pragma unroll
            for (int v = 0; v < 4; ++v) {
                int m = m0 + wm + i * 16 + quad * 4 + v;
                out[(size_t)m * DMODEL + n] = acc[i][j][v];
            }
        }
    }
}

// ---------------- depthwise 3x3 conv (SAME, cross-correlation) + bias + SiLU ----
__global__ __launch_bounds__(896) void k_conv(
    const bf16* __restrict__ xbc, const float* __restrict__ cw,
    const float* __restrict__ cb, bf16* __restrict__ out)
{
    const int bij = blockIdx.x;
    const int c = threadIdx.x;            // 0..895
    const int b = bij / (HH * WW);
    const int ij = bij % (HH * WW);
    const int i = ij / WW, j = ij % WW;
    float acc = cb[c];
#pragma unroll
    for (int ky = 0; ky < 3; ++ky) {
        int ii = i + ky - 1;
        if (ii < 0 || ii >= HH) continue;
#pragma unroll
        for (int kx = 0; kx < 3; ++kx) {
            int jj = j + kx - 1;
            if (jj < 0 || jj >= WW) continue;
            acc += cw[c * 9 + ky * 3 + kx] * b2f(xbc[((size_t)b * LL + ii * WW + jj) * CDIM + c]);
        }
    }
    float s = acc / (1.f + expf(-acc));   // silu
    out[((size_t)b * LL + ij) * CDIM + c] = f2b(s);
}

// ---------------- fused dx = dt*A*x_in, then 3x3 count-normalized avg pool ------
// out layout: dxp[b][h][l][d]  (bf16, overlaid on d_out)
__global__ __launch_bounds__(768) void k_dxpool(
    const bf16* __restrict__ xbc_conv, const float* __restrict__ dtbuf,
    const float* __restrict__ A_log, bf16* __restrict__ dxp)
{
    const int bl = blockIdx.x;
    const int tid = threadIdx.x;          // 0..767 = h*64+d
    const int b = bl / LL;
    const int l = bl % LL;
    const int i = l / WW, j = l % WW;
    const int h = tid >> 6;
    const int d = tid & 63;
    const float Ahd = -expf(A_log[tid]);
    float sum = 0.f;
    int cnt = 0;
#pragma unroll
    for (int dy = -1; dy <= 1; ++dy) {
        int ii = i + dy;
        if (ii < 0 || ii >= HH) continue;
#pragma unroll
        for (int dxx = -1; dxx <= 1; ++dxx) {
            int jj = j + dxx;
            if (jj < 0 || jj >= WW) continue;
            int ll = ii * WW + jj;
            ++cnt;
            float dtv = dtbuf[((size_t)b * LL + ll) * NH + h];
            float xv = b2f(xbc_conv[((size_t)b * LL + ll) * CDIM + tid]);
            sum += dtv * xv;
        }
    }
    float v = Ahd * sum / (float)cnt;
    dxp[(((size_t)b * NH + h) * LL + l) * HD + d] = f2b(v);
}

// ---------------- h_state[b,h,s,d] = sum_l Bm[b,l,s]*dxp[b,h,l,d]  (split-K) ----
#define SPLITK 8
__global__ __launch_bounds__(256) void k_hstate(
    const bf16* __restrict__ xbc_conv, const bf16* __restrict__ dxp,
    float* __restrict__ hstate)
{
    const int bh = blockIdx.x;            // 0..95
    const int b = bh / NH, h = bh % NH;
    const int lc = blockIdx.y;
    const int l_beg = lc * (LL / SPLITK);
    const int l_end = l_beg + (LL / SPLITK);   // 392, divisible by 8
    __shared__ float Bsh[8][64];
    __shared__ float Dsh[8][64 + 1];
    const int tid = threadIdx.x;
    const int tx = tid & 15;   // d-dir
    const int ty = tid >> 4;   // s-dir
    float acc[4][4];
#pragma unroll
    for (int i = 0; i < 4; ++i)
#pragma unroll
        for (int j = 0; j < 4; ++j) acc[i][j] = 0.f;

    for (int l0 = l_beg; l0 < l_end; l0 += 8) {
#pragma unroll
        for (int idx = tid; idx < 8 * 64; idx += 256) {
            int li = idx >> 6, q = idx & 63;
            Bsh[li][q] = b2f(xbc_conv[((size_t)b * LL + l0 + li) * CDIM + DINNER + q]);
            Dsh[li][q] = b2f(dxp[(((size_t)b * NH + h) * LL + l0 + li) * HD + q]);
        }
        __syncthreads();
#pragma unroll
        for (int li = 0; li < 8; ++li) {
            float a[4], c[4];
#pragma unroll
            for (int i = 0; i < 4; ++i) a[i] = Bsh[li][ty * 4 + i];
#pragma unroll
            for (int j = 0; j < 4; ++j) c[j] = Dsh[li][tx * 4 + j];
#pragma unroll
            for (int i = 0; i < 4; ++i)
#pragma unroll
                for (int j = 0; j < 4; ++j) acc[i][j] += a[i] * c[j];
        }
        __syncthreads();
    }
#pragma unroll
    for (int i = 0; i < 4; ++i)
#pragma unroll
        for (int j = 0; j < 4; ++j) {
            int s = ty * 4 + i, dd = tx * 4 + j;
            atomicAdd(&hstate[((size_t)bh * DS + s) * HD + dd], acc[i][j]);
        }
}

// ---------------- Ch + y: y[b,l,h*64+d] = sum_s Cm[b,l,s]*h[b,h,s,d] + xs*D[h] --
__global__ __launch_bounds__(256) void k_chy(
    const bf16* __restrict__ xbc_conv, const float* __restrict__ hstate,
    const float* __restrict__ Dp, bf16* __restrict__ ybuf)
{
    const int bh = blockIdx.x;
    const int b = bh / NH, h = bh % NH;
    const int l0 = blockIdx.y * 64;
    __shared__ float Hs[64][64];   // [s][d]
    const int tid = threadIdx.x;
    for (int idx = tid; idx < 4096; idx += 256)
        Hs[idx >> 6][idx & 63] = hstate[(size_t)bh * 4096 + idx];
    __syncthreads();
    const float Dh = Dp[h];
    const int d = tid & 63;
    const int lbase = tid >> 6;    // 0..3
#pragma unroll
    for (int r = 0; r < 16; ++r) {
        int ll = lbase + r * 4;
        int l = l0 + ll;
        const bf16* cm = &xbc_conv[((size_t)b * LL + l) * CDIM + DINNER + DS];
        float acc = 0.f;
#pragma unroll
        for (int s = 0; s < 64; ++s) acc += b2f(cm[s]) * Hs[s][d];
        float xv = b2f(xbc_conv[((size_t)b * LL + l) * CDIM + h * HD + d]);
        ybuf[((size_t)b * LL + l) * DINNER + h * HD + d] = f2b(acc + xv * Dh);
    }
}

// ---------------- g = y*silu(z); LayerNorm(768) -> gn ---------------------------
__global__ __launch_bounds__(256) void k_gln(
    const bf16* __restrict__ ybuf, const bf16* __restrict__ zbuf,
    const float* __restrict__ nw, const float* __restrict__ nb,
    bf16* __restrict__ gnbuf)
{
    const int bl = blockIdx.x;
    const int tid = threadIdx.x;   // 256
    __shared__ float s_sum[4], s_sq[4];
    float g[3];
    float sum = 0.f, sumsq = 0.f;
#pragma unroll
    for (int r = 0; r < 3; ++r) {
        int c = tid + r * 256;
        float yv = b2f(ybuf[(size_t)bl * DINNER + c]);
        float zv = b2f(zbuf[(size_t)bl * DINNER + c]);
        float gv = yv * (zv / (1.f + expf(-zv)));
        g[r] = gv;
        sum += gv;
        sumsq += gv * gv;
    }
#pragma unroll
    for (int off = 32; off > 0; off >>= 1) {
        sum += __shfl_down(sum, off, 64);
        sumsq += __shfl_down(sumsq, off, 64);
    }
    const int wave = tid >> 6, lane = tid & 63;
    if (lane == 0) { s_sum[wave] = sum; s_sq[wave] = sumsq; }
    __syncthreads();
    if (tid == 0) {
        float a = 0.f, b2 = 0.f;
#pragma unroll
        for (int w2 = 0; w2 < 4; ++w2) { a += s_sum[w2]; b2 += s_sq[w2]; }
        float mu = a / (float)DINNER;
        float var = b2 / (float)DINNER - mu * mu;
        s_sum[0] = mu;
        s_sq[0] = rsqrtf(var + LN_EPS);
    }
    __syncthreads();
    const float mu = s_sum[0], rstd = s_sq[0];
#pragma unroll
    for (int r = 0; r < 3; ++r) {
        int c = tid + r * 256;
        gnbuf[(size_t)bl * DINNER + c] = f2b((g[r] - mu) * rstd * nw[c] + nb[c]);
    }
}

extern "C" void kernel_launch(void* const* d_in, const int* in_sizes, int n_in,
                              void* d_out, int out_size, void* d_ws, size_t ws_size,
                              hipStream_t stream)
{
    const float* x         = (const float*)d_in[0];
    const float* in_proj_w = (const float*)d_in[1];
    const float* conv_w    = (const float*)d_in[2];
    const float* conv_b    = (const float*)d_in[3];
    const float* dt_bias   = (const float*)d_in[4];
    const float* A_log     = (const float*)d_in[5];
    const float* Dp        = (const float*)d_in[6];
    const float* norm_w    = (const float*)d_in[7];
    const float* norm_b    = (const float*)d_in[8];
    const float* out_proj_w= (const float*)d_in[9];

    // workspace layout (bytes), total ~133.8 MB (known-good was 133.2):
    char* wsb = (char*)d_ws;
    float*  dtbuf   = (float*) (wsb + 0);           //  1,204,224 fp32 MTOT*NH
    float*  hstate  = (float*) (wsb + 1204224);     //  1,572,864 fp32
    ushort* w1_lo   = (ushort*)(wsb + 1204224);     //  aliases hstate (1,376,256 <= 1,572,864);
                                                    //  hstate memset AFTER gemm1
    ushort* w1_hi   = (ushort*)(wsb + 2777088);     //  1,376,256 bf16 NPAD*384
    ushort* w2_hi   = (ushort*)(wsb + 4153344);     //    589,824 bf16 384*768
    ushort* zbuf    = (ushort*)(wsb + 4743168);     // 38,535,168 bf16 MTOT*DINNER
    ushort* xbcraw  = (ushort*)(wsb + 43278336);    // 44,957,696 bf16 MTOT*CDIM
    ushort* xbcconv = (ushort*)(wsb + 88236032);    // 44,957,696 bf16 MTOT*CDIM
    ushort* w2_lo   = (ushort*)(wsb + 133193728);   //    589,824 bf16
    // x_hi/x_lo (bf16 casts of x, 19.3 MB each) alias xbcconv: dead after gemm1,
    // xbcconv born at k_conv.
    ushort* x_hi    = xbcconv;
    ushort* x_lo    = xbcconv + (size_t)MTOT * DMODEL;
    // dxp / ybuf (bf16, 38.5 MB) overlaid on d_out; consumed before final GEMM write
    bf16*   dxp     = (bf16*)d_out;
    bf16*   ybuf    = (bf16*)d_out;
    ushort* gnbuf   = xbcraw;          // raw xBC dead after k_conv

    k_cast_x <<<MTOT * DMODEL / 4 / 256, 256, 0, stream>>>(
        (const float4*)x, (ushort4*)x_hi, (ushort4*)x_lo);
    k_cast_w1<<<NPAD * DMODEL / 4 / 256, 256, 0, stream>>>(
        in_proj_w, (ushort4*)w1_hi, (ushort4*)w1_lo);
    k_cast_w2<<<DMODEL * DINNER / 4 / 256, 256, 0, stream>>>(
        (const float4*)out_proj_w, (ushort4*)w2_hi, (ushort4*)w2_lo);

    k_gemm1_mfma<<<dim3(NPAD / 128, MTOT / 128), 256, 0, stream>>>(
        x_hi, x_lo, w1_hi, w1_lo, dt_bias, zbuf, xbcraw, dtbuf);

    // hstate memset AFTER gemm1 (w1_lo aliases this region)
    hipMemsetAsync(hstate, 0, (size_t)BB * NH * DS * HD * sizeof(float), stream);

    k_conv<<<BB * LL, CDIM, 0, stream>>>((const bf16*)xbcraw, conv_w, conv_b, (bf16*)xbcconv);
    k_dxpool<<<BB * LL, DINNER, 0, stream>>>((const bf16*)xbcconv, dtbuf, A_log, dxp);
    k_hstate<<<dim3(BB * NH, SPLITK), 256, 0, stream>>>((const bf16*)xbcconv, (const bf16*)dxp, hstate);
    k_chy<<<dim3(BB * NH, LL / 64), 256, 0, stream>>>((const bf16*)xbcconv, hstate, Dp, ybuf);
    k_gln<<<BB * LL, 256, 0, stream>>>(ybuf, (const bf16*)zbuf, norm_w, norm_b, (bf16*)gnbuf);
    k_gemm2_mfma<<<dim3(DMODEL / 128, MTOT / 128), 256, 0, stream>>>(
        gnbuf, w2_hi, w2_lo, (float*)d_out);
}

// Round 5
// 760.340 us; speedup vs baseline: 2.2458x; 1.3672x over previous
//
#include <hip/hip_runtime.h>
#include <hip/hip_bf16.h>
#include <math.h>

// Problem constants (fixed by setup_inputs: B=8, H=W=56)
#define BB 8
#define HH 56
#define WW 56
#define LL (HH*WW)          // 3136
#define DMODEL 384
#define DINNER 768
#define NH 12
#define HD 64
#define DS 64
#define CDIM (DINNER + 2*DS)    // 896
#define NPROJ (2*DINNER + 2*DS + NH) // 1676
#define NPAD 1792           // NPROJ padded to multiple of 128
#define MTOT (BB*LL)        // 25088
#define LN_EPS 1e-5f

typedef __hip_bfloat16 bf16;
typedef __attribute__((ext_vector_type(8))) __bf16 bf16x8;
typedef __attribute__((ext_vector_type(4))) float f32x4;

__device__ __forceinline__ float b2f(bf16 v) { return __bfloat162float(v); }
__device__ __forceinline__ bf16 f2b(float v) { return __float2bfloat16(v); }
__device__ __forceinline__ ushort f2bu(float v) {
    union { bf16 h; ushort u; } cv; cv.h = __float2bfloat16(v); return cv.u;
}
__device__ __forceinline__ float u2f(ushort u) {
    union { ushort u; bf16 h; } cv; cv.u = u; return __bfloat162float(cv.h);
}

// ---------------- cast kernels: fp32 -> bf16 hi + bf16 lo residual --------------
__global__ __launch_bounds__(256) void k_cast_x(
    const float4* __restrict__ in, ushort4* __restrict__ hi, ushort4* __restrict__ lo)
{
    int i = blockIdx.x * 256 + threadIdx.x;    // grid sized exactly
    float4 v = in[i];
    ushort4 h, l;
    h.x = f2bu(v.x); h.y = f2bu(v.y); h.z = f2bu(v.z); h.w = f2bu(v.w);
    l.x = f2bu(v.x - u2f(h.x)); l.y = f2bu(v.y - u2f(h.y));
    l.z = f2bu(v.z - u2f(h.z)); l.w = f2bu(v.w - u2f(h.w));
    hi[i] = h; lo[i] = l;
}

// w1 hi/lo [n][k], n<NPAD: zero-padded rows beyond NPROJ
__global__ __launch_bounds__(256) void k_cast_w1(
    const float* __restrict__ w, ushort4* __restrict__ hi, ushort4* __restrict__ lo)
{
    int i = blockIdx.x * 256 + threadIdx.x;   // over NPAD*384/4 = 172032
    int n = i / (DMODEL / 4);
    int k = (i % (DMODEL / 4)) * 4;
    ushort4 h = {0,0,0,0}, l = {0,0,0,0};
    if (n < NPROJ) {
        float4 v = *(const float4*)(w + (size_t)n * DMODEL + k);
        h.x = f2bu(v.x); h.y = f2bu(v.y); h.z = f2bu(v.z); h.w = f2bu(v.w);
        l.x = f2bu(v.x - u2f(h.x)); l.y = f2bu(v.y - u2f(h.y));
        l.z = f2bu(v.z - u2f(h.z)); l.w = f2bu(v.w - u2f(h.w));
    }
    hi[i] = h; lo[i] = l;
}

__global__ __launch_bounds__(256) void k_cast_w2(
    const float4* __restrict__ in, ushort4* __restrict__ hi, ushort4* __restrict__ lo)
{
    int i = blockIdx.x * 256 + threadIdx.x;   // over 384*768/4 = 73728
    float4 v = in[i];
    ushort4 h, l;
    h.x = f2bu(v.x); h.y = f2bu(v.y); h.z = f2bu(v.z); h.w = f2bu(v.w);
    l.x = f2bu(v.x - u2f(h.x)); l.y = f2bu(v.y - u2f(h.y));
    l.z = f2bu(v.z - u2f(h.z)); l.w = f2bu(v.w - u2f(h.w));
    hi[i] = h; lo[i] = l;
}

// ---------------- GEMM1 (MFMA, split-bf16): zxbcdt = x @ in_proj_w^T ------------
// M=25088, N=1792(pad), K=384. NT layout, 128x128 tile, BK=32, 4 waves 2x2.
// A and B both split hi/lo; acc += aH*bH + aL*bH + aH*bL  (fp32-grade inputs).
#define LDSW 40
__global__ __launch_bounds__(256) void k_gemm1_mfma(
    const ushort* __restrict__ xh, const ushort* __restrict__ xl,
    const ushort* __restrict__ wh, const ushort* __restrict__ wl,
    const float* __restrict__ dt_bias,
    ushort* __restrict__ zbuf, ushort* __restrict__ xbcbuf, float* __restrict__ dtbuf)
{
    __shared__ ushort AsH[128 * LDSW];
    __shared__ ushort AsL[128 * LDSW];
    __shared__ ushort BsH[128 * LDSW];
    __shared__ ushort BsL[128 * LDSW];
    const int m0 = blockIdx.y * 128;
    const int n0 = blockIdx.x * 128;
    const int tid = threadIdx.x;
    const int wid = tid >> 6;
    const int lane = tid & 63;
    const int r = lane & 15;
    const int quad = lane >> 4;
    const int wm = (wid >> 1) * 64;
    const int wn = (wid & 1) * 64;
    const int srow = tid >> 2;        // 0..63
    const int scol = (tid & 3) * 8;   // 0,8,16,24

    f32x4 acc[4][4];
#pragma unroll
    for (int i = 0; i < 4; ++i)
#pragma unroll
        for (int j = 0; j < 4; ++j) acc[i][j] = (f32x4){0.f, 0.f, 0.f, 0.f};

    for (int k0 = 0; k0 < DMODEL; k0 += 32) {
        size_t aoff0 = (size_t)(m0 + srow)      * DMODEL + k0 + scol;
        size_t aoff1 = (size_t)(m0 + srow + 64) * DMODEL + k0 + scol;
        size_t boff0 = (size_t)(n0 + srow)      * DMODEL + k0 + scol;
        size_t boff1 = (size_t)(n0 + srow + 64) * DMODEL + k0 + scol;
        int4 ah0 = *(const int4*)(xh + aoff0);
        int4 ah1 = *(const int4*)(xh + aoff1);
        int4 al0 = *(const int4*)(xl + aoff0);
        int4 al1 = *(const int4*)(xl + aoff1);
        int4 bh0 = *(const int4*)(wh + boff0);
        int4 bh1 = *(const int4*)(wh + boff1);
        int4 bl0 = *(const int4*)(wl + boff0);
        int4 bl1 = *(const int4*)(wl + boff1);
        __syncthreads();
        *(int4*)(AsH + srow * LDSW + scol)        = ah0;
        *(int4*)(AsH + (srow + 64) * LDSW + scol) = ah1;
        *(int4*)(AsL + srow * LDSW + scol)        = al0;
        *(int4*)(AsL + (srow + 64) * LDSW + scol) = al1;
        *(int4*)(BsH + srow * LDSW + scol)        = bh0;
        *(int4*)(BsH + (srow + 64) * LDSW + scol) = bh1;
        *(int4*)(BsL + srow * LDSW + scol)        = bl0;
        *(int4*)(BsL + (srow + 64) * LDSW + scol) = bl1;
        __syncthreads();
        bf16x8 afH[4], afL[4], bfH[4], bfL[4];
#pragma unroll
        for (int t = 0; t < 4; ++t) {
            afH[t] = *(const bf16x8*)(AsH + (wm + t * 16 + r) * LDSW + quad * 8);
            afL[t] = *(const bf16x8*)(AsL + (wm + t * 16 + r) * LDSW + quad * 8);
            bfH[t] = *(const bf16x8*)(BsH + (wn + t * 16 + r) * LDSW + quad * 8);
            bfL[t] = *(const bf16x8*)(BsL + (wn + t * 16 + r) * LDSW + quad * 8);
        }
#pragma unroll
        for (int i = 0; i < 4; ++i)
#pragma unroll
            for (int j = 0; j < 4; ++j) {
                acc[i][j] = __builtin_amdgcn_mfma_f32_16x16x32_bf16(afH[i], bfH[j], acc[i][j], 0, 0, 0);
                acc[i][j] = __builtin_amdgcn_mfma_f32_16x16x32_bf16(afL[i], bfH[j], acc[i][j], 0, 0, 0);
                acc[i][j] = __builtin_amdgcn_mfma_f32_16x16x32_bf16(afH[i], bfL[j], acc[i][j], 0, 0, 0);
            }
    }
    // epilogue: D row = quad*4+v (m), col = r (n); split by n
#pragma unroll
    for (int i = 0; i < 4; ++i) {
#pragma unroll
        for (int j = 0; j < 4; ++j) {
            int n = n0 + wn + j * 16 + r;
            if (n >= NPROJ) continue;
#pragma unroll
            for (int v = 0; v < 4; ++v) {
                int m = m0 + wm + i * 16 + quad * 4 + v;
                float val = acc[i][j][v];
                if (n < DINNER) {
                    zbuf[(size_t)m * DINNER + n] = f2bu(val);
                } else if (n < DINNER + CDIM) {
                    xbcbuf[(size_t)m * CDIM + (n - DINNER)] = f2bu(val);
                } else {
                    int h = n - (DINNER + CDIM);
                    float t = val + dt_bias[h];
                    float sp = (t > 20.f) ? t : log1pf(expf(t));
                    dtbuf[(size_t)m * NH + h] = sp;
                }
            }
        }
    }
}

// ---------------- GEMM2 (MFMA): out = gn @ (w2_hi+w2_lo)^T  (M=25088,N=384,K=768)
__global__ __launch_bounds__(256) void k_gemm2_mfma(
    const ushort* __restrict__ gn, const ushort* __restrict__ wh,
    const ushort* __restrict__ wl, float* __restrict__ out)
{
    __shared__ ushort As[128 * LDSW];
    __shared__ ushort BsH[128 * LDSW];
    __shared__ ushort BsL[128 * LDSW];
    const int m0 = blockIdx.y * 128;
    const int n0 = blockIdx.x * 128;
    const int tid = threadIdx.x;
    const int wid = tid >> 6;
    const int lane = tid & 63;
    const int r = lane & 15;
    const int quad = lane >> 4;
    const int wm = (wid >> 1) * 64;
    const int wn = (wid & 1) * 64;
    const int srow = tid >> 2;
    const int scol = (tid & 3) * 8;

    f32x4 acc[4][4];
#pragma unroll
    for (int i = 0; i < 4; ++i)
#pragma unroll
        for (int j = 0; j < 4; ++j) acc[i][j] = (f32x4){0.f, 0.f, 0.f, 0.f};

    for (int k0 = 0; k0 < DINNER; k0 += 32) {
        size_t aoff0 = (size_t)(m0 + srow)      * DINNER + k0 + scol;
        size_t aoff1 = (size_t)(m0 + srow + 64) * DINNER + k0 + scol;
        size_t boff0 = (size_t)(n0 + srow)      * DINNER + k0 + scol;
        size_t boff1 = (size_t)(n0 + srow + 64) * DINNER + k0 + scol;
        int4 a0  = *(const int4*)(gn + aoff0);
        int4 a1  = *(const int4*)(gn + aoff1);
        int4 bh0 = *(const int4*)(wh + boff0);
        int4 bh1 = *(const int4*)(wh + boff1);
        int4 bl0 = *(const int4*)(wl + boff0);
        int4 bl1 = *(const int4*)(wl + boff1);
        __syncthreads();
        *(int4*)(As + srow * LDSW + scol)         = a0;
        *(int4*)(As + (srow + 64) * LDSW + scol)  = a1;
        *(int4*)(BsH + srow * LDSW + scol)        = bh0;
        *(int4*)(BsH + (srow + 64) * LDSW + scol) = bh1;
        *(int4*)(BsL + srow * LDSW + scol)        = bl0;
        *(int4*)(BsL + (srow + 64) * LDSW + scol) = bl1;
        __syncthreads();
        bf16x8 af[4], bfH[4], bfL[4];
#pragma unroll
        for (int t = 0; t < 4; ++t) {
            af[t]  = *(const bf16x8*)(As + (wm + t * 16 + r) * LDSW + quad * 8);
            bfH[t] = *(const bf16x8*)(BsH + (wn + t * 16 + r) * LDSW + quad * 8);
            bfL[t] = *(const bf16x8*)(BsL + (wn + t * 16 + r) * LDSW + quad * 8);
        }
#pragma unroll
        for (int i = 0; i < 4; ++i)
#pragma unroll
            for (int j = 0; j < 4; ++j) {
                acc[i][j] = __builtin_amdgcn_mfma_f32_16x16x32_bf16(af[i], bfH[j], acc[i][j], 0, 0, 0);
                acc[i][j] = __builtin_amdgcn_mfma_f32_16x16x32_bf16(af[i], bfL[j], acc[i][j], 0, 0, 0);
            }
    }
#pragma unroll
    for (int i = 0; i < 4; ++i) {
#pragma unroll
        for (int j = 0; j < 4; ++j) {
            int n = n0 + wn + j * 16 + r;
#pragma unroll
            for (int v = 0; v < 4; ++v) {
                int m = m0 + wm + i * 16 + quad * 4 + v;
                out[(size_t)m * DMODEL + n] = acc[i][j][v];
            }
        }
    }
}

// ---------------- depthwise 3x3 conv (SAME, cross-correlation) + bias + SiLU ----
__global__ __launch_bounds__(896) void k_conv(
    const bf16* __restrict__ xbc, const float* __restrict__ cw,
    const float* __restrict__ cb, bf16* __restrict__ out)
{
    const int bij = blockIdx.x;
    const int c = threadIdx.x;            // 0..895
    const int b = bij / (HH * WW);
    const int ij = bij % (HH * WW);
    const int i = ij / WW, j = ij % WW;
    float acc = cb[c];
#pragma unroll
    for (int ky = 0; ky < 3; ++ky) {
        int ii = i + ky - 1;
        if (ii < 0 || ii >= HH) continue;
#pragma unroll
        for (int kx = 0; kx < 3; ++kx) {
            int jj = j + kx - 1;
            if (jj < 0 || jj >= WW) continue;
            acc += cw[c * 9 + ky * 3 + kx] * b2f(xbc[((size_t)b * LL + ii * WW + jj) * CDIM + c]);
        }
    }
    float s = acc / (1.f + expf(-acc));   // silu
    out[((size_t)b * LL + ij) * CDIM + c] = f2b(s);
}

// ---------------- fused dx = dt*A*x_in, then 3x3 count-normalized avg pool ------
// out layout: dxp[b][h][l][d]  (bf16, overlaid on d_out)
__global__ __launch_bounds__(768) void k_dxpool(
    const bf16* __restrict__ xbc_conv, const float* __restrict__ dtbuf,
    const float* __restrict__ A_log, bf16* __restrict__ dxp)
{
    const int bl = blockIdx.x;
    const int tid = threadIdx.x;          // 0..767 = h*64+d
    const int b = bl / LL;
    const int l = bl % LL;
    const int i = l / WW, j = l % WW;
    const int h = tid >> 6;
    const int d = tid & 63;
    const float Ahd = -expf(A_log[tid]);
    float sum = 0.f;
    int cnt = 0;
#pragma unroll
    for (int dy = -1; dy <= 1; ++dy) {
        int ii = i + dy;
        if (ii < 0 || ii >= HH) continue;
#pragma unroll
        for (int dxx = -1; dxx <= 1; ++dxx) {
            int jj = j + dxx;
            if (jj < 0 || jj >= WW) continue;
            int ll = ii * WW + jj;
            ++cnt;
            float dtv = dtbuf[((size_t)b * LL + ll) * NH + h];
            float xv = b2f(xbc_conv[((size_t)b * LL + ll) * CDIM + tid]);
            sum += dtv * xv;
        }
    }
    float v = Ahd * sum / (float)cnt;
    dxp[(((size_t)b * NH + h) * LL + l) * HD + d] = f2b(v);
}

// ---------------- h_state[b,h,s,d] = sum_l Bm[b,l,s]*dxp[b,h,l,d]  (split-K) ----
#define SPLITK 8
__global__ __launch_bounds__(256) void k_hstate(
    const bf16* __restrict__ xbc_conv, const bf16* __restrict__ dxp,
    float* __restrict__ hstate)
{
    const int bh = blockIdx.x;            // 0..95
    const int b = bh / NH, h = bh % NH;
    const int lc = blockIdx.y;
    const int l_beg = lc * (LL / SPLITK);
    const int l_end = l_beg + (LL / SPLITK);   // 392, divisible by 8
    __shared__ float Bsh[8][64];
    __shared__ float Dsh[8][64 + 1];
    const int tid = threadIdx.x;
    const int tx = tid & 15;   // d-dir
    const int ty = tid >> 4;   // s-dir
    float acc[4][4];
#pragma unroll
    for (int i = 0; i < 4; ++i)
#pragma unroll
        for (int j = 0; j < 4; ++j) acc[i][j] = 0.f;

    for (int l0 = l_beg; l0 < l_end; l0 += 8) {
#pragma unroll
        for (int idx = tid; idx < 8 * 64; idx += 256) {
            int li = idx >> 6, q = idx & 63;
            Bsh[li][q] = b2f(xbc_conv[((size_t)b * LL + l0 + li) * CDIM + DINNER + q]);
            Dsh[li][q] = b2f(dxp[(((size_t)b * NH + h) * LL + l0 + li) * HD + q]);
        }
        __syncthreads();
#pragma unroll
        for (int li = 0; li < 8; ++li) {
            float a[4], c[4];
#pragma unroll
            for (int i = 0; i < 4; ++i) a[i] = Bsh[li][ty * 4 + i];
#pragma unroll
            for (int j = 0; j < 4; ++j) c[j] = Dsh[li][tx * 4 + j];
#pragma unroll
            for (int i = 0; i < 4; ++i)
#pragma unroll
                for (int j = 0; j < 4; ++j) acc[i][j] += a[i] * c[j];
        }
        __syncthreads();
    }
#pragma unroll
    for (int i = 0; i < 4; ++i)
#pragma unroll
        for (int j = 0; j < 4; ++j) {
            int s = ty * 4 + i, dd = tx * 4 + j;
            atomicAdd(&hstate[((size_t)bh * DS + s) * HD + dd], acc[i][j]);
        }
}

// ---------------- h-prep: hstate fp32 [bh][s][d] -> hT bf16 hi/lo [bh][d][s] ----
__global__ __launch_bounds__(256) void k_hprep(
    const float* __restrict__ hstate, ushort* __restrict__ hT_hi, ushort* __restrict__ hT_lo)
{
    int i = blockIdx.x * 256 + threadIdx.x;   // over 96*4096 = 393216
    int bh = i >> 12;
    int rem = i & 4095;
    int d = rem >> 6, s = rem & 63;
    float v = hstate[((size_t)bh << 12) + s * 64 + d];   // transposed read
    ushort h = f2bu(v);
    hT_hi[i] = h;
    hT_lo[i] = f2bu(v - u2f(h));
}

// ---------------- Ch + y via MFMA: per (b,h), y = Cm[L x 64] @ h[64 x 64] -------
// Block: 256 thr = 4 waves; wave w handles l-chunk (blockIdx.x*4+w)*64 rows.
// B operand = hT (row-major [n=d][k=s]) staged in LDS (stride 72: 2-way-free banks).
#define HTW 72
__global__ __launch_bounds__(256) void k_chy_mfma(
    const ushort* __restrict__ xbc_conv, const ushort* __restrict__ hT_hi,
    const ushort* __restrict__ hT_lo, const float* __restrict__ Dp,
    ushort* __restrict__ ybuf)
{
    __shared__ ushort HsH[64 * HTW];
    __shared__ ushort HsL[64 * HTW];
    const int bh = blockIdx.y;
    const int b = bh / NH, h = bh % NH;
    const int tid = threadIdx.x;
    const int wid = tid >> 6;
    const int lane = tid & 63;
    const int r = lane & 15;
    const int quad = lane >> 4;

    // stage hT hi/lo (64x64 bf16 each) into LDS
    for (int idx = tid; idx < 512; idx += 256) {
        int row = idx >> 3, c8 = (idx & 7) * 8;
        *(int4*)(HsH + row * HTW + c8) = *(const int4*)(hT_hi + ((size_t)bh << 12) + row * 64 + c8);
        *(int4*)(HsL + row * HTW + c8) = *(const int4*)(hT_lo + ((size_t)bh << 12) + row * 64 + c8);
    }
    __syncthreads();

    const int chunk = blockIdx.x * 4 + wid;   // 0..48 valid (49 chunks of 64 l-rows)
    if (chunk >= 49) return;
    const int l0 = chunk * 64;

    f32x4 acc[4][4];
#pragma unroll
    for (int i = 0; i < 4; ++i)
#pragma unroll
        for (int j = 0; j < 4; ++j) acc[i][j] = (f32x4){0.f, 0.f, 0.f, 0.f};

#pragma unroll
    for (int kk = 0; kk < 2; ++kk) {          // K=64 in two 32-steps
        bf16x8 af[4], bfH[4], bfL[4];
#pragma unroll
        for (int t = 0; t < 4; ++t) {
            // A = Cm row (l0 + t*16 + r), cols kk*32 + quad*8 (global, K-contig)
            af[t] = *(const bf16x8*)(xbc_conv +
                ((size_t)(b * LL + l0 + t * 16 + r)) * CDIM + DINNER + DS + kk * 32 + quad * 8);
            bfH[t] = *(const bf16x8*)(HsH + (t * 16 + r) * HTW + kk * 32 + quad * 8);
            bfL[t] = *(const bf16x8*)(HsL + (t * 16 + r) * HTW + kk * 32 + quad * 8);
        }
#pragma unroll
        for (int i = 0; i < 4; ++i)
#pragma unroll
            for (int j = 0; j < 4; ++j) {
                acc[i][j] = __builtin_amdgcn_mfma_f32_16x16x32_bf16(af[i], bfH[j], acc[i][j], 0, 0, 0);
                acc[i][j] = __builtin_amdgcn_mfma_f32_16x16x32_bf16(af[i], bfL[j], acc[i][j], 0, 0, 0);
            }
    }
    // epilogue: y[b,l,h*64+d] = acc + x_in * D[h];  m=l row = quad*4+v, n=d col = r
    const float Dh = Dp[h];
#pragma unroll
    for (int i = 0; i < 4; ++i) {
#pragma unroll
        for (int j = 0; j < 4; ++j) {
            int d = j * 16 + r;
#pragma unroll
            for (int v = 0; v < 4; ++v) {
                int l = l0 + i * 16 + quad * 4 + v;
                float xv = u2f(xbc_conv[((size_t)(b * LL + l)) * CDIM + h * HD + d]);
                ybuf[((size_t)(b * LL + l)) * DINNER + h * HD + d] = f2bu(acc[i][j][v] + xv * Dh);
            }
        }
    }
}

// ---------------- g = y*silu(z); LayerNorm(768) -> gn ---------------------------
__global__ __launch_bounds__(256) void k_gln(
    const bf16* __restrict__ ybuf, const bf16* __restrict__ zbuf,
    const float* __restrict__ nw, const float* __restrict__ nb,
    bf16* __restrict__ gnbuf)
{
    const int bl = blockIdx.x;
    const int tid = threadIdx.x;   // 256
    __shared__ float s_sum[4], s_sq[4];
    float g[3];
    float sum = 0.f, sumsq = 0.f;
#pragma unroll
    for (int r = 0; r < 3; ++r) {
        int c = tid + r * 256;
        float yv = b2f(ybuf[(size_t)bl * DINNER + c]);
        float zv = b2f(zbuf[(size_t)bl * DINNER + c]);
        float gv = yv * (zv / (1.f + expf(-zv)));
        g[r] = gv;
        sum += gv;
        sumsq += gv * gv;
    }
#pragma unroll
    for (int off = 32; off > 0; off >>= 1) {
        sum += __shfl_down(sum, off, 64);
        sumsq += __shfl_down(sumsq, off, 64);
    }
    const int wave = tid >> 6, lane = tid & 63;
    if (lane == 0) { s_sum[wave] = sum; s_sq[wave] = sumsq; }
    __syncthreads();
    if (tid == 0) {
        float a = 0.f, b2 = 0.f;
#pragma unroll
        for (int w2 = 0; w2 < 4; ++w2) { a += s_sum[w2]; b2 += s_sq[w2]; }
        float mu = a / (float)DINNER;
        float var = b2 / (float)DINNER - mu * mu;
        s_sum[0] = mu;
        s_sq[0] = rsqrtf(var + LN_EPS);
    }
    __syncthreads();
    const float mu = s_sum[0], rstd = s_sq[0];
#pragma unroll
    for (int r = 0; r < 3; ++r) {
        int c = tid + r * 256;
        gnbuf[(size_t)bl * DINNER + c] = f2b((g[r] - mu) * rstd * nw[c] + nb[c]);
    }
}

extern "C" void kernel_launch(void* const* d_in, const int* in_sizes, int n_in,
                              void* d_out, int out_size, void* d_ws, size_t ws_size,
                              hipStream_t stream)
{
    const float* x         = (const float*)d_in[0];
    const float* in_proj_w = (const float*)d_in[1];
    const float* conv_w    = (const float*)d_in[2];
    const float* conv_b    = (const float*)d_in[3];
    const float* dt_bias   = (const float*)d_in[4];
    const float* A_log     = (const float*)d_in[5];
    const float* Dp        = (const float*)d_in[6];
    const float* norm_w    = (const float*)d_in[7];
    const float* norm_b    = (const float*)d_in[8];
    const float* out_proj_w= (const float*)d_in[9];

    // workspace layout (bytes), high-water 133,783,552 (same as passing round 4):
    char* wsb = (char*)d_ws;
    float*  dtbuf   = (float*) (wsb + 0);           //  1,204,224 fp32 MTOT*NH
    float*  hstate  = (float*) (wsb + 1204224);     //  1,572,864 fp32
    ushort* w1_lo   = (ushort*)(wsb + 1204224);     //  aliases hstate (1,376,256 <= 1,572,864);
                                                    //  hstate memset AFTER gemm1
    ushort* w1_hi   = (ushort*)(wsb + 2777088);     //  1,376,256 bf16 NPAD*384
    ushort* w2_hi   = (ushort*)(wsb + 4153344);     //    589,824 bf16 384*768
    ushort* zbuf    = (ushort*)(wsb + 4743168);     // 38,535,168 bf16 MTOT*DINNER
    ushort* xbcraw  = (ushort*)(wsb + 43278336);    // 44,957,696 bf16 MTOT*CDIM
    ushort* xbcconv = (ushort*)(wsb + 88236032);    // 44,957,696 bf16 MTOT*CDIM
    ushort* w2_lo   = (ushort*)(wsb + 133193728);   //    589,824 bf16
    // x_hi/x_lo (bf16 casts of x, 19.3 MB each) alias xbcconv: dead after gemm1.
    ushort* x_hi    = xbcconv;
    ushort* x_lo    = xbcconv + (size_t)MTOT * DMODEL;
    // hT hi/lo (96*4096 bf16 each = 786,432 B each) alias xbcraw: raw xBC dead
    // after k_conv; gnbuf (also xbcraw) written only at k_gln, after k_chy.
    ushort* hT_hi   = xbcraw;
    ushort* hT_lo   = xbcraw + 96 * 4096;
    // dxp / ybuf (bf16, 38.5 MB) overlaid on d_out; consumed before final GEMM write
    bf16*   dxp     = (bf16*)d_out;
    ushort* ybuf    = (ushort*)d_out;
    ushort* gnbuf   = xbcraw;          // raw xBC dead after k_conv (and hT consumed)

    k_cast_x <<<MTOT * DMODEL / 4 / 256, 256, 0, stream>>>(
        (const float4*)x, (ushort4*)x_hi, (ushort4*)x_lo);
    k_cast_w1<<<NPAD * DMODEL / 4 / 256, 256, 0, stream>>>(
        in_proj_w, (ushort4*)w1_hi, (ushort4*)w1_lo);
    k_cast_w2<<<DMODEL * DINNER / 4 / 256, 256, 0, stream>>>(
        (const float4*)out_proj_w, (ushort4*)w2_hi, (ushort4*)w2_lo);

    k_gemm1_mfma<<<dim3(NPAD / 128, MTOT / 128), 256, 0, stream>>>(
        x_hi, x_lo, w1_hi, w1_lo, dt_bias, zbuf, xbcraw, dtbuf);

    // hstate memset AFTER gemm1 (w1_lo aliases this region)
    hipMemsetAsync(hstate, 0, (size_t)BB * NH * DS * HD * sizeof(float), stream);

    k_conv<<<BB * LL, CDIM, 0, stream>>>((const bf16*)xbcraw, conv_w, conv_b, (bf16*)xbcconv);
    k_dxpool<<<BB * LL, DINNER, 0, stream>>>((const bf16*)xbcconv, dtbuf, A_log, dxp);
    k_hstate<<<dim3(BB * NH, SPLITK), 256, 0, stream>>>((const bf16*)xbcconv, (const bf16*)dxp, hstate);
    k_hprep<<<96 * 4096 / 256, 256, 0, stream>>>(hstate, hT_hi, hT_lo);
    k_chy_mfma<<<dim3(13, BB * NH), 256, 0, stream>>>(
        xbcconv, hT_hi, hT_lo, Dp, ybuf);
    k_gln<<<BB * LL, 256, 0, stream>>>((const bf16*)ybuf, (const bf16*)zbuf, norm_w, norm_b, (bf16*)gnbuf);
    k_gemm2_mfma<<<dim3(DMODEL / 128, MTOT / 128), 256, 0, stream>>>(
        gnbuf, w2_hi, w2_lo, (float*)d_out);
}

// Round 6
// 560.396 us; speedup vs baseline: 3.0470x; 1.3568x over previous
//
#include <hip/hip_runtime.h>
#include <hip/hip_bf16.h>
#include <math.h>

// Problem constants (fixed by setup_inputs: B=8, H=W=56)
#define BB 8
#define HH 56
#define WW 56
#define LL (HH*WW)          // 3136
#define DMODEL 384
#define DINNER 768
#define NH 12
#define HD 64
#define DS 64
#define CDIM (DINNER + 2*DS)    // 896
#define NPROJ (2*DINNER + 2*DS + NH) // 1676
#define NPAD 1792           // NPROJ padded to multiple of 128
#define MTOT (BB*LL)        // 25088
#define LN_EPS 1e-5f
#define NCG (CDIM/8)        // 112 channel-groups for conv
#define NDG (DINNER/8)      // 96 channel-groups for dxpool

typedef __hip_bfloat16 bf16;
typedef __attribute__((ext_vector_type(8))) __bf16 bf16x8;
typedef __attribute__((ext_vector_type(4))) float f32x4;

__device__ __forceinline__ float b2f(bf16 v) { return __bfloat162float(v); }
__device__ __forceinline__ bf16 f2b(float v) { return __float2bfloat16(v); }
__device__ __forceinline__ ushort f2bu(float v) {
    union { bf16 h; ushort u; } cv; cv.h = __float2bfloat16(v); return cv.u;
}
__device__ __forceinline__ float u2f(ushort u) {
    union { ushort u; bf16 h; } cv; cv.u = u; return __bfloat162float(cv.h);
}

// ---------------- cast kernels: fp32 -> bf16 hi + bf16 lo residual --------------
__global__ __launch_bounds__(256) void k_cast_x(
    const float4* __restrict__ in, ushort4* __restrict__ hi, ushort4* __restrict__ lo)
{
    int i = blockIdx.x * 256 + threadIdx.x;    // grid sized exactly
    float4 v = in[i];
    ushort4 h, l;
    h.x = f2bu(v.x); h.y = f2bu(v.y); h.z = f2bu(v.z); h.w = f2bu(v.w);
    l.x = f2bu(v.x - u2f(h.x)); l.y = f2bu(v.y - u2f(h.y));
    l.z = f2bu(v.z - u2f(h.z)); l.w = f2bu(v.w - u2f(h.w));
    hi[i] = h; lo[i] = l;
}

// w1 hi/lo [n][k], n<NPAD: zero-padded rows beyond NPROJ
__global__ __launch_bounds__(256) void k_cast_w1(
    const float* __restrict__ w, ushort4* __restrict__ hi, ushort4* __restrict__ lo)
{
    int i = blockIdx.x * 256 + threadIdx.x;   // over NPAD*384/4 = 172032
    int n = i / (DMODEL / 4);
    int k = (i % (DMODEL / 4)) * 4;
    ushort4 h = {0,0,0,0}, l = {0,0,0,0};
    if (n < NPROJ) {
        float4 v = *(const float4*)(w + (size_t)n * DMODEL + k);
        h.x = f2bu(v.x); h.y = f2bu(v.y); h.z = f2bu(v.z); h.w = f2bu(v.w);
        l.x = f2bu(v.x - u2f(h.x)); l.y = f2bu(v.y - u2f(h.y));
        l.z = f2bu(v.z - u2f(h.z)); l.w = f2bu(v.w - u2f(h.w));
    }
    hi[i] = h; lo[i] = l;
}

__global__ __launch_bounds__(256) void k_cast_w2(
    const float4* __restrict__ in, ushort4* __restrict__ hi, ushort4* __restrict__ lo)
{
    int i = blockIdx.x * 256 + threadIdx.x;   // over 384*768/4 = 73728
    float4 v = in[i];
    ushort4 h, l;
    h.x = f2bu(v.x); h.y = f2bu(v.y); h.z = f2bu(v.z); h.w = f2bu(v.w);
    l.x = f2bu(v.x - u2f(h.x)); l.y = f2bu(v.y - u2f(h.y));
    l.z = f2bu(v.z - u2f(h.z)); l.w = f2bu(v.w - u2f(h.w));
    hi[i] = h; lo[i] = l;
}

// ---------------- GEMM1 (MFMA, split-bf16): zxbcdt = x @ in_proj_w^T ------------
// M=25088, N=1792(pad), K=384. NT layout, 128x128 tile, BK=32, 4 waves 2x2.
// A and B both split hi/lo; acc += aH*bH + aL*bH + aH*bL  (fp32-grade inputs).
#define LDSW 40
__global__ __launch_bounds__(256) void k_gemm1_mfma(
    const ushort* __restrict__ xh, const ushort* __restrict__ xl,
    const ushort* __restrict__ wh, const ushort* __restrict__ wl,
    const float* __restrict__ dt_bias,
    ushort* __restrict__ zbuf, ushort* __restrict__ xbcbuf, float* __restrict__ dtbuf)
{
    __shared__ ushort AsH[128 * LDSW];
    __shared__ ushort AsL[128 * LDSW];
    __shared__ ushort BsH[128 * LDSW];
    __shared__ ushort BsL[128 * LDSW];
    const int m0 = blockIdx.y * 128;
    const int n0 = blockIdx.x * 128;
    const int tid = threadIdx.x;
    const int wid = tid >> 6;
    const int lane = tid & 63;
    const int r = lane & 15;
    const int quad = lane >> 4;
    const int wm = (wid >> 1) * 64;
    const int wn = (wid & 1) * 64;
    const int srow = tid >> 2;        // 0..63
    const int scol = (tid & 3) * 8;   // 0,8,16,24

    f32x4 acc[4][4];
#pragma unroll
    for (int i = 0; i < 4; ++i)
#pragma unroll
        for (int j = 0; j < 4; ++j) acc[i][j] = (f32x4){0.f, 0.f, 0.f, 0.f};

    for (int k0 = 0; k0 < DMODEL; k0 += 32) {
        size_t aoff0 = (size_t)(m0 + srow)      * DMODEL + k0 + scol;
        size_t aoff1 = (size_t)(m0 + srow + 64) * DMODEL + k0 + scol;
        size_t boff0 = (size_t)(n0 + srow)      * DMODEL + k0 + scol;
        size_t boff1 = (size_t)(n0 + srow + 64) * DMODEL + k0 + scol;
        int4 ah0 = *(const int4*)(xh + aoff0);
        int4 ah1 = *(const int4*)(xh + aoff1);
        int4 al0 = *(const int4*)(xl + aoff0);
        int4 al1 = *(const int4*)(xl + aoff1);
        int4 bh0 = *(const int4*)(wh + boff0);
        int4 bh1 = *(const int4*)(wh + boff1);
        int4 bl0 = *(const int4*)(wl + boff0);
        int4 bl1 = *(const int4*)(wl + boff1);
        __syncthreads();
        *(int4*)(AsH + srow * LDSW + scol)        = ah0;
        *(int4*)(AsH + (srow + 64) * LDSW + scol) = ah1;
        *(int4*)(AsL + srow * LDSW + scol)        = al0;
        *(int4*)(AsL + (srow + 64) * LDSW + scol) = al1;
        *(int4*)(BsH + srow * LDSW + scol)        = bh0;
        *(int4*)(BsH + (srow + 64) * LDSW + scol) = bh1;
        *(int4*)(BsL + srow * LDSW + scol)        = bl0;
        *(int4*)(BsL + (srow + 64) * LDSW + scol) = bl1;
        __syncthreads();
        bf16x8 afH[4], afL[4], bfH[4], bfL[4];
#pragma unroll
        for (int t = 0; t < 4; ++t) {
            afH[t] = *(const bf16x8*)(AsH + (wm + t * 16 + r) * LDSW + quad * 8);
            afL[t] = *(const bf16x8*)(AsL + (wm + t * 16 + r) * LDSW + quad * 8);
            bfH[t] = *(const bf16x8*)(BsH + (wn + t * 16 + r) * LDSW + quad * 8);
            bfL[t] = *(const bf16x8*)(BsL + (wn + t * 16 + r) * LDSW + quad * 8);
        }
#pragma unroll
        for (int i = 0; i < 4; ++i)
#pragma unroll
            for (int j = 0; j < 4; ++j) {
                acc[i][j] = __builtin_amdgcn_mfma_f32_16x16x32_bf16(afH[i], bfH[j], acc[i][j], 0, 0, 0);
                acc[i][j] = __builtin_amdgcn_mfma_f32_16x16x32_bf16(afL[i], bfH[j], acc[i][j], 0, 0, 0);
                acc[i][j] = __builtin_amdgcn_mfma_f32_16x16x32_bf16(afH[i], bfL[j], acc[i][j], 0, 0, 0);
            }
    }
    // epilogue: D row = quad*4+v (m), col = r (n); split by n
#pragma unroll
    for (int i = 0; i < 4; ++i) {
#pragma unroll
        for (int j = 0; j < 4; ++j) {
            int n = n0 + wn + j * 16 + r;
            if (n >= NPROJ) continue;
#pragma unroll
            for (int v = 0; v < 4; ++v) {
                int m = m0 + wm + i * 16 + quad * 4 + v;
                float val = acc[i][j][v];
                if (n < DINNER) {
                    zbuf[(size_t)m * DINNER + n] = f2bu(val);
                } else if (n < DINNER + CDIM) {
                    xbcbuf[(size_t)m * CDIM + (n - DINNER)] = f2bu(val);
                } else {
                    int h = n - (DINNER + CDIM);
                    float t = val + dt_bias[h];
                    float sp = (t > 20.f) ? t : log1pf(expf(t));
                    dtbuf[(size_t)m * NH + h] = sp;
                }
            }
        }
    }
}

// ---------------- GEMM2 (MFMA): out = gn @ (w2_hi+w2_lo)^T  (M=25088,N=384,K=768)
__global__ __launch_bounds__(256) void k_gemm2_mfma(
    const ushort* __restrict__ gn, const ushort* __restrict__ wh,
    const ushort* __restrict__ wl, float* __restrict__ out)
{
    __shared__ ushort As[128 * LDSW];
    __shared__ ushort BsH[128 * LDSW];
    __shared__ ushort BsL[128 * LDSW];
    const int m0 = blockIdx.y * 128;
    const int n0 = blockIdx.x * 128;
    const int tid = threadIdx.x;
    const int wid = tid >> 6;
    const int lane = tid & 63;
    const int r = lane & 15;
    const int quad = lane >> 4;
    const int wm = (wid >> 1) * 64;
    const int wn = (wid & 1) * 64;
    const int srow = tid >> 2;
    const int scol = (tid & 3) * 8;

    f32x4 acc[4][4];
#pragma unroll
    for (int i = 0; i < 4; ++i)
#pragma unroll
        for (int j = 0; j < 4; ++j) acc[i][j] = (f32x4){0.f, 0.f, 0.f, 0.f};

    for (int k0 = 0; k0 < DINNER; k0 += 32) {
        size_t aoff0 = (size_t)(m0 + srow)      * DINNER + k0 + scol;
        size_t aoff1 = (size_t)(m0 + srow + 64) * DINNER + k0 + scol;
        size_t boff0 = (size_t)(n0 + srow)      * DINNER + k0 + scol;
        size_t boff1 = (size_t)(n0 + srow + 64) * DINNER + k0 + scol;
        int4 a0  = *(const int4*)(gn + aoff0);
        int4 a1  = *(const int4*)(gn + aoff1);
        int4 bh0 = *(const int4*)(wh + boff0);
        int4 bh1 = *(const int4*)(wh + boff1);
        int4 bl0 = *(const int4*)(wl + boff0);
        int4 bl1 = *(const int4*)(wl + boff1);
        __syncthreads();
        *(int4*)(As + srow * LDSW + scol)         = a0;
        *(int4*)(As + (srow + 64) * LDSW + scol)  = a1;
        *(int4*)(BsH + srow * LDSW + scol)        = bh0;
        *(int4*)(BsH + (srow + 64) * LDSW + scol) = bh1;
        *(int4*)(BsL + srow * LDSW + scol)        = bl0;
        *(int4*)(BsL + (srow + 64) * LDSW + scol) = bl1;
        __syncthreads();
        bf16x8 af[4], bfH[4], bfL[4];
#pragma unroll
        for (int t = 0; t < 4; ++t) {
            af[t]  = *(const bf16x8*)(As + (wm + t * 16 + r) * LDSW + quad * 8);
            bfH[t] = *(const bf16x8*)(BsH + (wn + t * 16 + r) * LDSW + quad * 8);
            bfL[t] = *(const bf16x8*)(BsL + (wn + t * 16 + r) * LDSW + quad * 8);
        }
#pragma unroll
        for (int i = 0; i < 4; ++i)
#pragma unroll
            for (int j = 0; j < 4; ++j) {
                acc[i][j] = __builtin_amdgcn_mfma_f32_16x16x32_bf16(af[i], bfH[j], acc[i][j], 0, 0, 0);
                acc[i][j] = __builtin_amdgcn_mfma_f32_16x16x32_bf16(af[i], bfL[j], acc[i][j], 0, 0, 0);
            }
    }
#pragma unroll
    for (int i = 0; i < 4; ++i) {
#pragma unroll
        for (int j = 0; j < 4; ++j) {
            int n = n0 + wn + j * 16 + r;
#pragma unroll
            for (int v = 0; v < 4; ++v) {
                int m = m0 + wm + i * 16 + quad * 4 + v;
                out[(size_t)m * DMODEL + n] = acc[i][j][v];
            }
        }
    }
}

// ---------------- depthwise 3x3 conv + bias + SiLU, 8-channel vectorized --------
// thread = (pixel, channel-group-of-8). 9 bf16x8 taps + 18 float4 weight loads.
__global__ __launch_bounds__(256) void k_conv(
    const ushort* __restrict__ xbc, const float* __restrict__ cw,
    const float* __restrict__ cb, ushort* __restrict__ out)
{
    const int gid = blockIdx.x * 256 + threadIdx.x;  // over MTOT*NCG = 2,809,856
    const int cg  = gid % NCG;
    const int pix = gid / NCG;
    const int b = pix / LL, ij = pix % LL;
    const int i = ij / WW, j = ij % WW;
    const int c0 = cg * 8;

    // weights for channels c0..c0+7: 72 consecutive floats (cw is [c][9])
    float wreg[72];
#pragma unroll
    for (int t = 0; t < 18; ++t)
        *(float4*)(wreg + t * 4) = *(const float4*)(cw + c0 * 9 + t * 4);
    float acc[8];
    {
        float4 b0 = *(const float4*)(cb + c0);
        float4 b1 = *(const float4*)(cb + c0 + 4);
        acc[0]=b0.x; acc[1]=b0.y; acc[2]=b0.z; acc[3]=b0.w;
        acc[4]=b1.x; acc[5]=b1.y; acc[6]=b1.z; acc[7]=b1.w;
    }
#pragma unroll
    for (int ky = 0; ky < 3; ++ky) {
        int ii = i + ky - 1;
        if (ii < 0 || ii >= HH) continue;
#pragma unroll
        for (int kx = 0; kx < 3; ++kx) {
            int jj = j + kx - 1;
            if (jj < 0 || jj >= WW) continue;
            union { int4 q; ushort u[8]; } xv;
            xv.q = *(const int4*)(xbc + ((size_t)b * LL + ii * WW + jj) * CDIM + c0);
            int t = ky * 3 + kx;
#pragma unroll
            for (int q = 0; q < 8; ++q)
                acc[q] += wreg[q * 9 + t] * u2f(xv.u[q]);
        }
    }
    union { int4 q; ushort u[8]; } o;
#pragma unroll
    for (int q = 0; q < 8; ++q) {
        float s = acc[q] / (1.f + expf(-acc[q]));
        o.u[q] = f2bu(s);
    }
    *(int4*)(out + (size_t)pix * CDIM + c0) = o.q;
}

// ---------------- fused dx = dt*A*x_in + 3x3 count-norm avg pool, 8-wide --------
// thread = (pixel, channel-group-of-8 over DINNER). out: dxp[b][h][l][d]
__global__ __launch_bounds__(256) void k_dxpool(
    const ushort* __restrict__ xbc_conv, const float* __restrict__ dtbuf,
    const float* __restrict__ A_log, ushort* __restrict__ dxp)
{
    const int gid = blockIdx.x * 256 + threadIdx.x;  // over MTOT*NDG = 2,408,448
    const int cg  = gid % NDG;
    const int pix = gid / NDG;
    const int b = pix / LL, l = pix % LL;
    const int i = l / WW, j = l % WW;
    const int c0 = cg * 8;         // channel in [0,768)
    const int h = c0 >> 6;

    float Ah[8];
    {
        float4 a0 = *(const float4*)(A_log + c0);
        float4 a1 = *(const float4*)(A_log + c0 + 4);
        Ah[0]=a0.x; Ah[1]=a0.y; Ah[2]=a0.z; Ah[3]=a0.w;
        Ah[4]=a1.x; Ah[5]=a1.y; Ah[6]=a1.z; Ah[7]=a1.w;
    }
#pragma unroll
    for (int q = 0; q < 8; ++q) Ah[q] = -expf(Ah[q]);

    float sum[8] = {0.f,0.f,0.f,0.f,0.f,0.f,0.f,0.f};
    int cnt = 0;
#pragma unroll
    for (int dy = -1; dy <= 1; ++dy) {
        int ii = i + dy;
        if (ii < 0 || ii >= HH) continue;
#pragma unroll
        for (int dxx = -1; dxx <= 1; ++dxx) {
            int jj = j + dxx;
            if (jj < 0 || jj >= WW) continue;
            int ll = ii * WW + jj;
            ++cnt;
            float dtv = dtbuf[((size_t)b * LL + ll) * NH + h];
            union { int4 q; ushort u[8]; } xv;
            xv.q = *(const int4*)(xbc_conv + ((size_t)b * LL + ll) * CDIM + c0);
#pragma unroll
            for (int q = 0; q < 8; ++q)
                sum[q] += dtv * u2f(xv.u[q]);
        }
    }
    float inv = 1.f / (float)cnt;
    union { int4 q; ushort u[8]; } o;
#pragma unroll
    for (int q = 0; q < 8; ++q)
        o.u[q] = f2bu(Ah[q] * sum[q] * inv);
    *(int4*)(dxp + (((size_t)b * NH + h) * LL + l) * HD + (c0 & 63)) = o.q;
}

// ---------------- h_state[b,h,s,d] = sum_l Bm[b,l,s]*dxp[b,h,l,d]  (split-K) ----
#define SPLITK 8
__global__ __launch_bounds__(256) void k_hstate(
    const bf16* __restrict__ xbc_conv, const bf16* __restrict__ dxp,
    float* __restrict__ hstate)
{
    const int bh = blockIdx.x;            // 0..95
    const int b = bh / NH, h = bh % NH;
    const int lc = blockIdx.y;
    const int l_beg = lc * (LL / SPLITK);
    const int l_end = l_beg + (LL / SPLITK);   // 392, divisible by 8
    __shared__ float Bsh[8][64];
    __shared__ float Dsh[8][64 + 1];
    const int tid = threadIdx.x;
    const int tx = tid & 15;   // d-dir
    const int ty = tid >> 4;   // s-dir
    float acc[4][4];
#pragma unroll
    for (int i = 0; i < 4; ++i)
#pragma unroll
        for (int j = 0; j < 4; ++j) acc[i][j] = 0.f;

    for (int l0 = l_beg; l0 < l_end; l0 += 8) {
#pragma unroll
        for (int idx = tid; idx < 8 * 64; idx += 256) {
            int li = idx >> 6, q = idx & 63;
            Bsh[li][q] = b2f(xbc_conv[((size_t)b * LL + l0 + li) * CDIM + DINNER + q]);
            Dsh[li][q] = b2f(dxp[(((size_t)b * NH + h) * LL + l0 + li) * HD + q]);
        }
        __syncthreads();
#pragma unroll
        for (int li = 0; li < 8; ++li) {
            float a[4], c[4];
#pragma unroll
            for (int i = 0; i < 4; ++i) a[i] = Bsh[li][ty * 4 + i];
#pragma unroll
            for (int j = 0; j < 4; ++j) c[j] = Dsh[li][tx * 4 + j];
#pragma unroll
            for (int i = 0; i < 4; ++i)
#pragma unroll
                for (int j = 0; j < 4; ++j) acc[i][j] += a[i] * c[j];
        }
        __syncthreads();
    }
#pragma unroll
    for (int i = 0; i < 4; ++i)
#pragma unroll
        for (int j = 0; j < 4; ++j) {
            int s = ty * 4 + i, dd = tx * 4 + j;
            atomicAdd(&hstate[((size_t)bh * DS + s) * HD + dd], acc[i][j]);
        }
}

// ---------------- h-prep: hstate fp32 [bh][s][d] -> hT bf16 hi/lo [bh][d][s] ----
__global__ __launch_bounds__(256) void k_hprep(
    const float* __restrict__ hstate, ushort* __restrict__ hT_hi, ushort* __restrict__ hT_lo)
{
    int i = blockIdx.x * 256 + threadIdx.x;   // over 96*4096 = 393216
    int bh = i >> 12;
    int rem = i & 4095;
    int d = rem >> 6, s = rem & 63;
    float v = hstate[((size_t)bh << 12) + s * 64 + d];   // transposed read
    ushort h = f2bu(v);
    hT_hi[i] = h;
    hT_lo[i] = f2bu(v - u2f(h));
}

// ---------------- Ch + y via MFMA: per (b,h), y = Cm[L x 64] @ h[64 x 64] -------
#define HTW 72
__global__ __launch_bounds__(256) void k_chy_mfma(
    const ushort* __restrict__ xbc_conv, const ushort* __restrict__ hT_hi,
    const ushort* __restrict__ hT_lo, const float* __restrict__ Dp,
    ushort* __restrict__ ybuf)
{
    __shared__ ushort HsH[64 * HTW];
    __shared__ ushort HsL[64 * HTW];
    const int bh = blockIdx.y;
    const int b = bh / NH, h = bh % NH;
    const int tid = threadIdx.x;
    const int wid = tid >> 6;
    const int lane = tid & 63;
    const int r = lane & 15;
    const int quad = lane >> 4;

    for (int idx = tid; idx < 512; idx += 256) {
        int row = idx >> 3, c8 = (idx & 7) * 8;
        *(int4*)(HsH + row * HTW + c8) = *(const int4*)(hT_hi + ((size_t)bh << 12) + row * 64 + c8);
        *(int4*)(HsL + row * HTW + c8) = *(const int4*)(hT_lo + ((size_t)bh << 12) + row * 64 + c8);
    }
    __syncthreads();

    const int chunk = blockIdx.x * 4 + wid;   // 0..48 valid (49 chunks of 64 l-rows)
    if (chunk >= 49) return;
    const int l0 = chunk * 64;

    f32x4 acc[4][4];
#pragma unroll
    for (int i = 0; i < 4; ++i)
#pragma unroll
        for (int j = 0; j < 4; ++j) acc[i][j] = (f32x4){0.f, 0.f, 0.f, 0.f};

#pragma unroll
    for (int kk = 0; kk < 2; ++kk) {          // K=64 in two 32-steps
        bf16x8 af[4], bfH[4], bfL[4];
#pragma unroll
        for (int t = 0; t < 4; ++t) {
            af[t] = *(const bf16x8*)(xbc_conv +
                ((size_t)(b * LL + l0 + t * 16 + r)) * CDIM + DINNER + DS + kk * 32 + quad * 8);
            bfH[t] = *(const bf16x8*)(HsH + (t * 16 + r) * HTW + kk * 32 + quad * 8);
            bfL[t] = *(const bf16x8*)(HsL + (t * 16 + r) * HTW + kk * 32 + quad * 8);
        }
#pragma unroll
        for (int i = 0; i < 4; ++i)
#pragma unroll
            for (int j = 0; j < 4; ++j) {
                acc[i][j] = __builtin_amdgcn_mfma_f32_16x16x32_bf16(af[i], bfH[j], acc[i][j], 0, 0, 0);
                acc[i][j] = __builtin_amdgcn_mfma_f32_16x16x32_bf16(af[i], bfL[j], acc[i][j], 0, 0, 0);
            }
    }
    const float Dh = Dp[h];
#pragma unroll
    for (int i = 0; i < 4; ++i) {
#pragma unroll
        for (int j = 0; j < 4; ++j) {
            int d = j * 16 + r;
#pragma unroll
            for (int v = 0; v < 4; ++v) {
                int l = l0 + i * 16 + quad * 4 + v;
                float xv = u2f(xbc_conv[((size_t)(b * LL + l)) * CDIM + h * HD + d]);
                ybuf[((size_t)(b * LL + l)) * DINNER + h * HD + d] = f2bu(acc[i][j][v] + xv * Dh);
            }
        }
    }
}

// ---------------- g = y*silu(z); LayerNorm(768) -> gn ---------------------------
__global__ __launch_bounds__(256) void k_gln(
    const bf16* __restrict__ ybuf, const bf16* __restrict__ zbuf,
    const float* __restrict__ nw, const float* __restrict__ nb,
    bf16* __restrict__ gnbuf)
{
    const int bl = blockIdx.x;
    const int tid = threadIdx.x;   // 256
    __shared__ float s_sum[4], s_sq[4];
    float g[3];
    float sum = 0.f, sumsq = 0.f;
#pragma unroll
    for (int r = 0; r < 3; ++r) {
        int c = tid + r * 256;
        float yv = b2f(ybuf[(size_t)bl * DINNER + c]);
        float zv = b2f(zbuf[(size_t)bl * DINNER + c]);
        float gv = yv * (zv / (1.f + expf(-zv)));
        g[r] = gv;
        sum += gv;
        sumsq += gv * gv;
    }
#pragma unroll
    for (int off = 32; off > 0; off >>= 1) {
        sum += __shfl_down(sum, off, 64);
        sumsq += __shfl_down(sumsq, off, 64);
    }
    const int wave = tid >> 6, lane = tid & 63;
    if (lane == 0) { s_sum[wave] = sum; s_sq[wave] = sumsq; }
    __syncthreads();
    if (tid == 0) {
        float a = 0.f, b2 = 0.f;
#pragma unroll
        for (int w2 = 0; w2 < 4; ++w2) { a += s_sum[w2]; b2 += s_sq[w2]; }
        float mu = a / (float)DINNER;
        float var = b2 / (float)DINNER - mu * mu;
        s_sum[0] = mu;
        s_sq[0] = rsqrtf(var + LN_EPS);
    }
    __syncthreads();
    const float mu = s_sum[0], rstd = s_sq[0];
#pragma unroll
    for (int r = 0; r < 3; ++r) {
        int c = tid + r * 256;
        gnbuf[(size_t)bl * DINNER + c] = f2b((g[r] - mu) * rstd * nw[c] + nb[c]);
    }
}

extern "C" void kernel_launch(void* const* d_in, const int* in_sizes, int n_in,
                              void* d_out, int out_size, void* d_ws, size_t ws_size,
                              hipStream_t stream)
{
    const float* x         = (const float*)d_in[0];
    const float* in_proj_w = (const float*)d_in[1];
    const float* conv_w    = (const float*)d_in[2];
    const float* conv_b    = (const float*)d_in[3];
    const float* dt_bias   = (const float*)d_in[4];
    const float* A_log     = (const float*)d_in[5];
    const float* Dp        = (const float*)d_in[6];
    const float* norm_w    = (const float*)d_in[7];
    const float* norm_b    = (const float*)d_in[8];
    const float* out_proj_w= (const float*)d_in[9];

    // workspace layout (bytes), high-water 133,783,552 (same as passing round 4):
    char* wsb = (char*)d_ws;
    float*  dtbuf   = (float*) (wsb + 0);           //  1,204,224 fp32 MTOT*NH
    float*  hstate  = (float*) (wsb + 1204224);     //  1,572,864 fp32
    ushort* w1_lo   = (ushort*)(wsb + 1204224);     //  aliases hstate; memset AFTER gemm1
    ushort* w1_hi   = (ushort*)(wsb + 2777088);     //  1,376,256 bf16 NPAD*384
    ushort* w2_hi   = (ushort*)(wsb + 4153344);     //    589,824 bf16 384*768
    ushort* zbuf    = (ushort*)(wsb + 4743168);     // 38,535,168 bf16 MTOT*DINNER
    ushort* xbcraw  = (ushort*)(wsb + 43278336);    // 44,957,696 bf16 MTOT*CDIM
    ushort* xbcconv = (ushort*)(wsb + 88236032);    // 44,957,696 bf16 MTOT*CDIM
    ushort* w2_lo   = (ushort*)(wsb + 133193728);   //    589,824 bf16
    ushort* x_hi    = xbcconv;                      // dead after gemm1
    ushort* x_lo    = xbcconv + (size_t)MTOT * DMODEL;
    ushort* hT_hi   = xbcraw;                       // raw xBC dead after k_conv
    ushort* hT_lo   = xbcraw + 96 * 4096;
    bf16*   dxp     = (bf16*)d_out;                 // consumed before final GEMM write
    ushort* ybuf    = (ushort*)d_out;
    ushort* gnbuf   = xbcraw;

    k_cast_x <<<MTOT * DMODEL / 4 / 256, 256, 0, stream>>>(
        (const float4*)x, (ushort4*)x_hi, (ushort4*)x_lo);
    k_cast_w1<<<NPAD * DMODEL / 4 / 256, 256, 0, stream>>>(
        in_proj_w, (ushort4*)w1_hi, (ushort4*)w1_lo);
    k_cast_w2<<<DMODEL * DINNER / 4 / 256, 256, 0, stream>>>(
        (const float4*)out_proj_w, (ushort4*)w2_hi, (ushort4*)w2_lo);

    k_gemm1_mfma<<<dim3(NPAD / 128, MTOT / 128), 256, 0, stream>>>(
        x_hi, x_lo, w1_hi, w1_lo, dt_bias, zbuf, xbcraw, dtbuf);

    // hstate memset AFTER gemm1 (w1_lo aliases this region)
    hipMemsetAsync(hstate, 0, (size_t)BB * NH * DS * HD * sizeof(float), stream);

    k_conv<<<MTOT * NCG / 256, 256, 0, stream>>>(
        xbcraw, conv_w, conv_b, xbcconv);
    k_dxpool<<<MTOT * NDG / 256, 256, 0, stream>>>(
        xbcconv, dtbuf, A_log, (ushort*)dxp);
    k_hstate<<<dim3(BB * NH, SPLITK), 256, 0, stream>>>(
        (const bf16*)xbcconv, (const bf16*)dxp, hstate);
    k_hprep<<<96 * 4096 / 256, 256, 0, stream>>>(hstate, hT_hi, hT_lo);
    k_chy_mfma<<<dim3(13, BB * NH), 256, 0, stream>>>(
        xbcconv, hT_hi, hT_lo, Dp, ybuf);
    k_gln<<<BB * LL, 256, 0, stream>>>(
        (const bf16*)ybuf, (const bf16*)zbuf, norm_w, norm_b, (bf16*)gnbuf);
    k_gemm2_mfma<<<dim3(DMODEL / 128, MTOT / 128), 256, 0, stream>>>(
        gnbuf, w2_hi, w2_lo, (float*)d_out);
}

// Round 7
// 503.625 us; speedup vs baseline: 3.3905x; 1.1127x over previous
//
#include <hip/hip_runtime.h>
#include <hip/hip_bf16.h>
#include <math.h>

// Problem constants (fixed by setup_inputs: B=8, H=W=56)
#define BB 8
#define HH 56
#define WW 56
#define LL (HH*WW)          // 3136
#define DMODEL 384
#define DINNER 768
#define NH 12
#define HD 64
#define DS 64
#define CDIM (DINNER + 2*DS)    // 896
#define NPROJ (2*DINNER + 2*DS + NH) // 1676
#define NPAD 1792           // NPROJ padded to multiple of 128
#define MTOT (BB*LL)        // 25088
#define LN_EPS 1e-5f
#define NCG (CDIM/8)        // 112 channel-groups for conv
#define NDG (DINNER/8)      // 96 channel-groups for dxpool
#define SPLITL 7            // L-chunks for hstate (3136/7 = 448)

typedef __hip_bfloat16 bf16;
typedef __attribute__((ext_vector_type(8))) __bf16 bf16x8;
typedef __attribute__((ext_vector_type(4))) float f32x4;

__device__ __forceinline__ float b2f(bf16 v) { return __bfloat162float(v); }
__device__ __forceinline__ bf16 f2b(float v) { return __float2bfloat16(v); }
__device__ __forceinline__ ushort f2bu(float v) {
    union { bf16 h; ushort u; } cv; cv.h = __float2bfloat16(v); return cv.u;
}
__device__ __forceinline__ float u2f(ushort u) {
    union { ushort u; bf16 h; } cv; cv.u = u; return __bfloat162float(cv.h);
}

// ---------------- cast kernels: fp32 -> bf16 hi + bf16 lo residual --------------
__global__ __launch_bounds__(256) void k_cast_x(
    const float4* __restrict__ in, ushort4* __restrict__ hi, ushort4* __restrict__ lo)
{
    int i = blockIdx.x * 256 + threadIdx.x;    // grid sized exactly
    float4 v = in[i];
    ushort4 h, l;
    h.x = f2bu(v.x); h.y = f2bu(v.y); h.z = f2bu(v.z); h.w = f2bu(v.w);
    l.x = f2bu(v.x - u2f(h.x)); l.y = f2bu(v.y - u2f(h.y));
    l.z = f2bu(v.z - u2f(h.z)); l.w = f2bu(v.w - u2f(h.w));
    hi[i] = h; lo[i] = l;
}

// w1 hi/lo [n][k], n<NPAD: zero-padded rows beyond NPROJ
__global__ __launch_bounds__(256) void k_cast_w1(
    const float* __restrict__ w, ushort4* __restrict__ hi, ushort4* __restrict__ lo)
{
    int i = blockIdx.x * 256 + threadIdx.x;   // over NPAD*384/4 = 172032
    int n = i / (DMODEL / 4);
    int k = (i % (DMODEL / 4)) * 4;
    ushort4 h = {0,0,0,0}, l = {0,0,0,0};
    if (n < NPROJ) {
        float4 v = *(const float4*)(w + (size_t)n * DMODEL + k);
        h.x = f2bu(v.x); h.y = f2bu(v.y); h.z = f2bu(v.z); h.w = f2bu(v.w);
        l.x = f2bu(v.x - u2f(h.x)); l.y = f2bu(v.y - u2f(h.y));
        l.z = f2bu(v.z - u2f(h.z)); l.w = f2bu(v.w - u2f(h.w));
    }
    hi[i] = h; lo[i] = l;
}

__global__ __launch_bounds__(256) void k_cast_w2(
    const float4* __restrict__ in, ushort4* __restrict__ hi, ushort4* __restrict__ lo)
{
    int i = blockIdx.x * 256 + threadIdx.x;   // over 384*768/4 = 73728
    float4 v = in[i];
    ushort4 h, l;
    h.x = f2bu(v.x); h.y = f2bu(v.y); h.z = f2bu(v.z); h.w = f2bu(v.w);
    l.x = f2bu(v.x - u2f(h.x)); l.y = f2bu(v.y - u2f(h.y));
    l.z = f2bu(v.z - u2f(h.z)); l.w = f2bu(v.w - u2f(h.w));
    hi[i] = h; lo[i] = l;
}

// ---------------- GEMM1 (MFMA, split-bf16): zxbcdt = x @ in_proj_w^T ------------
// M=25088, N=1792(pad), K=384. NT layout, 128x128 tile, BK=32, 4 waves 2x2.
// A and B both split hi/lo; acc += aH*bH + aL*bH + aH*bL  (fp32-grade inputs).
#define LDSW 40
__global__ __launch_bounds__(256) void k_gemm1_mfma(
    const ushort* __restrict__ xh, const ushort* __restrict__ xl,
    const ushort* __restrict__ wh, const ushort* __restrict__ wl,
    const float* __restrict__ dt_bias,
    ushort* __restrict__ zbuf, ushort* __restrict__ xbcbuf, float* __restrict__ dtbuf)
{
    __shared__ ushort AsH[128 * LDSW];
    __shared__ ushort AsL[128 * LDSW];
    __shared__ ushort BsH[128 * LDSW];
    __shared__ ushort BsL[128 * LDSW];
    const int m0 = blockIdx.y * 128;
    const int n0 = blockIdx.x * 128;
    const int tid = threadIdx.x;
    const int wid = tid >> 6;
    const int lane = tid & 63;
    const int r = lane & 15;
    const int quad = lane >> 4;
    const int wm = (wid >> 1) * 64;
    const int wn = (wid & 1) * 64;
    const int srow = tid >> 2;        // 0..63
    const int scol = (tid & 3) * 8;   // 0,8,16,24

    f32x4 acc[4][4];
#pragma unroll
    for (int i = 0; i < 4; ++i)
#pragma unroll
        for (int j = 0; j < 4; ++j) acc[i][j] = (f32x4){0.f, 0.f, 0.f, 0.f};

    for (int k0 = 0; k0 < DMODEL; k0 += 32) {
        size_t aoff0 = (size_t)(m0 + srow)      * DMODEL + k0 + scol;
        size_t aoff1 = (size_t)(m0 + srow + 64) * DMODEL + k0 + scol;
        size_t boff0 = (size_t)(n0 + srow)      * DMODEL + k0 + scol;
        size_t boff1 = (size_t)(n0 + srow + 64) * DMODEL + k0 + scol;
        int4 ah0 = *(const int4*)(xh + aoff0);
        int4 ah1 = *(const int4*)(xh + aoff1);
        int4 al0 = *(const int4*)(xl + aoff0);
        int4 al1 = *(const int4*)(xl + aoff1);
        int4 bh0 = *(const int4*)(wh + boff0);
        int4 bh1 = *(const int4*)(wh + boff1);
        int4 bl0 = *(const int4*)(wl + boff0);
        int4 bl1 = *(const int4*)(wl + boff1);
        __syncthreads();
        *(int4*)(AsH + srow * LDSW + scol)        = ah0;
        *(int4*)(AsH + (srow + 64) * LDSW + scol) = ah1;
        *(int4*)(AsL + srow * LDSW + scol)        = al0;
        *(int4*)(AsL + (srow + 64) * LDSW + scol) = al1;
        *(int4*)(BsH + srow * LDSW + scol)        = bh0;
        *(int4*)(BsH + (srow + 64) * LDSW + scol) = bh1;
        *(int4*)(BsL + srow * LDSW + scol)        = bl0;
        *(int4*)(BsL + (srow + 64) * LDSW + scol) = bl1;
        __syncthreads();
        bf16x8 afH[4], afL[4], bfH[4], bfL[4];
#pragma unroll
        for (int t = 0; t < 4; ++t) {
            afH[t] = *(const bf16x8*)(AsH + (wm + t * 16 + r) * LDSW + quad * 8);
            afL[t] = *(const bf16x8*)(AsL + (wm + t * 16 + r) * LDSW + quad * 8);
            bfH[t] = *(const bf16x8*)(BsH + (wn + t * 16 + r) * LDSW + quad * 8);
            bfL[t] = *(const bf16x8*)(BsL + (wn + t * 16 + r) * LDSW + quad * 8);
        }
#pragma unroll
        for (int i = 0; i < 4; ++i)
#pragma unroll
            for (int j = 0; j < 4; ++j) {
                acc[i][j] = __builtin_amdgcn_mfma_f32_16x16x32_bf16(afH[i], bfH[j], acc[i][j], 0, 0, 0);
                acc[i][j] = __builtin_amdgcn_mfma_f32_16x16x32_bf16(afL[i], bfH[j], acc[i][j], 0, 0, 0);
                acc[i][j] = __builtin_amdgcn_mfma_f32_16x16x32_bf16(afH[i], bfL[j], acc[i][j], 0, 0, 0);
            }
    }
    // epilogue: D row = quad*4+v (m), col = r (n); split by n
#pragma unroll
    for (int i = 0; i < 4; ++i) {
#pragma unroll
        for (int j = 0; j < 4; ++j) {
            int n = n0 + wn + j * 16 + r;
            if (n >= NPROJ) continue;
#pragma unroll
            for (int v = 0; v < 4; ++v) {
                int m = m0 + wm + i * 16 + quad * 4 + v;
                float val = acc[i][j][v];
                if (n < DINNER) {
                    zbuf[(size_t)m * DINNER + n] = f2bu(val);
                } else if (n < DINNER + CDIM) {
                    xbcbuf[(size_t)m * CDIM + (n - DINNER)] = f2bu(val);
                } else {
                    int h = n - (DINNER + CDIM);
                    float t = val + dt_bias[h];
                    float sp = (t > 20.f) ? t : log1pf(expf(t));
                    dtbuf[(size_t)m * NH + h] = sp;
                }
            }
        }
    }
}

// ---------------- GEMM2 (MFMA): out = gn @ (w2_hi+w2_lo)^T  (M=25088,N=384,K=768)
__global__ __launch_bounds__(256) void k_gemm2_mfma(
    const ushort* __restrict__ gn, const ushort* __restrict__ wh,
    const ushort* __restrict__ wl, float* __restrict__ out)
{
    __shared__ ushort As[128 * LDSW];
    __shared__ ushort BsH[128 * LDSW];
    __shared__ ushort BsL[128 * LDSW];
    const int m0 = blockIdx.y * 128;
    const int n0 = blockIdx.x * 128;
    const int tid = threadIdx.x;
    const int wid = tid >> 6;
    const int lane = tid & 63;
    const int r = lane & 15;
    const int quad = lane >> 4;
    const int wm = (wid >> 1) * 64;
    const int wn = (wid & 1) * 64;
    const int srow = tid >> 2;
    const int scol = (tid & 3) * 8;

    f32x4 acc[4][4];
#pragma unroll
    for (int i = 0; i < 4; ++i)
#pragma unroll
        for (int j = 0; j < 4; ++j) acc[i][j] = (f32x4){0.f, 0.f, 0.f, 0.f};

    for (int k0 = 0; k0 < DINNER; k0 += 32) {
        size_t aoff0 = (size_t)(m0 + srow)      * DINNER + k0 + scol;
        size_t aoff1 = (size_t)(m0 + srow + 64) * DINNER + k0 + scol;
        size_t boff0 = (size_t)(n0 + srow)      * DINNER + k0 + scol;
        size_t boff1 = (size_t)(n0 + srow + 64) * DINNER + k0 + scol;
        int4 a0  = *(const int4*)(gn + aoff0);
        int4 a1  = *(const int4*)(gn + aoff1);
        int4 bh0 = *(const int4*)(wh + boff0);
        int4 bh1 = *(const int4*)(wh + boff1);
        int4 bl0 = *(const int4*)(wl + boff0);
        int4 bl1 = *(const int4*)(wl + boff1);
        __syncthreads();
        *(int4*)(As + srow * LDSW + scol)         = a0;
        *(int4*)(As + (srow + 64) * LDSW + scol)  = a1;
        *(int4*)(BsH + srow * LDSW + scol)        = bh0;
        *(int4*)(BsH + (srow + 64) * LDSW + scol) = bh1;
        *(int4*)(BsL + srow * LDSW + scol)        = bl0;
        *(int4*)(BsL + (srow + 64) * LDSW + scol) = bl1;
        __syncthreads();
        bf16x8 af[4], bfH[4], bfL[4];
#pragma unroll
        for (int t = 0; t < 4; ++t) {
            af[t]  = *(const bf16x8*)(As + (wm + t * 16 + r) * LDSW + quad * 8);
            bfH[t] = *(const bf16x8*)(BsH + (wn + t * 16 + r) * LDSW + quad * 8);
            bfL[t] = *(const bf16x8*)(BsL + (wn + t * 16 + r) * LDSW + quad * 8);
        }
#pragma unroll
        for (int i = 0; i < 4; ++i)
#pragma unroll
            for (int j = 0; j < 4; ++j) {
                acc[i][j] = __builtin_amdgcn_mfma_f32_16x16x32_bf16(af[i], bfH[j], acc[i][j], 0, 0, 0);
                acc[i][j] = __builtin_amdgcn_mfma_f32_16x16x32_bf16(af[i], bfL[j], acc[i][j], 0, 0, 0);
            }
    }
#pragma unroll
    for (int i = 0; i < 4; ++i) {
#pragma unroll
        for (int j = 0; j < 4; ++j) {
            int n = n0 + wn + j * 16 + r;
#pragma unroll
            for (int v = 0; v < 4; ++v) {
                int m = m0 + wm + i * 16 + quad * 4 + v;
                out[(size_t)m * DMODEL + n] = acc[i][j][v];
            }
        }
    }
}

// ---------------- depthwise 3x3 conv + bias + SiLU, 8-channel vectorized --------
__global__ __launch_bounds__(256) void k_conv(
    const ushort* __restrict__ xbc, const float* __restrict__ cw,
    const float* __restrict__ cb, ushort* __restrict__ out)
{
    const int gid = blockIdx.x * 256 + threadIdx.x;  // over MTOT*NCG = 2,809,856
    const int cg  = gid % NCG;
    const int pix = gid / NCG;
    const int b = pix / LL, ij = pix % LL;
    const int i = ij / WW, j = ij % WW;
    const int c0 = cg * 8;

    float wreg[72];
#pragma unroll
    for (int t = 0; t < 18; ++t)
        *(float4*)(wreg + t * 4) = *(const float4*)(cw + c0 * 9 + t * 4);
    float acc[8];
    {
        float4 b0 = *(const float4*)(cb + c0);
        float4 b1 = *(const float4*)(cb + c0 + 4);
        acc[0]=b0.x; acc[1]=b0.y; acc[2]=b0.z; acc[3]=b0.w;
        acc[4]=b1.x; acc[5]=b1.y; acc[6]=b1.z; acc[7]=b1.w;
    }
#pragma unroll
    for (int ky = 0; ky < 3; ++ky) {
        int ii = i + ky - 1;
        if (ii < 0 || ii >= HH) continue;
#pragma unroll
        for (int kx = 0; kx < 3; ++kx) {
            int jj = j + kx - 1;
            if (jj < 0 || jj >= WW) continue;
            union { int4 q; ushort u[8]; } xv;
            xv.q = *(const int4*)(xbc + ((size_t)b * LL + ii * WW + jj) * CDIM + c0);
            int t = ky * 3 + kx;
#pragma unroll
            for (int q = 0; q < 8; ++q)
                acc[q] += wreg[q * 9 + t] * u2f(xv.u[q]);
        }
    }
    union { int4 q; ushort u[8]; } o;
#pragma unroll
    for (int q = 0; q < 8; ++q) {
        float s = acc[q] / (1.f + expf(-acc[q]));
        o.u[q] = f2bu(s);
    }
    *(int4*)(out + (size_t)pix * CDIM + c0) = o.q;
}

// ---------------- fused dx = dt*A*x_in + 3x3 count-norm avg pool, 8-wide --------
__global__ __launch_bounds__(256) void k_dxpool(
    const ushort* __restrict__ xbc_conv, const float* __restrict__ dtbuf,
    const float* __restrict__ A_log, ushort* __restrict__ dxp)
{
    const int gid = blockIdx.x * 256 + threadIdx.x;  // over MTOT*NDG = 2,408,448
    const int cg  = gid % NDG;
    const int pix = gid / NDG;
    const int b = pix / LL, l = pix % LL;
    const int i = l / WW, j = l % WW;
    const int c0 = cg * 8;         // channel in [0,768)
    const int h = c0 >> 6;

    float Ah[8];
    {
        float4 a0 = *(const float4*)(A_log + c0);
        float4 a1 = *(const float4*)(A_log + c0 + 4);
        Ah[0]=a0.x; Ah[1]=a0.y; Ah[2]=a0.z; Ah[3]=a0.w;
        Ah[4]=a1.x; Ah[5]=a1.y; Ah[6]=a1.z; Ah[7]=a1.w;
    }
#pragma unroll
    for (int q = 0; q < 8; ++q) Ah[q] = -expf(Ah[q]);

    float sum[8] = {0.f,0.f,0.f,0.f,0.f,0.f,0.f,0.f};
    int cnt = 0;
#pragma unroll
    for (int dy = -1; dy <= 1; ++dy) {
        int ii = i + dy;
        if (ii < 0 || ii >= HH) continue;
#pragma unroll
        for (int dxx = -1; dxx <= 1; ++dxx) {
            int jj = j + dxx;
            if (jj < 0 || jj >= WW) continue;
            int ll = ii * WW + jj;
            ++cnt;
            float dtv = dtbuf[((size_t)b * LL + ll) * NH + h];
            union { int4 q; ushort u[8]; } xv;
            xv.q = *(const int4*)(xbc_conv + ((size_t)b * LL + ll) * CDIM + c0);
#pragma unroll
            for (int q = 0; q < 8; ++q)
                sum[q] += dtv * u2f(xv.u[q]);
        }
    }
    float inv = 1.f / (float)cnt;
    union { int4 q; ushort u[8]; } o;
#pragma unroll
    for (int q = 0; q < 8; ++q)
        o.u[q] = f2bu(Ah[q] * sum[q] * inv);
    *(int4*)(dxp + (((size_t)b * NH + h) * LL + l) * HD + (c0 & 63)) = o.q;
}

// ---------------- h_state via MFMA (no atomics): Ht_part[d][s] ------------------
// Per block (lc, bh): K-chunk of 448 l. Stage 32-l tiles of dxp->[d][l], Bm->[s][l]
// in LDS (stride 33: conflict-free scatter writes), MFMA A=dxp(m=d) B=Bm(n=s).
// Partials hpart[lc][bh][d][s] fp32, reduced in k_hprep.
#define LDSP 33
__global__ __launch_bounds__(256) void k_hstate_mfma(
    const ushort* __restrict__ xbc_conv, const ushort* __restrict__ dxp,
    float* __restrict__ hpart)
{
    __shared__ ushort DsT[64 * LDSP];   // [d][l]
    __shared__ ushort BsT[64 * LDSP];   // [s][l]
    const int lc = blockIdx.x;          // 0..6
    const int bh = blockIdx.y;          // 0..95
    const int b = bh / NH, h = bh % NH;
    const int tid = threadIdx.x;
    const int wid = tid >> 6;
    const int lane = tid & 63;
    const int r = lane & 15;
    const int quad = lane >> 4;
    const int wd = (wid >> 1) * 32;     // d-offset of wave quadrant
    const int wsn = (wid & 1) * 32;     // s-offset
    const int lt = tid >> 3;            // 0..31 (l within tile)
    const int sg = (tid & 7) * 8;       // 0,8,..,56 (channel group)

    f32x4 acc[2][2];
#pragma unroll
    for (int i = 0; i < 2; ++i)
#pragma unroll
        for (int j = 0; j < 2; ++j) acc[i][j] = (f32x4){0.f, 0.f, 0.f, 0.f};

    const int l_base = lc * (LL / SPLITL);    // 448-chunk
    for (int step = 0; step < (LL / SPLITL) / 32; ++step) {
        int l0 = l_base + step * 32;
        union { int4 q; ushort u[8]; } dv, bv;
        dv.q = *(const int4*)(dxp + (((size_t)bh) * LL + l0 + lt) * HD + sg);
        bv.q = *(const int4*)(xbc_conv + ((size_t)(b * LL + l0 + lt)) * CDIM + DINNER + sg);
        __syncthreads();
#pragma unroll
        for (int q = 0; q < 8; ++q) {
            DsT[(sg + q) * LDSP + lt] = dv.u[q];
            BsT[(sg + q) * LDSP + lt] = bv.u[q];
        }
        __syncthreads();
        bf16x8 af[2], bf[2];
#pragma unroll
        for (int t = 0; t < 2; ++t) {
            af[t] = *(const bf16x8*)(DsT + (wd + t * 16 + r) * LDSP + quad * 8);
            bf[t] = *(const bf16x8*)(BsT + (wsn + t * 16 + r) * LDSP + quad * 8);
        }
#pragma unroll
        for (int i = 0; i < 2; ++i)
#pragma unroll
            for (int j = 0; j < 2; ++j)
                acc[i][j] = __builtin_amdgcn_mfma_f32_16x16x32_bf16(af[i], bf[j], acc[i][j], 0, 0, 0);
    }
    // C layout: m=d row = quad*4+v, n=s col = r.  Store fp32 partial [d][s].
    float* outp = hpart + ((size_t)(lc * 96 + bh) << 12);
#pragma unroll
    for (int i = 0; i < 2; ++i)
#pragma unroll
        for (int j = 0; j < 2; ++j)
#pragma unroll
            for (int v = 0; v < 4; ++v)
                outp[(wd + i * 16 + quad * 4 + v) * 64 + (wsn + j * 16 + r)] = acc[i][j][v];
}

// ---------------- h-prep: reduce 7 partials [d][s] -> hT bf16 hi/lo [bh][d][s] --
__global__ __launch_bounds__(256) void k_hprep(
    const float* __restrict__ hpart, ushort* __restrict__ hT_hi, ushort* __restrict__ hT_lo)
{
    int i = blockIdx.x * 256 + threadIdx.x;   // over 96*4096 = 393216
    int bh = i >> 12;
    int rem = i & 4095;                       // = d*64+s
    float v = 0.f;
#pragma unroll
    for (int lc = 0; lc < SPLITL; ++lc)
        v += hpart[((size_t)(lc * 96 + bh) << 12) + rem];
    ushort h = f2bu(v);
    hT_hi[i] = h;
    hT_lo[i] = f2bu(v - u2f(h));
}

// ---------------- Ch + y via MFMA: per (b,h), y = Cm[L x 64] @ h[64 x 64] -------
#define HTW 72
__global__ __launch_bounds__(256) void k_chy_mfma(
    const ushort* __restrict__ xbc_conv, const ushort* __restrict__ hT_hi,
    const ushort* __restrict__ hT_lo, const float* __restrict__ Dp,
    ushort* __restrict__ ybuf)
{
    __shared__ ushort HsH[64 * HTW];
    __shared__ ushort HsL[64 * HTW];
    const int bh = blockIdx.y;
    const int b = bh / NH, h = bh % NH;
    const int tid = threadIdx.x;
    const int wid = tid >> 6;
    const int lane = tid & 63;
    const int r = lane & 15;
    const int quad = lane >> 4;

    for (int idx = tid; idx < 512; idx += 256) {
        int row = idx >> 3, c8 = (idx & 7) * 8;
        *(int4*)(HsH + row * HTW + c8) = *(const int4*)(hT_hi + ((size_t)bh << 12) + row * 64 + c8);
        *(int4*)(HsL + row * HTW + c8) = *(const int4*)(hT_lo + ((size_t)bh << 12) + row * 64 + c8);
    }
    __syncthreads();

    const int chunk = blockIdx.x * 4 + wid;   // 0..48 valid (49 chunks of 64 l-rows)
    if (chunk >= 49) return;
    const int l0 = chunk * 64;

    f32x4 acc[4][4];
#pragma unroll
    for (int i = 0; i < 4; ++i)
#pragma unroll
        for (int j = 0; j < 4; ++j) acc[i][j] = (f32x4){0.f, 0.f, 0.f, 0.f};

#pragma unroll
    for (int kk = 0; kk < 2; ++kk) {          // K=64 in two 32-steps
        bf16x8 af[4], bfH[4], bfL[4];
#pragma unroll
        for (int t = 0; t < 4; ++t) {
            af[t] = *(const bf16x8*)(xbc_conv +
                ((size_t)(b * LL + l0 + t * 16 + r)) * CDIM + DINNER + DS + kk * 32 + quad * 8);
            bfH[t] = *(const bf16x8*)(HsH + (t * 16 + r) * HTW + kk * 32 + quad * 8);
            bfL[t] = *(const bf16x8*)(HsL + (t * 16 + r) * HTW + kk * 32 + quad * 8);
        }
#pragma unroll
        for (int i = 0; i < 4; ++i)
#pragma unroll
            for (int j = 0; j < 4; ++j) {
                acc[i][j] = __builtin_amdgcn_mfma_f32_16x16x32_bf16(af[i], bfH[j], acc[i][j], 0, 0, 0);
                acc[i][j] = __builtin_amdgcn_mfma_f32_16x16x32_bf16(af[i], bfL[j], acc[i][j], 0, 0, 0);
            }
    }
    const float Dh = Dp[h];
#pragma unroll
    for (int i = 0; i < 4; ++i) {
#pragma unroll
        for (int j = 0; j < 4; ++j) {
            int d = j * 16 + r;
#pragma unroll
            for (int v = 0; v < 4; ++v) {
                int l = l0 + i * 16 + quad * 4 + v;
                float xv = u2f(xbc_conv[((size_t)(b * LL + l)) * CDIM + h * HD + d]);
                ybuf[((size_t)(b * LL + l)) * DINNER + h * HD + d] = f2bu(acc[i][j][v] + xv * Dh);
            }
        }
    }
}

// ---------------- g = y*silu(z); LayerNorm(768), wave-per-row -------------------
__global__ __launch_bounds__(256) void k_gln(
    const ushort* __restrict__ ybuf, const ushort* __restrict__ zbuf,
    const float* __restrict__ nw, const float* __restrict__ nb,
    ushort* __restrict__ gnbuf)
{
    const int row = blockIdx.x * 4 + (threadIdx.x >> 6);
    const int lane = threadIdx.x & 63;
    const size_t base = (size_t)row * DINNER;

    float g[12];
    float sum = 0.f, sumsq = 0.f;
#pragma unroll
    for (int p = 0; p < 3; ++p) {
        int c = lane * 4 + p * 256;
        union { ushort4 q; ushort u[4]; } yv, zv;
        yv.q = *(const ushort4*)(ybuf + base + c);
        zv.q = *(const ushort4*)(zbuf + base + c);
#pragma unroll
        for (int q = 0; q < 4; ++q) {
            float y = u2f(yv.u[q]);
            float z = u2f(zv.u[q]);
            float gv = y * (z / (1.f + expf(-z)));
            g[p * 4 + q] = gv;
            sum += gv;
            sumsq += gv * gv;
        }
    }
#pragma unroll
    for (int off = 32; off > 0; off >>= 1) {
        sum += __shfl_xor(sum, off, 64);
        sumsq += __shfl_xor(sumsq, off, 64);
    }
    const float mu = sum / (float)DINNER;
    const float var = sumsq / (float)DINNER - mu * mu;
    const float rstd = rsqrtf(var + LN_EPS);
#pragma unroll
    for (int p = 0; p < 3; ++p) {
        int c = lane * 4 + p * 256;
        float4 w = *(const float4*)(nw + c);
        float4 bb = *(const float4*)(nb + c);
        union { ushort4 q; ushort u[4]; } o;
        o.u[0] = f2bu((g[p*4+0] - mu) * rstd * w.x + bb.x);
        o.u[1] = f2bu((g[p*4+1] - mu) * rstd * w.y + bb.y);
        o.u[2] = f2bu((g[p*4+2] - mu) * rstd * w.z + bb.z);
        o.u[3] = f2bu((g[p*4+3] - mu) * rstd * w.w + bb.w);
        *(ushort4*)(gnbuf + base + c) = o.q;
    }
}

extern "C" void kernel_launch(void* const* d_in, const int* in_sizes, int n_in,
                              void* d_out, int out_size, void* d_ws, size_t ws_size,
                              hipStream_t stream)
{
    const float* x         = (const float*)d_in[0];
    const float* in_proj_w = (const float*)d_in[1];
    const float* conv_w    = (const float*)d_in[2];
    const float* conv_b    = (const float*)d_in[3];
    const float* dt_bias   = (const float*)d_in[4];
    const float* A_log     = (const float*)d_in[5];
    const float* Dp        = (const float*)d_in[6];
    const float* norm_w    = (const float*)d_in[7];
    const float* norm_b    = (const float*)d_in[8];
    const float* out_proj_w= (const float*)d_in[9];

    // workspace layout (bytes), high-water 133,783,552 (known-good):
    char* wsb = (char*)d_ws;
    float*  dtbuf   = (float*) (wsb + 0);           //  1,204,224 fp32 MTOT*NH
    ushort* w1_lo   = (ushort*)(wsb + 1204224);     //  1,376,256 bf16 (old hstate slot)
    ushort* w1_hi   = (ushort*)(wsb + 2777088);     //  1,376,256 bf16 NPAD*384
    ushort* w2_hi   = (ushort*)(wsb + 4153344);     //    589,824 bf16 384*768
    ushort* zbuf    = (ushort*)(wsb + 4743168);     // 38,535,168 bf16 MTOT*DINNER
    ushort* xbcraw  = (ushort*)(wsb + 43278336);    // 44,957,696 bf16 MTOT*CDIM
    ushort* xbcconv = (ushort*)(wsb + 88236032);    // 44,957,696 bf16 MTOT*CDIM
    ushort* w2_lo   = (ushort*)(wsb + 133193728);   //    589,824 bf16
    ushort* x_hi    = xbcconv;                      // dead after gemm1
    ushort* x_lo    = xbcconv + (size_t)MTOT * DMODEL;
    // within dead xbcraw region (raw xBC dead after k_conv):
    ushort* hT_hi   = xbcraw;                       //   786,432 B
    ushort* hT_lo   = xbcraw + 96 * 4096;           //   786,432 B
    float*  hpart   = (float*)(wsb + 44851200);     // 11,010,048 B (7*96*4096 fp32)
    bf16*   dxp     = (bf16*)d_out;                 // consumed before final GEMM write
    ushort* ybuf    = (ushort*)d_out;
    ushort* gnbuf   = xbcraw;                       // clobbers hT/hpart after consumed

    k_cast_x <<<MTOT * DMODEL / 4 / 256, 256, 0, stream>>>(
        (const float4*)x, (ushort4*)x_hi, (ushort4*)x_lo);
    k_cast_w1<<<NPAD * DMODEL / 4 / 256, 256, 0, stream>>>(
        in_proj_w, (ushort4*)w1_hi, (ushort4*)w1_lo);
    k_cast_w2<<<DMODEL * DINNER / 4 / 256, 256, 0, stream>>>(
        (const float4*)out_proj_w, (ushort4*)w2_hi, (ushort4*)w2_lo);

    k_gemm1_mfma<<<dim3(NPAD / 128, MTOT / 128), 256, 0, stream>>>(
        x_hi, x_lo, w1_hi, w1_lo, dt_bias, zbuf, xbcraw, dtbuf);

    k_conv<<<MTOT * NCG / 256, 256, 0, stream>>>(
        xbcraw, conv_w, conv_b, xbcconv);
    k_dxpool<<<MTOT * NDG / 256, 256, 0, stream>>>(
        xbcconv, dtbuf, A_log, (ushort*)dxp);
    k_hstate_mfma<<<dim3(SPLITL, BB * NH), 256, 0, stream>>>(
        xbcconv, (const ushort*)dxp, hpart);
    k_hprep<<<96 * 4096 / 256, 256, 0, stream>>>(hpart, hT_hi, hT_lo);
    k_chy_mfma<<<dim3(13, BB * NH), 256, 0, stream>>>(
        xbcconv, hT_hi, hT_lo, Dp, ybuf);
    k_gln<<<MTOT / 4, 256, 0, stream>>>(
        ybuf, zbuf, norm_w, norm_b, gnbuf);
    k_gemm2_mfma<<<dim3(DMODEL / 128, MTOT / 128), 256, 0, stream>>>(
        gnbuf, w2_hi, w2_lo, (float*)d_out);
}

// Round 8
// 425.359 us; speedup vs baseline: 4.0144x; 1.1840x over previous
//
#include <hip/hip_runtime.h>
#include <hip/hip_bf16.h>
#include <math.h>

// Problem constants (fixed by setup_inputs: B=8, H=W=56)
#define BB 8
#define HH 56
#define WW 56
#define LL (HH*WW)          // 3136
#define DMODEL 384
#define DINNER 768
#define NH 12
#define HD 64
#define DS 64
#define CDIM (DINNER + 2*DS)    // 896
#define NPROJ (2*DINNER + 2*DS + NH) // 1676
#define NPAD 1792           // NPROJ padded to multiple of 128
#define MTOT (BB*LL)        // 25088
#define LN_EPS 1e-5f
#define NCG (CDIM/8)        // 112 channel-groups for conv
#define NDG (DINNER/8)      // 96 channel-groups for dxpool
#define SPLITL 7            // L-chunks for hstate (3136/7 = 448)

typedef __attribute__((ext_vector_type(8))) _Float16 f16x8;
typedef __attribute__((ext_vector_type(4))) float f32x4;

// f16 <-> f32 with bits in ushort
__device__ __forceinline__ ushort f2hu(float v) {
    union { _Float16 h; ushort u; } cv; cv.h = (_Float16)v; return cv.u;
}
__device__ __forceinline__ float hu2f(ushort u) {
    union { ushort u; _Float16 h; } cv; cv.u = u; return (float)cv.h;
}

// ---------------- cast kernels: fp32 -> f16 -------------------------------------
__global__ __launch_bounds__(256) void k_cast_x(
    const float4* __restrict__ in, ushort4* __restrict__ out)
{
    int i = blockIdx.x * 256 + threadIdx.x;    // grid sized exactly
    float4 v = in[i];
    ushort4 h;
    h.x = f2hu(v.x); h.y = f2hu(v.y); h.z = f2hu(v.z); h.w = f2hu(v.w);
    out[i] = h;
}

// w1 [n][k], n<NPAD: zero-padded rows beyond NPROJ
__global__ __launch_bounds__(256) void k_cast_w1(
    const float* __restrict__ w, ushort4* __restrict__ out)
{
    int i = blockIdx.x * 256 + threadIdx.x;   // over NPAD*384/4 = 172032
    int n = i / (DMODEL / 4);
    int k = (i % (DMODEL / 4)) * 4;
    ushort4 h = {0,0,0,0};
    if (n < NPROJ) {
        float4 v = *(const float4*)(w + (size_t)n * DMODEL + k);
        h.x = f2hu(v.x); h.y = f2hu(v.y); h.z = f2hu(v.z); h.w = f2hu(v.w);
    }
    out[i] = h;
}

__global__ __launch_bounds__(256) void k_cast_w2(
    const float4* __restrict__ in, ushort4* __restrict__ out)
{
    int i = blockIdx.x * 256 + threadIdx.x;   // over 384*768/4 = 73728
    float4 v = in[i];
    ushort4 h;
    h.x = f2hu(v.x); h.y = f2hu(v.y); h.z = f2hu(v.z); h.w = f2hu(v.w);
    out[i] = h;
}

// ---------------- GEMM1 (MFMA f16): zxbcdt = x @ in_proj_w^T --------------------
// M=25088, N=1792(pad), K=384. NT layout, 128x128 tile, BK=32, 4 waves 2x2.
#define LDSW 40
__global__ __launch_bounds__(256) void k_gemm1_mfma(
    const ushort* __restrict__ xh, const ushort* __restrict__ wh,
    const float* __restrict__ dt_bias,
    ushort* __restrict__ zbuf, ushort* __restrict__ xbcbuf, float* __restrict__ dtbuf)
{
    __shared__ ushort As[128 * LDSW];
    __shared__ ushort Bs[128 * LDSW];
    const int m0 = blockIdx.y * 128;
    const int n0 = blockIdx.x * 128;
    const int tid = threadIdx.x;
    const int wid = tid >> 6;
    const int lane = tid & 63;
    const int r = lane & 15;
    const int quad = lane >> 4;
    const int wm = (wid >> 1) * 64;
    const int wn = (wid & 1) * 64;
    const int srow = tid >> 2;        // 0..63
    const int scol = (tid & 3) * 8;   // 0,8,16,24

    f32x4 acc[4][4];
#pragma unroll
    for (int i = 0; i < 4; ++i)
#pragma unroll
        for (int j = 0; j < 4; ++j) acc[i][j] = (f32x4){0.f, 0.f, 0.f, 0.f};

    for (int k0 = 0; k0 < DMODEL; k0 += 32) {
        int4 a0 = *(const int4*)(xh + (size_t)(m0 + srow)      * DMODEL + k0 + scol);
        int4 a1 = *(const int4*)(xh + (size_t)(m0 + srow + 64) * DMODEL + k0 + scol);
        int4 b0 = *(const int4*)(wh + (size_t)(n0 + srow)      * DMODEL + k0 + scol);
        int4 b1 = *(const int4*)(wh + (size_t)(n0 + srow + 64) * DMODEL + k0 + scol);
        __syncthreads();
        *(int4*)(As + srow * LDSW + scol)        = a0;
        *(int4*)(As + (srow + 64) * LDSW + scol) = a1;
        *(int4*)(Bs + srow * LDSW + scol)        = b0;
        *(int4*)(Bs + (srow + 64) * LDSW + scol) = b1;
        __syncthreads();
        f16x8 af[4], bfr[4];
#pragma unroll
        for (int t = 0; t < 4; ++t) {
            af[t]  = *(const f16x8*)(As + (wm + t * 16 + r) * LDSW + quad * 8);
            bfr[t] = *(const f16x8*)(Bs + (wn + t * 16 + r) * LDSW + quad * 8);
        }
#pragma unroll
        for (int i = 0; i < 4; ++i)
#pragma unroll
            for (int j = 0; j < 4; ++j)
                acc[i][j] = __builtin_amdgcn_mfma_f32_16x16x32_f16(af[i], bfr[j], acc[i][j], 0, 0, 0);
    }
    // epilogue: D row = quad*4+v (m), col = r (n); split by n
#pragma unroll
    for (int i = 0; i < 4; ++i) {
#pragma unroll
        for (int j = 0; j < 4; ++j) {
            int n = n0 + wn + j * 16 + r;
            if (n >= NPROJ) continue;
#pragma unroll
            for (int v = 0; v < 4; ++v) {
                int m = m0 + wm + i * 16 + quad * 4 + v;
                float val = acc[i][j][v];
                if (n < DINNER) {
                    zbuf[(size_t)m * DINNER + n] = f2hu(val);
                } else if (n < DINNER + CDIM) {
                    xbcbuf[(size_t)m * CDIM + (n - DINNER)] = f2hu(val);
                } else {
                    int h = n - (DINNER + CDIM);
                    float t = val + dt_bias[h];
                    float sp = (t > 20.f) ? t : log1pf(expf(t));
                    dtbuf[(size_t)m * NH + h] = sp;
                }
            }
        }
    }
}

// ---------------- GEMM2 (MFMA f16): out = gn @ w2^T  (M=25088,N=384,K=768) ------
__global__ __launch_bounds__(256) void k_gemm2_mfma(
    const ushort* __restrict__ gn, const ushort* __restrict__ wh,
    float* __restrict__ out)
{
    __shared__ ushort As[128 * LDSW];
    __shared__ ushort Bs[128 * LDSW];
    const int m0 = blockIdx.y * 128;
    const int n0 = blockIdx.x * 128;
    const int tid = threadIdx.x;
    const int wid = tid >> 6;
    const int lane = tid & 63;
    const int r = lane & 15;
    const int quad = lane >> 4;
    const int wm = (wid >> 1) * 64;
    const int wn = (wid & 1) * 64;
    const int srow = tid >> 2;
    const int scol = (tid & 3) * 8;

    f32x4 acc[4][4];
#pragma unroll
    for (int i = 0; i < 4; ++i)
#pragma unroll
        for (int j = 0; j < 4; ++j) acc[i][j] = (f32x4){0.f, 0.f, 0.f, 0.f};

    for (int k0 = 0; k0 < DINNER; k0 += 32) {
        int4 a0 = *(const int4*)(gn + (size_t)(m0 + srow)      * DINNER + k0 + scol);
        int4 a1 = *(const int4*)(gn + (size_t)(m0 + srow + 64) * DINNER + k0 + scol);
        int4 b0 = *(const int4*)(wh + (size_t)(n0 + srow)      * DINNER + k0 + scol);
        int4 b1 = *(const int4*)(wh + (size_t)(n0 + srow + 64) * DINNER + k0 + scol);
        __syncthreads();
        *(int4*)(As + srow * LDSW + scol)        = a0;
        *(int4*)(As + (srow + 64) * LDSW + scol) = a1;
        *(int4*)(Bs + srow * LDSW + scol)        = b0;
        *(int4*)(Bs + (srow + 64) * LDSW + scol) = b1;
        __syncthreads();
        f16x8 af[4], bfr[4];
#pragma unroll
        for (int t = 0; t < 4; ++t) {
            af[t]  = *(const f16x8*)(As + (wm + t * 16 + r) * LDSW + quad * 8);
            bfr[t] = *(const f16x8*)(Bs + (wn + t * 16 + r) * LDSW + quad * 8);
        }
#pragma unroll
        for (int i = 0; i < 4; ++i)
#pragma unroll
            for (int j = 0; j < 4; ++j)
                acc[i][j] = __builtin_amdgcn_mfma_f32_16x16x32_f16(af[i], bfr[j], acc[i][j], 0, 0, 0);
    }
#pragma unroll
    for (int i = 0; i < 4; ++i) {
#pragma unroll
        for (int j = 0; j < 4; ++j) {
            int n = n0 + wn + j * 16 + r;
#pragma unroll
            for (int v = 0; v < 4; ++v) {
                int m = m0 + wm + i * 16 + quad * 4 + v;
                out[(size_t)m * DMODEL + n] = acc[i][j][v];
            }
        }
    }
}

// ---------------- depthwise 3x3 conv + bias + SiLU, 8-channel vectorized --------
__global__ __launch_bounds__(256) void k_conv(
    const ushort* __restrict__ xbc, const float* __restrict__ cw,
    const float* __restrict__ cb, ushort* __restrict__ out)
{
    const int gid = blockIdx.x * 256 + threadIdx.x;  // over MTOT*NCG = 2,809,856
    const int cg  = gid % NCG;
    const int pix = gid / NCG;
    const int b = pix / LL, ij = pix % LL;
    const int i = ij / WW, j = ij % WW;
    const int c0 = cg * 8;

    float wreg[72];
#pragma unroll
    for (int t = 0; t < 18; ++t)
        *(float4*)(wreg + t * 4) = *(const float4*)(cw + c0 * 9 + t * 4);
    float acc[8];
    {
        float4 b0 = *(const float4*)(cb + c0);
        float4 b1 = *(const float4*)(cb + c0 + 4);
        acc[0]=b0.x; acc[1]=b0.y; acc[2]=b0.z; acc[3]=b0.w;
        acc[4]=b1.x; acc[5]=b1.y; acc[6]=b1.z; acc[7]=b1.w;
    }
#pragma unroll
    for (int ky = 0; ky < 3; ++ky) {
        int ii = i + ky - 1;
        if (ii < 0 || ii >= HH) continue;
#pragma unroll
        for (int kx = 0; kx < 3; ++kx) {
            int jj = j + kx - 1;
            if (jj < 0 || jj >= WW) continue;
            union { int4 q; ushort u[8]; } xv;
            xv.q = *(const int4*)(xbc + ((size_t)b * LL + ii * WW + jj) * CDIM + c0);
            int t = ky * 3 + kx;
#pragma unroll
            for (int q = 0; q < 8; ++q)
                acc[q] += wreg[q * 9 + t] * hu2f(xv.u[q]);
        }
    }
    union { int4 q; ushort u[8]; } o;
#pragma unroll
    for (int q = 0; q < 8; ++q) {
        float s = acc[q] / (1.f + expf(-acc[q]));
        o.u[q] = f2hu(s);
    }
    *(int4*)(out + (size_t)pix * CDIM + c0) = o.q;
}

// ---------------- fused dx = dt*A*x_in + 3x3 count-norm avg pool, 8-wide --------
__global__ __launch_bounds__(256) void k_dxpool(
    const ushort* __restrict__ xbc_conv, const float* __restrict__ dtbuf,
    const float* __restrict__ A_log, ushort* __restrict__ dxp)
{
    const int gid = blockIdx.x * 256 + threadIdx.x;  // over MTOT*NDG = 2,408,448
    const int cg  = gid % NDG;
    const int pix = gid / NDG;
    const int b = pix / LL, l = pix % LL;
    const int i = l / WW, j = l % WW;
    const int c0 = cg * 8;         // channel in [0,768)
    const int h = c0 >> 6;

    float Ah[8];
    {
        float4 a0 = *(const float4*)(A_log + c0);
        float4 a1 = *(const float4*)(A_log + c0 + 4);
        Ah[0]=a0.x; Ah[1]=a0.y; Ah[2]=a0.z; Ah[3]=a0.w;
        Ah[4]=a1.x; Ah[5]=a1.y; Ah[6]=a1.z; Ah[7]=a1.w;
    }
#pragma unroll
    for (int q = 0; q < 8; ++q) Ah[q] = -expf(Ah[q]);

    float sum[8] = {0.f,0.f,0.f,0.f,0.f,0.f,0.f,0.f};
    int cnt = 0;
#pragma unroll
    for (int dy = -1; dy <= 1; ++dy) {
        int ii = i + dy;
        if (ii < 0 || ii >= HH) continue;
#pragma unroll
        for (int dxx = -1; dxx <= 1; ++dxx) {
            int jj = j + dxx;
            if (jj < 0 || jj >= WW) continue;
            int ll = ii * WW + jj;
            ++cnt;
            float dtv = dtbuf[((size_t)b * LL + ll) * NH + h];
            union { int4 q; ushort u[8]; } xv;
            xv.q = *(const int4*)(xbc_conv + ((size_t)b * LL + ll) * CDIM + c0);
#pragma unroll
            for (int q = 0; q < 8; ++q)
                sum[q] += dtv * hu2f(xv.u[q]);
        }
    }
    float inv = 1.f / (float)cnt;
    union { int4 q; ushort u[8]; } o;
#pragma unroll
    for (int q = 0; q < 8; ++q)
        o.u[q] = f2hu(Ah[q] * sum[q] * inv);
    *(int4*)(dxp + (((size_t)b * NH + h) * LL + l) * HD + (c0 & 63)) = o.q;
}

// ---------------- h_state via MFMA (no atomics): Ht_part[d][s] ------------------
#define LDSP 33
__global__ __launch_bounds__(256) void k_hstate_mfma(
    const ushort* __restrict__ xbc_conv, const ushort* __restrict__ dxp,
    float* __restrict__ hpart)
{
    __shared__ ushort DsT[64 * LDSP];   // [d][l]
    __shared__ ushort BsT[64 * LDSP];   // [s][l]
    const int lc = blockIdx.x;          // 0..6
    const int bh = blockIdx.y;          // 0..95
    const int b = bh / NH;
    const int tid = threadIdx.x;
    const int wid = tid >> 6;
    const int lane = tid & 63;
    const int r = lane & 15;
    const int quad = lane >> 4;
    const int wd = (wid >> 1) * 32;     // d-offset of wave quadrant
    const int wsn = (wid & 1) * 32;     // s-offset
    const int lt = tid >> 3;            // 0..31 (l within tile)
    const int sg = (tid & 7) * 8;       // 0,8,..,56 (channel group)

    f32x4 acc[2][2];
#pragma unroll
    for (int i = 0; i < 2; ++i)
#pragma unroll
        for (int j = 0; j < 2; ++j) acc[i][j] = (f32x4){0.f, 0.f, 0.f, 0.f};

    const int l_base = lc * (LL / SPLITL);    // 448-chunk
    for (int step = 0; step < (LL / SPLITL) / 32; ++step) {
        int l0 = l_base + step * 32;
        union { int4 q; ushort u[8]; } dv, bv;
        dv.q = *(const int4*)(dxp + (((size_t)bh) * LL + l0 + lt) * HD + sg);
        bv.q = *(const int4*)(xbc_conv + ((size_t)(b * LL + l0 + lt)) * CDIM + DINNER + sg);
        __syncthreads();
#pragma unroll
        for (int q = 0; q < 8; ++q) {
            DsT[(sg + q) * LDSP + lt] = dv.u[q];
            BsT[(sg + q) * LDSP + lt] = bv.u[q];
        }
        __syncthreads();
        f16x8 af[2], bf[2];
#pragma unroll
        for (int t = 0; t < 2; ++t) {
            af[t] = *(const f16x8*)(DsT + (wd + t * 16 + r) * LDSP + quad * 8);
            bf[t] = *(const f16x8*)(BsT + (wsn + t * 16 + r) * LDSP + quad * 8);
        }
#pragma unroll
        for (int i = 0; i < 2; ++i)
#pragma unroll
            for (int j = 0; j < 2; ++j)
                acc[i][j] = __builtin_amdgcn_mfma_f32_16x16x32_f16(af[i], bf[j], acc[i][j], 0, 0, 0);
    }
    float* outp = hpart + ((size_t)(lc * 96 + bh) << 12);
#pragma unroll
    for (int i = 0; i < 2; ++i)
#pragma unroll
        for (int j = 0; j < 2; ++j)
#pragma unroll
            for (int v = 0; v < 4; ++v)
                outp[(wd + i * 16 + quad * 4 + v) * 64 + (wsn + j * 16 + r)] = acc[i][j][v];
}

// ---------------- h-prep: reduce 7 partials [d][s] -> hT f16 [bh][d][s] ---------
__global__ __launch_bounds__(256) void k_hprep(
    const float* __restrict__ hpart, ushort* __restrict__ hT)
{
    int i = blockIdx.x * 256 + threadIdx.x;   // over 96*4096 = 393216
    int bh = i >> 12;
    int rem = i & 4095;                       // = d*64+s
    float v = 0.f;
#pragma unroll
    for (int lc = 0; lc < SPLITL; ++lc)
        v += hpart[((size_t)(lc * 96 + bh) << 12) + rem];
    hT[i] = f2hu(v);
}

// ---------------- Ch + y via MFMA: per (b,h), y = Cm[L x 64] @ h[64 x 64] -------
#define HTW 72
__global__ __launch_bounds__(256) void k_chy_mfma(
    const ushort* __restrict__ xbc_conv, const ushort* __restrict__ hT,
    const float* __restrict__ Dp, ushort* __restrict__ ybuf)
{
    __shared__ ushort Hs[64 * HTW];
    const int bh = blockIdx.y;
    const int b = bh / NH, h = bh % NH;
    const int tid = threadIdx.x;
    const int wid = tid >> 6;
    const int lane = tid & 63;
    const int r = lane & 15;
    const int quad = lane >> 4;

    for (int idx = tid; idx < 512; idx += 256) {
        int row = idx >> 3, c8 = (idx & 7) * 8;
        *(int4*)(Hs + row * HTW + c8) = *(const int4*)(hT + ((size_t)bh << 12) + row * 64 + c8);
    }
    __syncthreads();

    const int chunk = blockIdx.x * 4 + wid;   // 0..48 valid (49 chunks of 64 l-rows)
    if (chunk >= 49) return;
    const int l0 = chunk * 64;

    f32x4 acc[4][4];
#pragma unroll
    for (int i = 0; i < 4; ++i)
#pragma unroll
        for (int j = 0; j < 4; ++j) acc[i][j] = (f32x4){0.f, 0.f, 0.f, 0.f};

#pragma unroll
    for (int kk = 0; kk < 2; ++kk) {          // K=64 in two 32-steps
        f16x8 af[4], bfr[4];
#pragma unroll
        for (int t = 0; t < 4; ++t) {
            af[t] = *(const f16x8*)(xbc_conv +
                ((size_t)(b * LL + l0 + t * 16 + r)) * CDIM + DINNER + DS + kk * 32 + quad * 8);
            bfr[t] = *(const f16x8*)(Hs + (t * 16 + r) * HTW + kk * 32 + quad * 8);
        }
#pragma unroll
        for (int i = 0; i < 4; ++i)
#pragma unroll
            for (int j = 0; j < 4; ++j)
                acc[i][j] = __builtin_amdgcn_mfma_f32_16x16x32_f16(af[i], bfr[j], acc[i][j], 0, 0, 0);
    }
    const float Dh = Dp[h];
#pragma unroll
    for (int i = 0; i < 4; ++i) {
#pragma unroll
        for (int j = 0; j < 4; ++j) {
            int d = j * 16 + r;
#pragma unroll
            for (int v = 0; v < 4; ++v) {
                int l = l0 + i * 16 + quad * 4 + v;
                float xv = hu2f(xbc_conv[((size_t)(b * LL + l)) * CDIM + h * HD + d]);
                ybuf[((size_t)(b * LL + l)) * DINNER + h * HD + d] = f2hu(acc[i][j][v] + xv * Dh);
            }
        }
    }
}

// ---------------- g = y*silu(z); LayerNorm(768), wave-per-row -------------------
__global__ __launch_bounds__(256) void k_gln(
    const ushort* __restrict__ ybuf, const ushort* __restrict__ zbuf,
    const float* __restrict__ nw, const float* __restrict__ nb,
    ushort* __restrict__ gnbuf)
{
    const int row = blockIdx.x * 4 + (threadIdx.x >> 6);
    const int lane = threadIdx.x & 63;
    const size_t base = (size_t)row * DINNER;

    float g[12];
    float sum = 0.f, sumsq = 0.f;
#pragma unroll
    for (int p = 0; p < 3; ++p) {
        int c = lane * 4 + p * 256;
        union { ushort4 q; ushort u[4]; } yv, zv;
        yv.q = *(const ushort4*)(ybuf + base + c);
        zv.q = *(const ushort4*)(zbuf + base + c);
#pragma unroll
        for (int q = 0; q < 4; ++q) {
            float y = hu2f(yv.u[q]);
            float z = hu2f(zv.u[q]);
            float gv = y * (z / (1.f + expf(-z)));
            g[p * 4 + q] = gv;
            sum += gv;
            sumsq += gv * gv;
        }
    }
#pragma unroll
    for (int off = 32; off > 0; off >>= 1) {
        sum += __shfl_xor(sum, off, 64);
        sumsq += __shfl_xor(sumsq, off, 64);
    }
    const float mu = sum / (float)DINNER;
    const float var = sumsq / (float)DINNER - mu * mu;
    const float rstd = rsqrtf(var + LN_EPS);
#pragma unroll
    for (int p = 0; p < 3; ++p) {
        int c = lane * 4 + p * 256;
        float4 w = *(const float4*)(nw + c);
        float4 bb = *(const float4*)(nb + c);
        union { ushort4 q; ushort u[4]; } o;
        o.u[0] = f2hu((g[p*4+0] - mu) * rstd * w.x + bb.x);
        o.u[1] = f2hu((g[p*4+1] - mu) * rstd * w.y + bb.y);
        o.u[2] = f2hu((g[p*4+2] - mu) * rstd * w.z + bb.z);
        o.u[3] = f2hu((g[p*4+3] - mu) * rstd * w.w + bb.w);
        *(ushort4*)(gnbuf + base + c) = o.q;
    }
}

extern "C" void kernel_launch(void* const* d_in, const int* in_sizes, int n_in,
                              void* d_out, int out_size, void* d_ws, size_t ws_size,
                              hipStream_t stream)
{
    const float* x         = (const float*)d_in[0];
    const float* in_proj_w = (const float*)d_in[1];
    const float* conv_w    = (const float*)d_in[2];
    const float* conv_b    = (const float*)d_in[3];
    const float* dt_bias   = (const float*)d_in[4];
    const float* A_log     = (const float*)d_in[5];
    const float* Dp        = (const float*)d_in[6];
    const float* norm_w    = (const float*)d_in[7];
    const float* norm_b    = (const float*)d_in[8];
    const float* out_proj_w= (const float*)d_in[9];

    // workspace layout (bytes) — same offsets as known-good round 7, lo slots unused:
    char* wsb = (char*)d_ws;
    float*  dtbuf   = (float*) (wsb + 0);           //  1,204,224 fp32 MTOT*NH
    ushort* w1      = (ushort*)(wsb + 2777088);     //  1,376,256 f16 NPAD*384
    ushort* w2      = (ushort*)(wsb + 4153344);     //    589,824 f16 384*768
    ushort* zbuf    = (ushort*)(wsb + 4743168);     // 38,535,168 f16 MTOT*DINNER
    ushort* xbcraw  = (ushort*)(wsb + 43278336);    // 44,957,696 f16 MTOT*CDIM
    ushort* xbcconv = (ushort*)(wsb + 88236032);    // 44,957,696 f16 MTOT*CDIM
    ushort* x16     = xbcconv;                      // f16 cast of x; dead after gemm1
    // within dead xbcraw region (raw xBC dead after k_conv):
    ushort* hT      = xbcraw;                       //    786,432 B
    float*  hpart   = (float*)(wsb + 44851200);     // 11,010,048 B (7*96*4096 fp32)
    ushort* dxp     = (ushort*)d_out;               // consumed before final GEMM write
    ushort* ybuf    = (ushort*)d_out;
    ushort* gnbuf   = xbcraw;                       // clobbers hT/hpart after consumed

    k_cast_x <<<MTOT * DMODEL / 4 / 256, 256, 0, stream>>>(
        (const float4*)x, (ushort4*)x16);
    k_cast_w1<<<NPAD * DMODEL / 4 / 256, 256, 0, stream>>>(
        in_proj_w, (ushort4*)w1);
    k_cast_w2<<<DMODEL * DINNER / 4 / 256, 256, 0, stream>>>(
        (const float4*)out_proj_w, (ushort4*)w2);

    k_gemm1_mfma<<<dim3(NPAD / 128, MTOT / 128), 256, 0, stream>>>(
        x16, w1, dt_bias, zbuf, xbcraw, dtbuf);

    k_conv<<<MTOT * NCG / 256, 256, 0, stream>>>(
        xbcraw, conv_w, conv_b, xbcconv);
    k_dxpool<<<MTOT * NDG / 256, 256, 0, stream>>>(
        xbcconv, dtbuf, A_log, dxp);
    k_hstate_mfma<<<dim3(SPLITL, BB * NH), 256, 0, stream>>>(
        xbcconv, dxp, hpart);
    k_hprep<<<96 * 4096 / 256, 256, 0, stream>>>(hpart, hT);
    k_chy_mfma<<<dim3(13, BB * NH), 256, 0, stream>>>(
        xbcconv, hT, Dp, ybuf);
    k_gln<<<MTOT / 4, 256, 0, stream>>>(
        ybuf, zbuf, norm_w, norm_b, gnbuf);
    k_gemm2_mfma<<<dim3(DMODEL / 128, MTOT / 128), 256, 0, stream>>>(
        gnbuf, w2, (float*)d_out);
}

// Round 9
// 411.759 us; speedup vs baseline: 4.1470x; 1.0330x over previous
//
#include <hip/hip_runtime.h>
#include <hip/hip_bf16.h>
#include <math.h>

// Problem constants (fixed by setup_inputs: B=8, H=W=56)
#define BB 8
#define HH 56
#define WW 56
#define LL (HH*WW)          // 3136
#define DMODEL 384
#define DINNER 768
#define NH 12
#define HD 64
#define DS 64
#define CDIM (DINNER + 2*DS)    // 896
#define NPROJ (2*DINNER + 2*DS + NH) // 1676
#define NPAD 1792           // NPROJ padded to multiple of 128
#define MTOT (BB*LL)        // 25088
#define LN_EPS 1e-5f
#define NCG (CDIM/8)        // 112 channel-groups for conv
#define NDG (DINNER/8)      // 96 channel-groups for dxpool
#define SPLITL 7            // L-chunks for hstate (3136/7 = 448)

typedef __attribute__((ext_vector_type(8))) _Float16 f16x8;
typedef __attribute__((ext_vector_type(4))) float f32x4;

// f16 <-> f32 with bits in ushort
__device__ __forceinline__ ushort f2hu(float v) {
    union { _Float16 h; ushort u; } cv; cv.h = (_Float16)v; return cv.u;
}
__device__ __forceinline__ float hu2f(ushort u) {
    union { ushort u; _Float16 h; } cv; cv.u = u; return (float)cv.h;
}

// ---------------- cast kernels: fp32 -> f16 -------------------------------------
__global__ __launch_bounds__(256) void k_cast_x(
    const float4* __restrict__ in, ushort4* __restrict__ out)
{
    int i = blockIdx.x * 256 + threadIdx.x;    // grid sized exactly
    float4 v = in[i];
    ushort4 h;
    h.x = f2hu(v.x); h.y = f2hu(v.y); h.z = f2hu(v.z); h.w = f2hu(v.w);
    out[i] = h;
}

// merged weight cast: w1 [n][k] zero-padded to NPAD rows, then w2 straight cast
#define W1Q (NPAD*DMODEL/4)    // 172032
#define W2Q (DMODEL*DINNER/4)  // 73728
__global__ __launch_bounds__(256) void k_cast_w(
    const float* __restrict__ w1src, const float* __restrict__ w2src,
    ushort4* __restrict__ w1dst, ushort4* __restrict__ w2dst)
{
    int i = blockIdx.x * 256 + threadIdx.x;   // over W1Q+W2Q = 245760
    if (i < W1Q) {
        int n = i / (DMODEL / 4);
        int k = (i % (DMODEL / 4)) * 4;
        ushort4 h = {0,0,0,0};
        if (n < NPROJ) {
            float4 v = *(const float4*)(w1src + (size_t)n * DMODEL + k);
            h.x = f2hu(v.x); h.y = f2hu(v.y); h.z = f2hu(v.z); h.w = f2hu(v.w);
        }
        w1dst[i] = h;
    } else {
        int t = i - W1Q;
        float4 v = ((const float4*)w2src)[t];
        ushort4 h;
        h.x = f2hu(v.x); h.y = f2hu(v.y); h.z = f2hu(v.z); h.w = f2hu(v.w);
        w2dst[t] = h;
    }
}

// ---------------- GEMM1 (MFMA f16, pipelined dbuf): zxbcdt = x @ in_proj_w^T ----
// M=25088, N=1792(pad), K=384. 128x128 tile, BK=32, 4 waves 2x2.
// Register prefetch of tile k+1 overlaps compute of tile k; 1 barrier/iter.
#define LDSW 40
__global__ __launch_bounds__(256) void k_gemm1_mfma(
    const ushort* __restrict__ xh, const ushort* __restrict__ wh,
    const float* __restrict__ dt_bias,
    ushort* __restrict__ zbuf, ushort* __restrict__ xbcbuf, float* __restrict__ dtbuf)
{
    __shared__ ushort As[2][128 * LDSW];
    __shared__ ushort Bs[2][128 * LDSW];
    const int m0 = blockIdx.y * 128;
    const int n0 = blockIdx.x * 128;
    const int tid = threadIdx.x;
    const int wid = tid >> 6;
    const int lane = tid & 63;
    const int r = lane & 15;
    const int quad = lane >> 4;
    const int wm = (wid >> 1) * 64;
    const int wn = (wid & 1) * 64;
    const int srow = tid >> 2;        // 0..63
    const int scol = (tid & 3) * 8;   // 0,8,16,24

    f32x4 acc[4][4];
#pragma unroll
    for (int i = 0; i < 4; ++i)
#pragma unroll
        for (int j = 0; j < 4; ++j) acc[i][j] = (f32x4){0.f, 0.f, 0.f, 0.f};

    // preload tile 0
    {
        int4 a0 = *(const int4*)(xh + (size_t)(m0 + srow)      * DMODEL + scol);
        int4 a1 = *(const int4*)(xh + (size_t)(m0 + srow + 64) * DMODEL + scol);
        int4 b0 = *(const int4*)(wh + (size_t)(n0 + srow)      * DMODEL + scol);
        int4 b1 = *(const int4*)(wh + (size_t)(n0 + srow + 64) * DMODEL + scol);
        *(int4*)(As[0] + srow * LDSW + scol)        = a0;
        *(int4*)(As[0] + (srow + 64) * LDSW + scol) = a1;
        *(int4*)(Bs[0] + srow * LDSW + scol)        = b0;
        *(int4*)(Bs[0] + (srow + 64) * LDSW + scol) = b1;
    }
    __syncthreads();

    int cur = 0;
    for (int k0 = 32; k0 <= DMODEL; k0 += 32) {
        const bool has = (k0 < DMODEL);
        int4 na0, na1, nb0, nb1;
        if (has) {
            na0 = *(const int4*)(xh + (size_t)(m0 + srow)      * DMODEL + k0 + scol);
            na1 = *(const int4*)(xh + (size_t)(m0 + srow + 64) * DMODEL + k0 + scol);
            nb0 = *(const int4*)(wh + (size_t)(n0 + srow)      * DMODEL + k0 + scol);
            nb1 = *(const int4*)(wh + (size_t)(n0 + srow + 64) * DMODEL + k0 + scol);
        }
        // compute tile k0-32 from buf cur (loads above stay in flight)
        f16x8 af[4], bfr[4];
#pragma unroll
        for (int t = 0; t < 4; ++t) {
            af[t]  = *(const f16x8*)(As[cur] + (wm + t * 16 + r) * LDSW + quad * 8);
            bfr[t] = *(const f16x8*)(Bs[cur] + (wn + t * 16 + r) * LDSW + quad * 8);
        }
#pragma unroll
        for (int i = 0; i < 4; ++i)
#pragma unroll
            for (int j = 0; j < 4; ++j)
                acc[i][j] = __builtin_amdgcn_mfma_f32_16x16x32_f16(af[i], bfr[j], acc[i][j], 0, 0, 0);
        if (has) {
            *(int4*)(As[cur ^ 1] + srow * LDSW + scol)        = na0;
            *(int4*)(As[cur ^ 1] + (srow + 64) * LDSW + scol) = na1;
            *(int4*)(Bs[cur ^ 1] + srow * LDSW + scol)        = nb0;
            *(int4*)(Bs[cur ^ 1] + (srow + 64) * LDSW + scol) = nb1;
            __syncthreads();
            cur ^= 1;
        }
    }
    // epilogue: D row = quad*4+v (m), col = r (n); split by n
#pragma unroll
    for (int i = 0; i < 4; ++i) {
#pragma unroll
        for (int j = 0; j < 4; ++j) {
            int n = n0 + wn + j * 16 + r;
            if (n >= NPROJ) continue;
#pragma unroll
            for (int v = 0; v < 4; ++v) {
                int m = m0 + wm + i * 16 + quad * 4 + v;
                float val = acc[i][j][v];
                if (n < DINNER) {
                    zbuf[(size_t)m * DINNER + n] = f2hu(val);
                } else if (n < DINNER + CDIM) {
                    xbcbuf[(size_t)m * CDIM + (n - DINNER)] = f2hu(val);
                } else {
                    int h = n - (DINNER + CDIM);
                    float t = val + dt_bias[h];
                    float sp = (t > 20.f) ? t : log1pf(expf(t));
                    dtbuf[(size_t)m * NH + h] = sp;
                }
            }
        }
    }
}

// ---------------- GEMM2 (MFMA f16, pipelined dbuf): out = gn @ w2^T -------------
__global__ __launch_bounds__(256) void k_gemm2_mfma(
    const ushort* __restrict__ gn, const ushort* __restrict__ wh,
    float* __restrict__ out)
{
    __shared__ ushort As[2][128 * LDSW];
    __shared__ ushort Bs[2][128 * LDSW];
    const int m0 = blockIdx.y * 128;
    const int n0 = blockIdx.x * 128;
    const int tid = threadIdx.x;
    const int wid = tid >> 6;
    const int lane = tid & 63;
    const int r = lane & 15;
    const int quad = lane >> 4;
    const int wm = (wid >> 1) * 64;
    const int wn = (wid & 1) * 64;
    const int srow = tid >> 2;
    const int scol = (tid & 3) * 8;

    f32x4 acc[4][4];
#pragma unroll
    for (int i = 0; i < 4; ++i)
#pragma unroll
        for (int j = 0; j < 4; ++j) acc[i][j] = (f32x4){0.f, 0.f, 0.f, 0.f};

    {
        int4 a0 = *(const int4*)(gn + (size_t)(m0 + srow)      * DINNER + scol);
        int4 a1 = *(const int4*)(gn + (size_t)(m0 + srow + 64) * DINNER + scol);
        int4 b0 = *(const int4*)(wh + (size_t)(n0 + srow)      * DINNER + scol);
        int4 b1 = *(const int4*)(wh + (size_t)(n0 + srow + 64) * DINNER + scol);
        *(int4*)(As[0] + srow * LDSW + scol)        = a0;
        *(int4*)(As[0] + (srow + 64) * LDSW + scol) = a1;
        *(int4*)(Bs[0] + srow * LDSW + scol)        = b0;
        *(int4*)(Bs[0] + (srow + 64) * LDSW + scol) = b1;
    }
    __syncthreads();

    int cur = 0;
    for (int k0 = 32; k0 <= DINNER; k0 += 32) {
        const bool has = (k0 < DINNER);
        int4 na0, na1, nb0, nb1;
        if (has) {
            na0 = *(const int4*)(gn + (size_t)(m0 + srow)      * DINNER + k0 + scol);
            na1 = *(const int4*)(gn + (size_t)(m0 + srow + 64) * DINNER + k0 + scol);
            nb0 = *(const int4*)(wh + (size_t)(n0 + srow)      * DINNER + k0 + scol);
            nb1 = *(const int4*)(wh + (size_t)(n0 + srow + 64) * DINNER + k0 + scol);
        }
        f16x8 af[4], bfr[4];
#pragma unroll
        for (int t = 0; t < 4; ++t) {
            af[t]  = *(const f16x8*)(As[cur] + (wm + t * 16 + r) * LDSW + quad * 8);
            bfr[t] = *(const f16x8*)(Bs[cur] + (wn + t * 16 + r) * LDSW + quad * 8);
        }
#pragma unroll
        for (int i = 0; i < 4; ++i)
#pragma unroll
            for (int j = 0; j < 4; ++j)
                acc[i][j] = __builtin_amdgcn_mfma_f32_16x16x32_f16(af[i], bfr[j], acc[i][j], 0, 0, 0);
        if (has) {
            *(int4*)(As[cur ^ 1] + srow * LDSW + scol)        = na0;
            *(int4*)(As[cur ^ 1] + (srow + 64) * LDSW + scol) = na1;
            *(int4*)(Bs[cur ^ 1] + srow * LDSW + scol)        = nb0;
            *(int4*)(Bs[cur ^ 1] + (srow + 64) * LDSW + scol) = nb1;
            __syncthreads();
            cur ^= 1;
        }
    }
#pragma unroll
    for (int i = 0; i < 4; ++i) {
#pragma unroll
        for (int j = 0; j < 4; ++j) {
            int n = n0 + wn + j * 16 + r;
#pragma unroll
            for (int v = 0; v < 4; ++v) {
                int m = m0 + wm + i * 16 + quad * 4 + v;
                out[(size_t)m * DMODEL + n] = acc[i][j][v];
            }
        }
    }
}

// ---------------- depthwise 3x3 conv + bias + SiLU, 8-channel vectorized --------
__global__ __launch_bounds__(256) void k_conv(
    const ushort* __restrict__ xbc, const float* __restrict__ cw,
    const float* __restrict__ cb, ushort* __restrict__ out)
{
    const int gid = blockIdx.x * 256 + threadIdx.x;  // over MTOT*NCG = 2,809,856
    const int cg  = gid % NCG;
    const int pix = gid / NCG;
    const int b = pix / LL, ij = pix % LL;
    const int i = ij / WW, j = ij % WW;
    const int c0 = cg * 8;

    float wreg[72];
#pragma unroll
    for (int t = 0; t < 18; ++t)
        *(float4*)(wreg + t * 4) = *(const float4*)(cw + c0 * 9 + t * 4);
    float acc[8];
    {
        float4 b0 = *(const float4*)(cb + c0);
        float4 b1 = *(const float4*)(cb + c0 + 4);
        acc[0]=b0.x; acc[1]=b0.y; acc[2]=b0.z; acc[3]=b0.w;
        acc[4]=b1.x; acc[5]=b1.y; acc[6]=b1.z; acc[7]=b1.w;
    }
#pragma unroll
    for (int ky = 0; ky < 3; ++ky) {
        int ii = i + ky - 1;
        if (ii < 0 || ii >= HH) continue;
#pragma unroll
        for (int kx = 0; kx < 3; ++kx) {
            int jj = j + kx - 1;
            if (jj < 0 || jj >= WW) continue;
            union { int4 q; ushort u[8]; } xv;
            xv.q = *(const int4*)(xbc + ((size_t)b * LL + ii * WW + jj) * CDIM + c0);
            int t = ky * 3 + kx;
#pragma unroll
            for (int q = 0; q < 8; ++q)
                acc[q] += wreg[q * 9 + t] * hu2f(xv.u[q]);
        }
    }
    union { int4 q; ushort u[8]; } o;
#pragma unroll
    for (int q = 0; q < 8; ++q) {
        float s = acc[q] / (1.f + expf(-acc[q]));
        o.u[q] = f2hu(s);
    }
    *(int4*)(out + (size_t)pix * CDIM + c0) = o.q;
}

// ---------------- fused dx = dt*A*x_in + 3x3 count-norm avg pool, 8-wide --------
__global__ __launch_bounds__(256) void k_dxpool(
    const ushort* __restrict__ xbc_conv, const float* __restrict__ dtbuf,
    const float* __restrict__ A_log, ushort* __restrict__ dxp)
{
    const int gid = blockIdx.x * 256 + threadIdx.x;  // over MTOT*NDG = 2,408,448
    const int cg  = gid % NDG;
    const int pix = gid / NDG;
    const int b = pix / LL, l = pix % LL;
    const int i = l / WW, j = l % WW;
    const int c0 = cg * 8;         // channel in [0,768)
    const int h = c0 >> 6;

    float Ah[8];
    {
        float4 a0 = *(const float4*)(A_log + c0);
        float4 a1 = *(const float4*)(A_log + c0 + 4);
        Ah[0]=a0.x; Ah[1]=a0.y; Ah[2]=a0.z; Ah[3]=a0.w;
        Ah[4]=a1.x; Ah[5]=a1.y; Ah[6]=a1.z; Ah[7]=a1.w;
    }
#pragma unroll
    for (int q = 0; q < 8; ++q) Ah[q] = -expf(Ah[q]);

    float sum[8] = {0.f,0.f,0.f,0.f,0.f,0.f,0.f,0.f};
    int cnt = 0;
#pragma unroll
    for (int dy = -1; dy <= 1; ++dy) {
        int ii = i + dy;
        if (ii < 0 || ii >= HH) continue;
#pragma unroll
        for (int dxx = -1; dxx <= 1; ++dxx) {
            int jj = j + dxx;
            if (jj < 0 || jj >= WW) continue;
            int ll = ii * WW + jj;
            ++cnt;
            float dtv = dtbuf[((size_t)b * LL + ll) * NH + h];
            union { int4 q; ushort u[8]; } xv;
            xv.q = *(const int4*)(xbc_conv + ((size_t)b * LL + ll) * CDIM + c0);
#pragma unroll
            for (int q = 0; q < 8; ++q)
                sum[q] += dtv * hu2f(xv.u[q]);
        }
    }
    float inv = 1.f / (float)cnt;
    union { int4 q; ushort u[8]; } o;
#pragma unroll
    for (int q = 0; q < 8; ++q)
        o.u[q] = f2hu(Ah[q] * sum[q] * inv);
    *(int4*)(dxp + (((size_t)b * NH + h) * LL + l) * HD + (c0 & 63)) = o.q;
}

// ---------------- h_state via MFMA (no atomics): Ht_part[d][s] ------------------
#define LDSP 33
__global__ __launch_bounds__(256) void k_hstate_mfma(
    const ushort* __restrict__ xbc_conv, const ushort* __restrict__ dxp,
    float* __restrict__ hpart)
{
    __shared__ ushort DsT[64 * LDSP];   // [d][l]
    __shared__ ushort BsT[64 * LDSP];   // [s][l]
    const int lc = blockIdx.x;          // 0..6
    const int bh = blockIdx.y;          // 0..95
    const int b = bh / NH;
    const int tid = threadIdx.x;
    const int wid = tid >> 6;
    const int lane = tid & 63;
    const int r = lane & 15;
    const int quad = lane >> 4;
    const int wd = (wid >> 1) * 32;     // d-offset of wave quadrant
    const int wsn = (wid & 1) * 32;     // s-offset
    const int lt = tid >> 3;            // 0..31 (l within tile)
    const int sg = (tid & 7) * 8;       // 0,8,..,56 (channel group)

    f32x4 acc[2][2];
#pragma unroll
    for (int i = 0; i < 2; ++i)
#pragma unroll
        for (int j = 0; j < 2; ++j) acc[i][j] = (f32x4){0.f, 0.f, 0.f, 0.f};

    const int l_base = lc * (LL / SPLITL);    // 448-chunk
    for (int step = 0; step < (LL / SPLITL) / 32; ++step) {
        int l0 = l_base + step * 32;
        union { int4 q; ushort u[8]; } dv, bv;
        dv.q = *(const int4*)(dxp + (((size_t)bh) * LL + l0 + lt) * HD + sg);
        bv.q = *(const int4*)(xbc_conv + ((size_t)(b * LL + l0 + lt)) * CDIM + DINNER + sg);
        __syncthreads();
#pragma unroll
        for (int q = 0; q < 8; ++q) {
            DsT[(sg + q) * LDSP + lt] = dv.u[q];
            BsT[(sg + q) * LDSP + lt] = bv.u[q];
        }
        __syncthreads();
        f16x8 af[2], bf[2];
#pragma unroll
        for (int t = 0; t < 2; ++t) {
            af[t] = *(const f16x8*)(DsT + (wd + t * 16 + r) * LDSP + quad * 8);
            bf[t] = *(const f16x8*)(BsT + (wsn + t * 16 + r) * LDSP + quad * 8);
        }
#pragma unroll
        for (int i = 0; i < 2; ++i)
#pragma unroll
            for (int j = 0; j < 2; ++j)
                acc[i][j] = __builtin_amdgcn_mfma_f32_16x16x32_f16(af[i], bf[j], acc[i][j], 0, 0, 0);
    }
    float* outp = hpart + ((size_t)(lc * 96 + bh) << 12);
#pragma unroll
    for (int i = 0; i < 2; ++i)
#pragma unroll
        for (int j = 0; j < 2; ++j)
#pragma unroll
            for (int v = 0; v < 4; ++v)
                outp[(wd + i * 16 + quad * 4 + v) * 64 + (wsn + j * 16 + r)] = acc[i][j][v];
}

// ---------------- h-prep: reduce 7 partials [d][s] -> hT f16 [bh][d][s] ---------
__global__ __launch_bounds__(256) void k_hprep(
    const float* __restrict__ hpart, ushort* __restrict__ hT)
{
    int i = blockIdx.x * 256 + threadIdx.x;   // over 96*4096 = 393216
    int bh = i >> 12;
    int rem = i & 4095;                       // = d*64+s
    float v = 0.f;
#pragma unroll
    for (int lc = 0; lc < SPLITL; ++lc)
        v += hpart[((size_t)(lc * 96 + bh) << 12) + rem];
    hT[i] = f2hu(v);
}

// ---------------- Ch + y via MFMA: per (b,h), y = Cm[L x 64] @ h[64 x 64] -------
#define HTW 72
__global__ __launch_bounds__(256) void k_chy_mfma(
    const ushort* __restrict__ xbc_conv, const ushort* __restrict__ hT,
    const float* __restrict__ Dp, ushort* __restrict__ ybuf)
{
    __shared__ ushort Hs[64 * HTW];
    const int bh = blockIdx.y;
    const int b = bh / NH, h = bh % NH;
    const int tid = threadIdx.x;
    const int wid = tid >> 6;
    const int lane = tid & 63;
    const int r = lane & 15;
    const int quad = lane >> 4;

    for (int idx = tid; idx < 512; idx += 256) {
        int row = idx >> 3, c8 = (idx & 7) * 8;
        *(int4*)(Hs + row * HTW + c8) = *(const int4*)(hT + ((size_t)bh << 12) + row * 64 + c8);
    }
    __syncthreads();

    const int chunk = blockIdx.x * 4 + wid;   // 0..48 valid (49 chunks of 64 l-rows)
    if (chunk >= 49) return;
    const int l0 = chunk * 64;

    f32x4 acc[4][4];
#pragma unroll
    for (int i = 0; i < 4; ++i)
#pragma unroll
        for (int j = 0; j < 4; ++j) acc[i][j] = (f32x4){0.f, 0.f, 0.f, 0.f};

#pragma unroll
    for (int kk = 0; kk < 2; ++kk) {          // K=64 in two 32-steps
        f16x8 af[4], bfr[4];
#pragma unroll
        for (int t = 0; t < 4; ++t) {
            af[t] = *(const f16x8*)(xbc_conv +
                ((size_t)(b * LL + l0 + t * 16 + r)) * CDIM + DINNER + DS + kk * 32 + quad * 8);
            bfr[t] = *(const f16x8*)(Hs + (t * 16 + r) * HTW + kk * 32 + quad * 8);
        }
#pragma unroll
        for (int i = 0; i < 4; ++i)
#pragma unroll
            for (int j = 0; j < 4; ++j)
                acc[i][j] = __builtin_amdgcn_mfma_f32_16x16x32_f16(af[i], bfr[j], acc[i][j], 0, 0, 0);
    }
    const float Dh = Dp[h];
#pragma unroll
    for (int i = 0; i < 4; ++i) {
#pragma unroll
        for (int j = 0; j < 4; ++j) {
            int d = j * 16 + r;
#pragma unroll
            for (int v = 0; v < 4; ++v) {
                int l = l0 + i * 16 + quad * 4 + v;
                float xv = hu2f(xbc_conv[((size_t)(b * LL + l)) * CDIM + h * HD + d]);
                ybuf[((size_t)(b * LL + l)) * DINNER + h * HD + d] = f2hu(acc[i][j][v] + xv * Dh);
            }
        }
    }
}

// ---------------- g = y*silu(z); LayerNorm(768), wave-per-row -------------------
__global__ __launch_bounds__(256) void k_gln(
    const ushort* __restrict__ ybuf, const ushort* __restrict__ zbuf,
    const float* __restrict__ nw, const float* __restrict__ nb,
    ushort* __restrict__ gnbuf)
{
    const int row = blockIdx.x * 4 + (threadIdx.x >> 6);
    const int lane = threadIdx.x & 63;
    const size_t base = (size_t)row * DINNER;

    float g[12];
    float sum = 0.f, sumsq = 0.f;
#pragma unroll
    for (int p = 0; p < 3; ++p) {
        int c = lane * 4 + p * 256;
        union { ushort4 q; ushort u[4]; } yv, zv;
        yv.q = *(const ushort4*)(ybuf + base + c);
        zv.q = *(const ushort4*)(zbuf + base + c);
#pragma unroll
        for (int q = 0; q < 4; ++q) {
            float y = hu2f(yv.u[q]);
            float z = hu2f(zv.u[q]);
            float gv = y * (z / (1.f + expf(-z)));
            g[p * 4 + q] = gv;
            sum += gv;
            sumsq += gv * gv;
        }
    }
#pragma unroll
    for (int off = 32; off > 0; off >>= 1) {
        sum += __shfl_xor(sum, off, 64);
        sumsq += __shfl_xor(sumsq, off, 64);
    }
    const float mu = sum / (float)DINNER;
    const float var = sumsq / (float)DINNER - mu * mu;
    const float rstd = rsqrtf(var + LN_EPS);
#pragma unroll
    for (int p = 0; p < 3; ++p) {
        int c = lane * 4 + p * 256;
        float4 w = *(const float4*)(nw + c);
        float4 bb = *(const float4*)(nb + c);
        union { ushort4 q; ushort u[4]; } o;
        o.u[0] = f2hu((g[p*4+0] - mu) * rstd * w.x + bb.x);
        o.u[1] = f2hu((g[p*4+1] - mu) * rstd * w.y + bb.y);
        o.u[2] = f2hu((g[p*4+2] - mu) * rstd * w.z + bb.z);
        o.u[3] = f2hu((g[p*4+3] - mu) * rstd * w.w + bb.w);
        *(ushort4*)(gnbuf + base + c) = o.q;
    }
}

extern "C" void kernel_launch(void* const* d_in, const int* in_sizes, int n_in,
                              void* d_out, int out_size, void* d_ws, size_t ws_size,
                              hipStream_t stream)
{
    const float* x         = (const float*)d_in[0];
    const float* in_proj_w = (const float*)d_in[1];
    const float* conv_w    = (const float*)d_in[2];
    const float* conv_b    = (const float*)d_in[3];
    const float* dt_bias   = (const float*)d_in[4];
    const float* A_log     = (const float*)d_in[5];
    const float* Dp        = (const float*)d_in[6];
    const float* norm_w    = (const float*)d_in[7];
    const float* norm_b    = (const float*)d_in[8];
    const float* out_proj_w= (const float*)d_in[9];

    // workspace layout (bytes) — same offsets as known-good round 7/8:
    char* wsb = (char*)d_ws;
    float*  dtbuf   = (float*) (wsb + 0);           //  1,204,224 fp32 MTOT*NH
    ushort* w1      = (ushort*)(wsb + 2777088);     //  1,376,256 f16 NPAD*384
    ushort* w2      = (ushort*)(wsb + 4153344);     //    589,824 f16 384*768
    ushort* zbuf    = (ushort*)(wsb + 4743168);     // 38,535,168 f16 MTOT*DINNER
    ushort* xbcraw  = (ushort*)(wsb + 43278336);    // 44,957,696 f16 MTOT*CDIM
    ushort* xbcconv = (ushort*)(wsb + 88236032);    // 44,957,696 f16 MTOT*CDIM
    ushort* x16     = xbcconv;                      // f16 cast of x; dead after gemm1
    // within dead xbcraw region (raw xBC dead after k_conv):
    ushort* hT      = xbcraw;                       //    786,432 B
    float*  hpart   = (float*)(wsb + 44851200);     // 11,010,048 B (7*96*4096 fp32)
    ushort* dxp     = (ushort*)d_out;               // consumed before final GEMM write
    ushort* ybuf    = (ushort*)d_out;
    ushort* gnbuf   = xbcraw;                       // clobbers hT/hpart after consumed

    k_cast_x <<<MTOT * DMODEL / 4 / 256, 256, 0, stream>>>(
        (const float4*)x, (ushort4*)x16);
    k_cast_w<<<(W1Q + W2Q) / 256, 256, 0, stream>>>(
        in_proj_w, out_proj_w, (ushort4*)w1, (ushort4*)w2);

    k_gemm1_mfma<<<dim3(NPAD / 128, MTOT / 128), 256, 0, stream>>>(
        x16, w1, dt_bias, zbuf, xbcraw, dtbuf);

    k_conv<<<MTOT * NCG / 256, 256, 0, stream>>>(
        xbcraw, conv_w, conv_b, xbcconv);
    k_dxpool<<<MTOT * NDG / 256, 256, 0, stream>>>(
        xbcconv, dtbuf, A_log, dxp);
    k_hstate_mfma<<<dim3(SPLITL, BB * NH), 256, 0, stream>>>(
        xbcconv, dxp, hpart);
    k_hprep<<<96 * 4096 / 256, 256, 0, stream>>>(hpart, hT);
    k_chy_mfma<<<dim3(13, BB * NH), 256, 0, stream>>>(
        xbcconv, hT, Dp, ybuf);
    k_gln<<<MTOT / 4, 256, 0, stream>>>(
        ybuf, zbuf, norm_w, norm_b, gnbuf);
    k_gemm2_mfma<<<dim3(DMODEL / 128, MTOT / 128), 256, 0, stream>>>(
        gnbuf, w2, (float*)d_out);
}

// Round 10
// 365.918 us; speedup vs baseline: 4.6665x; 1.1253x over previous
//
#include <hip/hip_runtime.h>
#include <hip/hip_bf16.h>
#include <math.h>

// Problem constants (fixed by setup_inputs: B=8, H=W=56)
#define BB 8
#define HH 56
#define WW 56
#define LL (HH*WW)          // 3136
#define DMODEL 384
#define DINNER 768
#define NH 12
#define HD 64
#define DS 64
#define CDIM (DINNER + 2*DS)    // 896
#define NPROJ (2*DINNER + 2*DS + NH) // 1676
#define NPAD 1792           // NPROJ padded to multiple of 128
#define MTOT (BB*LL)        // 25088
#define LN_EPS 1e-5f
#define NCG (CDIM/8)        // 112 channel-groups for conv
#define NDG (DINNER/8)      // 96 channel-groups for dxpool
#define SPLITL 7            // L-chunks for hstate (3136/7 = 448)

typedef __attribute__((ext_vector_type(8))) _Float16 f16x8;
typedef __attribute__((ext_vector_type(4))) float f32x4;

// f16 <-> f32 with bits in ushort
__device__ __forceinline__ ushort f2hu(float v) {
    union { _Float16 h; ushort u; } cv; cv.h = (_Float16)v; return cv.u;
}
__device__ __forceinline__ float hu2f(ushort u) {
    union { ushort u; _Float16 h; } cv; cv.u = u; return (float)cv.h;
}

// ---------------- cast kernels: fp32 -> f16 -------------------------------------
__global__ __launch_bounds__(256) void k_cast_x(
    const float4* __restrict__ in, ushort4* __restrict__ out)
{
    int i = blockIdx.x * 256 + threadIdx.x;    // grid sized exactly
    float4 v = in[i];
    ushort4 h;
    h.x = f2hu(v.x); h.y = f2hu(v.y); h.z = f2hu(v.z); h.w = f2hu(v.w);
    out[i] = h;
}

// merged weight cast: w1 (padded), w2, and conv-weight reorg cwr[cg][tap][8ch] fp32
#define W1Q (NPAD*DMODEL/4)    // 172032
#define W2Q (DMODEL*DINNER/4)  // 73728
#define CWQ (NCG*72/4)         // 2016
__global__ __launch_bounds__(256) void k_cast_w(
    const float* __restrict__ w1src, const float* __restrict__ w2src,
    const float* __restrict__ cwsrc,
    ushort4* __restrict__ w1dst, ushort4* __restrict__ w2dst,
    float* __restrict__ cwrdst)
{
    int i = blockIdx.x * 256 + threadIdx.x;   // over W1Q+W2Q+CWQ
    if (i < W1Q) {
        int n = i / (DMODEL / 4);
        int k = (i % (DMODEL / 4)) * 4;
        ushort4 h = {0,0,0,0};
        if (n < NPROJ) {
            float4 v = *(const float4*)(w1src + (size_t)n * DMODEL + k);
            h.x = f2hu(v.x); h.y = f2hu(v.y); h.z = f2hu(v.z); h.w = f2hu(v.w);
        }
        w1dst[i] = h;
    } else if (i < W1Q + W2Q) {
        int t = i - W1Q;
        float4 v = ((const float4*)w2src)[t];
        ushort4 h;
        h.x = f2hu(v.x); h.y = f2hu(v.y); h.z = f2hu(v.z); h.w = f2hu(v.w);
        w2dst[t] = h;
    } else if (i < W1Q + W2Q + CWQ) {
        int t = i - W1Q - W2Q;
#pragma unroll
        for (int k = 0; k < 4; ++k) {
            int e = 4 * t + k;                // index into cwr: cg*72 + tap*8 + q
            int cgx = e / 72;
            int rr = e % 72;
            int tap = rr >> 3, q = rr & 7;
            cwrdst[e] = cwsrc[(cgx * 8 + q) * 9 + tap];
        }
    }
}

// ---------------- GEMM1 (MFMA f16, pipelined dbuf): zxbcdt = x @ in_proj_w^T ----
#define LDSW 40
__global__ __launch_bounds__(256) void k_gemm1_mfma(
    const ushort* __restrict__ xh, const ushort* __restrict__ wh,
    const float* __restrict__ dt_bias,
    ushort* __restrict__ zbuf, ushort* __restrict__ xbcbuf, float* __restrict__ dtbuf)
{
    __shared__ ushort As[2][128 * LDSW];
    __shared__ ushort Bs[2][128 * LDSW];
    const int m0 = blockIdx.y * 128;
    const int n0 = blockIdx.x * 128;
    const int tid = threadIdx.x;
    const int wid = tid >> 6;
    const int lane = tid & 63;
    const int r = lane & 15;
    const int quad = lane >> 4;
    const int wm = (wid >> 1) * 64;
    const int wn = (wid & 1) * 64;
    const int srow = tid >> 2;        // 0..63
    const int scol = (tid & 3) * 8;   // 0,8,16,24

    f32x4 acc[4][4];
#pragma unroll
    for (int i = 0; i < 4; ++i)
#pragma unroll
        for (int j = 0; j < 4; ++j) acc[i][j] = (f32x4){0.f, 0.f, 0.f, 0.f};

    {
        int4 a0 = *(const int4*)(xh + (size_t)(m0 + srow)      * DMODEL + scol);
        int4 a1 = *(const int4*)(xh + (size_t)(m0 + srow + 64) * DMODEL + scol);
        int4 b0 = *(const int4*)(wh + (size_t)(n0 + srow)      * DMODEL + scol);
        int4 b1 = *(const int4*)(wh + (size_t)(n0 + srow + 64) * DMODEL + scol);
        *(int4*)(As[0] + srow * LDSW + scol)        = a0;
        *(int4*)(As[0] + (srow + 64) * LDSW + scol) = a1;
        *(int4*)(Bs[0] + srow * LDSW + scol)        = b0;
        *(int4*)(Bs[0] + (srow + 64) * LDSW + scol) = b1;
    }
    __syncthreads();

    int cur = 0;
    for (int k0 = 32; k0 <= DMODEL; k0 += 32) {
        const bool has = (k0 < DMODEL);
        int4 na0, na1, nb0, nb1;
        if (has) {
            na0 = *(const int4*)(xh + (size_t)(m0 + srow)      * DMODEL + k0 + scol);
            na1 = *(const int4*)(xh + (size_t)(m0 + srow + 64) * DMODEL + k0 + scol);
            nb0 = *(const int4*)(wh + (size_t)(n0 + srow)      * DMODEL + k0 + scol);
            nb1 = *(const int4*)(wh + (size_t)(n0 + srow + 64) * DMODEL + k0 + scol);
        }
        f16x8 af[4], bfr[4];
#pragma unroll
        for (int t = 0; t < 4; ++t) {
            af[t]  = *(const f16x8*)(As[cur] + (wm + t * 16 + r) * LDSW + quad * 8);
            bfr[t] = *(const f16x8*)(Bs[cur] + (wn + t * 16 + r) * LDSW + quad * 8);
        }
#pragma unroll
        for (int i = 0; i < 4; ++i)
#pragma unroll
            for (int j = 0; j < 4; ++j)
                acc[i][j] = __builtin_amdgcn_mfma_f32_16x16x32_f16(af[i], bfr[j], acc[i][j], 0, 0, 0);
        if (has) {
            *(int4*)(As[cur ^ 1] + srow * LDSW + scol)        = na0;
            *(int4*)(As[cur ^ 1] + (srow + 64) * LDSW + scol) = na1;
            *(int4*)(Bs[cur ^ 1] + srow * LDSW + scol)        = nb0;
            *(int4*)(Bs[cur ^ 1] + (srow + 64) * LDSW + scol) = nb1;
            __syncthreads();
            cur ^= 1;
        }
    }
#pragma unroll
    for (int i = 0; i < 4; ++i) {
#pragma unroll
        for (int j = 0; j < 4; ++j) {
            int n = n0 + wn + j * 16 + r;
            if (n >= NPROJ) continue;
#pragma unroll
            for (int v = 0; v < 4; ++v) {
                int m = m0 + wm + i * 16 + quad * 4 + v;
                float val = acc[i][j][v];
                if (n < DINNER) {
                    zbuf[(size_t)m * DINNER + n] = f2hu(val);
                } else if (n < DINNER + CDIM) {
                    xbcbuf[(size_t)m * CDIM + (n - DINNER)] = f2hu(val);
                } else {
                    int h = n - (DINNER + CDIM);
                    float t = val + dt_bias[h];
                    float sp = (t > 20.f) ? t : log1pf(expf(t));
                    dtbuf[(size_t)m * NH + h] = sp;
                }
            }
        }
    }
}

// ---------------- GEMM2 (MFMA f16, pipelined dbuf): out = gn @ w2^T -------------
__global__ __launch_bounds__(256) void k_gemm2_mfma(
    const ushort* __restrict__ gn, const ushort* __restrict__ wh,
    float* __restrict__ out)
{
    __shared__ ushort As[2][128 * LDSW];
    __shared__ ushort Bs[2][128 * LDSW];
    const int m0 = blockIdx.y * 128;
    const int n0 = blockIdx.x * 128;
    const int tid = threadIdx.x;
    const int wid = tid >> 6;
    const int lane = tid & 63;
    const int r = lane & 15;
    const int quad = lane >> 4;
    const int wm = (wid >> 1) * 64;
    const int wn = (wid & 1) * 64;
    const int srow = tid >> 2;
    const int scol = (tid & 3) * 8;

    f32x4 acc[4][4];
#pragma unroll
    for (int i = 0; i < 4; ++i)
#pragma unroll
        for (int j = 0; j < 4; ++j) acc[i][j] = (f32x4){0.f, 0.f, 0.f, 0.f};

    {
        int4 a0 = *(const int4*)(gn + (size_t)(m0 + srow)      * DINNER + scol);
        int4 a1 = *(const int4*)(gn + (size_t)(m0 + srow + 64) * DINNER + scol);
        int4 b0 = *(const int4*)(wh + (size_t)(n0 + srow)      * DINNER + scol);
        int4 b1 = *(const int4*)(wh + (size_t)(n0 + srow + 64) * DINNER + scol);
        *(int4*)(As[0] + srow * LDSW + scol)        = a0;
        *(int4*)(As[0] + (srow + 64) * LDSW + scol) = a1;
        *(int4*)(Bs[0] + srow * LDSW + scol)        = b0;
        *(int4*)(Bs[0] + (srow + 64) * LDSW + scol) = b1;
    }
    __syncthreads();

    int cur = 0;
    for (int k0 = 32; k0 <= DINNER; k0 += 32) {
        const bool has = (k0 < DINNER);
        int4 na0, na1, nb0, nb1;
        if (has) {
            na0 = *(const int4*)(gn + (size_t)(m0 + srow)      * DINNER + k0 + scol);
            na1 = *(const int4*)(gn + (size_t)(m0 + srow + 64) * DINNER + k0 + scol);
            nb0 = *(const int4*)(wh + (size_t)(n0 + srow)      * DINNER + k0 + scol);
            nb1 = *(const int4*)(wh + (size_t)(n0 + srow + 64) * DINNER + k0 + scol);
        }
        f16x8 af[4], bfr[4];
#pragma unroll
        for (int t = 0; t < 4; ++t) {
            af[t]  = *(const f16x8*)(As[cur] + (wm + t * 16 + r) * LDSW + quad * 8);
            bfr[t] = *(const f16x8*)(Bs[cur] + (wn + t * 16 + r) * LDSW + quad * 8);
        }
#pragma unroll
        for (int i = 0; i < 4; ++i)
#pragma unroll
            for (int j = 0; j < 4; ++j)
                acc[i][j] = __builtin_amdgcn_mfma_f32_16x16x32_f16(af[i], bfr[j], acc[i][j], 0, 0, 0);
        if (has) {
            *(int4*)(As[cur ^ 1] + srow * LDSW + scol)        = na0;
            *(int4*)(As[cur ^ 1] + (srow + 64) * LDSW + scol) = na1;
            *(int4*)(Bs[cur ^ 1] + srow * LDSW + scol)        = nb0;
            *(int4*)(Bs[cur ^ 1] + (srow + 64) * LDSW + scol) = nb1;
            __syncthreads();
            cur ^= 1;
        }
    }
#pragma unroll
    for (int i = 0; i < 4; ++i) {
#pragma unroll
        for (int j = 0; j < 4; ++j) {
            int n = n0 + wn + j * 16 + r;
#pragma unroll
            for (int v = 0; v < 4; ++v) {
                int m = m0 + wm + i * 16 + quad * 4 + v;
                out[(size_t)m * DMODEL + n] = acc[i][j][v];
            }
        }
    }
}

// ---------------- depthwise 3x3 conv + bias + SiLU, 4 pixels x 8 ch per thread --
// cwr layout: [cg][tap 0..8][8ch] fp32 (row's 24 weights = 6 contiguous float4).
__global__ __launch_bounds__(256) void k_conv(
    const ushort* __restrict__ xbc, const float* __restrict__ cwr,
    const float* __restrict__ cb, ushort* __restrict__ out)
{
    const int gid = blockIdx.x * 256 + threadIdx.x;  // over MTOT/4*NCG = 702,464
    const int cg  = gid % NCG;
    const int pq  = gid / NCG;
    const int b   = pq / (LL / 4);
    const int rem = pq % (LL / 4);
    const int i   = rem / (WW / 4);
    const int j0  = (rem % (WW / 4)) * 4;
    const int c0  = cg * 8;

    float acc[4][8];
    {
        float4 b0 = *(const float4*)(cb + c0);
        float4 b1 = *(const float4*)(cb + c0 + 4);
#pragma unroll
        for (int p = 0; p < 4; ++p) {
            acc[p][0]=b0.x; acc[p][1]=b0.y; acc[p][2]=b0.z; acc[p][3]=b0.w;
            acc[p][4]=b1.x; acc[p][5]=b1.y; acc[p][6]=b1.z; acc[p][7]=b1.w;
        }
    }
    const size_t rowbase = (size_t)b * LL;
#pragma unroll
    for (int ky = 0; ky < 3; ++ky) {
        int ii = i + ky - 1;
        if (ii < 0 || ii >= HH) continue;
        float w[24];
        const float* wr = cwr + (cg * 9 + ky * 3) * 8;
#pragma unroll
        for (int t = 0; t < 6; ++t)
            *(float4*)(w + t * 4) = *(const float4*)(wr + t * 4);
        float xc[6][8];
#pragma unroll
        for (int col = 0; col < 6; ++col) {
            int jj = j0 - 1 + col;
            if (jj >= 0 && jj < WW) {
                union { int4 q; ushort u[8]; } xv;
                xv.q = *(const int4*)(xbc + (rowbase + ii * WW + jj) * CDIM + c0);
#pragma unroll
                for (int q = 0; q < 8; ++q) xc[col][q] = hu2f(xv.u[q]);
            } else {
#pragma unroll
                for (int q = 0; q < 8; ++q) xc[col][q] = 0.f;
            }
        }
#pragma unroll
        for (int p = 0; p < 4; ++p)
#pragma unroll
            for (int kx = 0; kx < 3; ++kx)
#pragma unroll
                for (int q = 0; q < 8; ++q)
                    acc[p][q] += w[kx * 8 + q] * xc[p + kx][q];
    }
#pragma unroll
    for (int p = 0; p < 4; ++p) {
        union { int4 q; ushort u[8]; } o;
#pragma unroll
        for (int q = 0; q < 8; ++q) {
            float s = acc[p][q] / (1.f + expf(-acc[p][q]));
            o.u[q] = f2hu(s);
        }
        *(int4*)(out + (rowbase + i * WW + j0 + p) * CDIM + c0) = o.q;
    }
}

// ---------------- fused dx + 3x3 count-norm avg pool, 4 pixels x 8 ch -----------
__global__ __launch_bounds__(256) void k_dxpool(
    const ushort* __restrict__ xbc_conv, const float* __restrict__ dtbuf,
    const float* __restrict__ A_log, ushort* __restrict__ dxp)
{
    const int gid = blockIdx.x * 256 + threadIdx.x;  // over MTOT/4*NDG = 602,112
    const int cg  = gid % NDG;
    const int pq  = gid / NDG;
    const int b   = pq / (LL / 4);
    const int rem = pq % (LL / 4);
    const int i   = rem / (WW / 4);
    const int j0  = (rem % (WW / 4)) * 4;
    const int c0  = cg * 8;         // channel in [0,768)
    const int h   = c0 >> 6;

    float Ah[8];
    {
        float4 a0 = *(const float4*)(A_log + c0);
        float4 a1 = *(const float4*)(A_log + c0 + 4);
        Ah[0]=a0.x; Ah[1]=a0.y; Ah[2]=a0.z; Ah[3]=a0.w;
        Ah[4]=a1.x; Ah[5]=a1.y; Ah[6]=a1.z; Ah[7]=a1.w;
    }
#pragma unroll
    for (int q = 0; q < 8; ++q) Ah[q] = -expf(Ah[q]);

    float sum[4][8];
#pragma unroll
    for (int p = 0; p < 4; ++p)
#pragma unroll
        for (int q = 0; q < 8; ++q) sum[p][q] = 0.f;

    const size_t rowbase = (size_t)b * LL;
#pragma unroll
    for (int ky = 0; ky < 3; ++ky) {
        int ii = i + ky - 1;
        if (ii < 0 || ii >= HH) continue;
        float dtv[6];
        float xc[6][8];
#pragma unroll
        for (int col = 0; col < 6; ++col) {
            int jj = j0 - 1 + col;
            if (jj >= 0 && jj < WW) {
                dtv[col] = dtbuf[(rowbase + ii * WW + jj) * NH + h];
                union { int4 q; ushort u[8]; } xv;
                xv.q = *(const int4*)(xbc_conv + (rowbase + ii * WW + jj) * CDIM + c0);
#pragma unroll
                for (int q = 0; q < 8; ++q) xc[col][q] = hu2f(xv.u[q]);
            } else {
                dtv[col] = 0.f;
#pragma unroll
                for (int q = 0; q < 8; ++q) xc[col][q] = 0.f;
            }
        }
#pragma unroll
        for (int p = 0; p < 4; ++p)
#pragma unroll
            for (int kx = 0; kx < 3; ++kx)
#pragma unroll
                for (int q = 0; q < 8; ++q)
                    sum[p][q] += dtv[p + kx] * xc[p + kx][q];
    }
    const int rv = 3 - (i == 0) - (i == HH - 1);
#pragma unroll
    for (int p = 0; p < 4; ++p) {
        int j = j0 + p;
        int cv = 3 - (j == 0) - (j == WW - 1);
        float inv = 1.f / (float)(rv * cv);
        union { int4 q; ushort u[8]; } o;
#pragma unroll
        for (int q = 0; q < 8; ++q)
            o.u[q] = f2hu(Ah[q] * sum[p][q] * inv);
        *(int4*)(dxp + (((size_t)b * NH + h) * LL + i * WW + j) * HD + (c0 & 63)) = o.q;
    }
}

// ---------------- h_state via MFMA (no atomics): Ht_part[d][s] ------------------
#define LDSP 33
__global__ __launch_bounds__(256) void k_hstate_mfma(
    const ushort* __restrict__ xbc_conv, const ushort* __restrict__ dxp,
    float* __restrict__ hpart)
{
    __shared__ ushort DsT[64 * LDSP];   // [d][l]
    __shared__ ushort BsT[64 * LDSP];   // [s][l]
    const int lc = blockIdx.x;          // 0..6
    const int bh = blockIdx.y;          // 0..95
    const int b = bh / NH;
    const int tid = threadIdx.x;
    const int wid = tid >> 6;
    const int lane = tid & 63;
    const int r = lane & 15;
    const int quad = lane >> 4;
    const int wd = (wid >> 1) * 32;     // d-offset of wave quadrant
    const int wsn = (wid & 1) * 32;     // s-offset
    const int lt = tid >> 3;            // 0..31 (l within tile)
    const int sg = (tid & 7) * 8;       // 0,8,..,56 (channel group)

    f32x4 acc[2][2];
#pragma unroll
    for (int i = 0; i < 2; ++i)
#pragma unroll
        for (int j = 0; j < 2; ++j) acc[i][j] = (f32x4){0.f, 0.f, 0.f, 0.f};

    const int l_base = lc * (LL / SPLITL);    // 448-chunk
    for (int step = 0; step < (LL / SPLITL) / 32; ++step) {
        int l0 = l_base + step * 32;
        union { int4 q; ushort u[8]; } dv, bv;
        dv.q = *(const int4*)(dxp + (((size_t)bh) * LL + l0 + lt) * HD + sg);
        bv.q = *(const int4*)(xbc_conv + ((size_t)(b * LL + l0 + lt)) * CDIM + DINNER + sg);
        __syncthreads();
#pragma unroll
        for (int q = 0; q < 8; ++q) {
            DsT[(sg + q) * LDSP + lt] = dv.u[q];
            BsT[(sg + q) * LDSP + lt] = bv.u[q];
        }
        __syncthreads();
        f16x8 af[2], bf[2];
#pragma unroll
        for (int t = 0; t < 2; ++t) {
            af[t] = *(const f16x8*)(DsT + (wd + t * 16 + r) * LDSP + quad * 8);
            bf[t] = *(const f16x8*)(BsT + (wsn + t * 16 + r) * LDSP + quad * 8);
        }
#pragma unroll
        for (int i = 0; i < 2; ++i)
#pragma unroll
            for (int j = 0; j < 2; ++j)
                acc[i][j] = __builtin_amdgcn_mfma_f32_16x16x32_f16(af[i], bf[j], acc[i][j], 0, 0, 0);
    }
    float* outp = hpart + ((size_t)(lc * 96 + bh) << 12);
#pragma unroll
    for (int i = 0; i < 2; ++i)
#pragma unroll
        for (int j = 0; j < 2; ++j)
#pragma unroll
            for (int v = 0; v < 4; ++v)
                outp[(wd + i * 16 + quad * 4 + v) * 64 + (wsn + j * 16 + r)] = acc[i][j][v];
}

// ---------------- h-prep: reduce 7 partials [d][s] -> hT f16 [bh][d][s] ---------
__global__ __launch_bounds__(256) void k_hprep(
    const float* __restrict__ hpart, ushort* __restrict__ hT)
{
    int i = blockIdx.x * 256 + threadIdx.x;   // over 96*4096 = 393216
    int bh = i >> 12;
    int rem = i & 4095;                       // = d*64+s
    float v = 0.f;
#pragma unroll
    for (int lc = 0; lc < SPLITL; ++lc)
        v += hpart[((size_t)(lc * 96 + bh) << 12) + rem];
    hT[i] = f2hu(v);
}

// ---------------- Ch + y via MFMA: per (b,h), y = Cm[L x 64] @ h[64 x 64] -------
#define HTW 72
__global__ __launch_bounds__(256) void k_chy_mfma(
    const ushort* __restrict__ xbc_conv, const ushort* __restrict__ hT,
    const float* __restrict__ Dp, ushort* __restrict__ ybuf)
{
    __shared__ ushort Hs[64 * HTW];
    const int bh = blockIdx.y;
    const int b = bh / NH, h = bh % NH;
    const int tid = threadIdx.x;
    const int wid = tid >> 6;
    const int lane = tid & 63;
    const int r = lane & 15;
    const int quad = lane >> 4;

    for (int idx = tid; idx < 512; idx += 256) {
        int row = idx >> 3, c8 = (idx & 7) * 8;
        *(int4*)(Hs + row * HTW + c8) = *(const int4*)(hT + ((size_t)bh << 12) + row * 64 + c8);
    }
    __syncthreads();

    const int chunk = blockIdx.x * 4 + wid;   // 0..48 valid (49 chunks of 64 l-rows)
    if (chunk >= 49) return;
    const int l0 = chunk * 64;

    f32x4 acc[4][4];
#pragma unroll
    for (int i = 0; i < 4; ++i)
#pragma unroll
        for (int j = 0; j < 4; ++j) acc[i][j] = (f32x4){0.f, 0.f, 0.f, 0.f};

#pragma unroll
    for (int kk = 0; kk < 2; ++kk) {          // K=64 in two 32-steps
        f16x8 af[4], bfr[4];
#pragma unroll
        for (int t = 0; t < 4; ++t) {
            af[t] = *(const f16x8*)(xbc_conv +
                ((size_t)(b * LL + l0 + t * 16 + r)) * CDIM + DINNER + DS + kk * 32 + quad * 8);
            bfr[t] = *(const f16x8*)(Hs + (t * 16 + r) * HTW + kk * 32 + quad * 8);
        }
#pragma unroll
        for (int i = 0; i < 4; ++i)
#pragma unroll
            for (int j = 0; j < 4; ++j)
                acc[i][j] = __builtin_amdgcn_mfma_f32_16x16x32_f16(af[i], bfr[j], acc[i][j], 0, 0, 0);
    }
    const float Dh = Dp[h];
#pragma unroll
    for (int i = 0; i < 4; ++i) {
#pragma unroll
        for (int j = 0; j < 4; ++j) {
            int d = j * 16 + r;
#pragma unroll
            for (int v = 0; v < 4; ++v) {
                int l = l0 + i * 16 + quad * 4 + v;
                float xv = hu2f(xbc_conv[((size_t)(b * LL + l)) * CDIM + h * HD + d]);
                ybuf[((size_t)(b * LL + l)) * DINNER + h * HD + d] = f2hu(acc[i][j][v] + xv * Dh);
            }
        }
    }
}

// ---------------- g = y*silu(z); LayerNorm(768), wave-per-row -------------------
__global__ __launch_bounds__(256) void k_gln(
    const ushort* __restrict__ ybuf, const ushort* __restrict__ zbuf,
    const float* __restrict__ nw, const float* __restrict__ nb,
    ushort* __restrict__ gnbuf)
{
    const int row = blockIdx.x * 4 + (threadIdx.x >> 6);
    const int lane = threadIdx.x & 63;
    const size_t base = (size_t)row * DINNER;

    float g[12];
    float sum = 0.f, sumsq = 0.f;
#pragma unroll
    for (int p = 0; p < 3; ++p) {
        int c = lane * 4 + p * 256;
        union { ushort4 q; ushort u[4]; } yv, zv;
        yv.q = *(const ushort4*)(ybuf + base + c);
        zv.q = *(const ushort4*)(zbuf + base + c);
#pragma unroll
        for (int q = 0; q < 4; ++q) {
            float y = hu2f(yv.u[q]);
            float z = hu2f(zv.u[q]);
            float gv = y * (z / (1.f + expf(-z)));
            g[p * 4 + q] = gv;
            sum += gv;
            sumsq += gv * gv;
        }
    }
#pragma unroll
    for (int off = 32; off > 0; off >>= 1) {
        sum += __shfl_xor(sum, off, 64);
        sumsq += __shfl_xor(sumsq, off, 64);
    }
    const float mu = sum / (float)DINNER;
    const float var = sumsq / (float)DINNER - mu * mu;
    const float rstd = rsqrtf(var + LN_EPS);
#pragma unroll
    for (int p = 0; p < 3; ++p) {
        int c = lane * 4 + p * 256;
        float4 w = *(const float4*)(nw + c);
        float4 bb = *(const float4*)(nb + c);
        union { ushort4 q; ushort u[4]; } o;
        o.u[0] = f2hu((g[p*4+0] - mu) * rstd * w.x + bb.x);
        o.u[1] = f2hu((g[p*4+1] - mu) * rstd * w.y + bb.y);
        o.u[2] = f2hu((g[p*4+2] - mu) * rstd * w.z + bb.z);
        o.u[3] = f2hu((g[p*4+3] - mu) * rstd * w.w + bb.w);
        *(ushort4*)(gnbuf + base + c) = o.q;
    }
}

extern "C" void kernel_launch(void* const* d_in, const int* in_sizes, int n_in,
                              void* d_out, int out_size, void* d_ws, size_t ws_size,
                              hipStream_t stream)
{
    const float* x         = (const float*)d_in[0];
    const float* in_proj_w = (const float*)d_in[1];
    const float* conv_w    = (const float*)d_in[2];
    const float* conv_b    = (const float*)d_in[3];
    const float* dt_bias   = (const float*)d_in[4];
    const float* A_log     = (const float*)d_in[5];
    const float* Dp        = (const float*)d_in[6];
    const float* norm_w    = (const float*)d_in[7];
    const float* norm_b    = (const float*)d_in[8];
    const float* out_proj_w= (const float*)d_in[9];

    // workspace layout (bytes) — same offsets as known-good rounds 7-9:
    char* wsb = (char*)d_ws;
    float*  dtbuf   = (float*) (wsb + 0);           //  1,204,224 fp32 MTOT*NH
    float*  cwr     = (float*) (wsb + 1204224);     //     32,256 fp32 conv-w reorg
    ushort* w1      = (ushort*)(wsb + 2777088);     //  1,376,256 f16 NPAD*384
    ushort* w2      = (ushort*)(wsb + 4153344);     //    589,824 f16 384*768
    ushort* zbuf    = (ushort*)(wsb + 4743168);     // 38,535,168 f16 MTOT*DINNER
    ushort* xbcraw  = (ushort*)(wsb + 43278336);    // 44,957,696 f16 MTOT*CDIM
    ushort* xbcconv = (ushort*)(wsb + 88236032);    // 44,957,696 f16 MTOT*CDIM
    ushort* x16     = xbcconv;                      // f16 cast of x; dead after gemm1
    ushort* hT      = xbcraw;                       //    786,432 B (raw xBC dead after conv)
    float*  hpart   = (float*)(wsb + 44851200);     // 11,010,048 B (7*96*4096 fp32)
    ushort* dxp     = (ushort*)d_out;               // consumed before final GEMM write
    ushort* ybuf    = (ushort*)d_out;
    ushort* gnbuf   = xbcraw;                       // clobbers hT/hpart after consumed

    k_cast_x <<<MTOT * DMODEL / 4 / 256, 256, 0, stream>>>(
        (const float4*)x, (ushort4*)x16);
    k_cast_w<<<(W1Q + W2Q + CWQ + 255) / 256, 256, 0, stream>>>(
        in_proj_w, out_proj_w, conv_w, (ushort4*)w1, (ushort4*)w2, cwr);

    k_gemm1_mfma<<<dim3(NPAD / 128, MTOT / 128), 256, 0, stream>>>(
        x16, w1, dt_bias, zbuf, xbcraw, dtbuf);

    k_conv<<<MTOT / 4 * NCG / 256, 256, 0, stream>>>(
        xbcraw, cwr, conv_b, xbcconv);
    k_dxpool<<<MTOT / 4 * NDG / 256, 256, 0, stream>>>(
        xbcconv, dtbuf, A_log, dxp);
    k_hstate_mfma<<<dim3(SPLITL, BB * NH), 256, 0, stream>>>(
        xbcconv, dxp, hpart);
    k_hprep<<<96 * 4096 / 256, 256, 0, stream>>>(hpart, hT);
    k_chy_mfma<<<dim3(13, BB * NH), 256, 0, stream>>>(
        xbcconv, hT, Dp, ybuf);
    k_gln<<<MTOT / 4, 256, 0, stream>>>(
        ybuf, zbuf, norm_w, norm_b, gnbuf);
    k_gemm2_mfma<<<dim3(DMODEL / 128, MTOT / 128), 256, 0, stream>>>(
        gnbuf, w2, (float*)d_out);
}